// Round 1
// baseline (1827.084 us; speedup 1.0000x reference)
//
#include <hip/hip_runtime.h>
#include <math.h>

#define NPIX 4096
#define EPSBN 1e-5f

__device__ __forceinline__ float sigmoidf_(float x) { return 1.0f / (1.0f + expf(-x)); }

// ---------------------------------------------------------------------------
// Generic 1x1-conv GEMM: out[b][co][n] = epi( sum_ci w[co][ci]*in[b][ci][n] + bias[co] )
// MODE 0: bias only
// MODE 1: relu(bn(acc+bias))
// MODE 2: out = aux * sigmoid(relu(bn(acc+bias)))          (gate1; aux = feat)
// MODE 3: out = aux * sigmoid(relu(bn(acc+bias)) + yr[b][co])   (final)
// Tile: 64co x 64n, 256 threads, 4x4 per thread.
// ---------------------------------------------------------------------------
template <int MODE>
__global__ __launch_bounds__(256) void conv1x1_k(
    const float* __restrict__ in, const float* __restrict__ w,
    const float* __restrict__ bias, float* __restrict__ out,
    int Cin, int Cout,
    const float* __restrict__ bng, const float* __restrict__ bnb,
    const float* __restrict__ bnm, const float* __restrict__ bnv,
    const float* __restrict__ aux, const float* __restrict__ yr)
{
    const int bz = blockIdx.z;
    const int n0 = blockIdx.x * 64;
    const int co0 = blockIdx.y * 64;
    const int tid = threadIdx.x;
    const int tj = tid & 15;   // n sub-tile
    const int ti = tid >> 4;   // co sub-tile
    __shared__ alignas(16) float ls_in[16][64];  // [k][n]
    __shared__ alignas(16) float ls_w[16][68];   // [k][co], padded (272B rows: aligned, low-conflict)
    float acc[4][4] = {};
    const float* inb = in + (size_t)bz * Cin * NPIX;

    for (int k0 = 0; k0 < Cin; k0 += 16) {
        int e = tid;
#pragma unroll
        for (int r = 0; r < 4; ++r, e += 256) {
            int kk = e >> 6, nn = e & 63;
            ls_in[kk][nn] = inb[(size_t)(k0 + kk) * NPIX + n0 + nn];
        }
        e = tid;
#pragma unroll
        for (int r = 0; r < 4; ++r, e += 256) {
            int cc = e >> 4, kk = e & 15;
            ls_w[kk][cc] = w[(size_t)(co0 + cc) * Cin + k0 + kk];
        }
        __syncthreads();
#pragma unroll
        for (int kk = 0; kk < 16; ++kk) {
            float4 xv = *(const float4*)&ls_in[kk][tj << 2];
            float4 wv = *(const float4*)&ls_w[kk][ti << 2];
            float xa[4] = {xv.x, xv.y, xv.z, xv.w};
            float wa[4] = {wv.x, wv.y, wv.z, wv.w};
#pragma unroll
            for (int i = 0; i < 4; ++i)
#pragma unroll
                for (int j = 0; j < 4; ++j)
                    acc[i][j] = fmaf(wa[i], xa[j], acc[i][j]);
        }
        __syncthreads();
    }

#pragma unroll
    for (int i = 0; i < 4; ++i) {
        int co = co0 + (ti << 2) + i;
        float bi = bias[co];
        float s = 0.f, t = 0.f;
        if (MODE >= 1) {
            s = bng[co] * rsqrtf(bnv[co] + EPSBN);
            t = bnb[co] - bnm[co] * s;
        }
        float yrv = (MODE == 3) ? yr[(size_t)bz * Cout + co] : 0.f;
        size_t base = ((size_t)bz * Cout + co) * NPIX + n0 + (tj << 2);
        float4 av = make_float4(0.f, 0.f, 0.f, 0.f);
        if (MODE >= 2) av = *(const float4*)(aux + base);
        const float* ap = &av.x;
        float4 res;
        float* rp = &res.x;
#pragma unroll
        for (int j = 0; j < 4; ++j) {
            float x = acc[i][j] + bi;
            float r;
            if (MODE == 0)      r = x;
            else if (MODE == 1) r = fmaxf(s * x + t, 0.f);
            else if (MODE == 2) r = ap[j] * sigmoidf_(fmaxf(s * x + t, 0.f));
            else                r = ap[j] * sigmoidf_(fmaxf(s * x + t, 0.f) + yrv);
            rp[j] = r;
        }
        *(float4*)(out + base) = res;
    }
}

// ---------------------------------------------------------------------------
// energy[n][m] = sum_{c<128} q[c][n]*k[c][m]   (single batch; q,k pre-offset)
// ---------------------------------------------------------------------------
__global__ __launch_bounds__(256) void energy_k(
    const float* __restrict__ q, const float* __restrict__ k,
    float* __restrict__ e)
{
    const int m0 = blockIdx.x * 64;
    const int n0 = blockIdx.y * 64;
    const int tid = threadIdx.x;
    const int tj = tid & 15;  // m
    const int ti = tid >> 4;  // n
    __shared__ alignas(16) float ls_q[16][64];
    __shared__ alignas(16) float ls_k[16][64];
    float acc[4][4] = {};

    for (int c0 = 0; c0 < 128; c0 += 16) {
        int el = tid;
#pragma unroll
        for (int r = 0; r < 4; ++r, el += 256) {
            int kk = el >> 6, nn = el & 63;
            ls_q[kk][nn] = q[(size_t)(c0 + kk) * NPIX + n0 + nn];
            ls_k[kk][nn] = k[(size_t)(c0 + kk) * NPIX + m0 + nn];
        }
        __syncthreads();
#pragma unroll
        for (int kk = 0; kk < 16; ++kk) {
            float4 qv = *(const float4*)&ls_q[kk][ti << 2];
            float4 kv = *(const float4*)&ls_k[kk][tj << 2];
            float qa[4] = {qv.x, qv.y, qv.z, qv.w};
            float ka[4] = {kv.x, kv.y, kv.z, kv.w};
#pragma unroll
            for (int i = 0; i < 4; ++i)
#pragma unroll
                for (int j = 0; j < 4; ++j)
                    acc[i][j] = fmaf(qa[i], ka[j], acc[i][j]);
        }
        __syncthreads();
    }
#pragma unroll
    for (int i = 0; i < 4; ++i) {
        size_t base = (size_t)(n0 + (ti << 2) + i) * NPIX + m0 + (tj << 2);
        float4 res = make_float4(acc[i][0], acc[i][1], acc[i][2], acc[i][3]);
        *(float4*)(e + base) = res;
    }
}

// ---------------------------------------------------------------------------
// Row softmax over 4096 (in-place). One block per row.
// ---------------------------------------------------------------------------
__global__ __launch_bounds__(256) void softmax_k(float* __restrict__ e)
{
    const size_t row = blockIdx.x;
    float* r = e + row * NPIX;
    const int tid = threadIdx.x;
    float vals[16];
    float mx = -1e30f;
#pragma unroll
    for (int i = 0; i < 16; ++i) {
        vals[i] = r[tid + (i << 8)];
        mx = fmaxf(mx, vals[i]);
    }
#pragma unroll
    for (int o = 32; o; o >>= 1) mx = fmaxf(mx, __shfl_xor(mx, o));
    __shared__ float sm[4], ss[4];
    if ((tid & 63) == 0) sm[tid >> 6] = mx;
    __syncthreads();
    mx = fmaxf(fmaxf(sm[0], sm[1]), fmaxf(sm[2], sm[3]));
    float s = 0.f;
#pragma unroll
    for (int i = 0; i < 16; ++i) {
        vals[i] = expf(vals[i] - mx);
        s += vals[i];
    }
#pragma unroll
    for (int o = 32; o; o >>= 1) s += __shfl_xor(s, o);
    if ((tid & 63) == 0) ss[tid >> 6] = s;
    __syncthreads();
    s = ss[0] + ss[1] + ss[2] + ss[3];
    float inv = 1.0f / s;
#pragma unroll
    for (int i = 0; i < 16; ++i) r[tid + (i << 8)] = vals[i] * inv;
}

// ---------------------------------------------------------------------------
// feat[c][n] = sum_m v[c][m] * attn[n][m]   (single batch; v,f pre-offset)
// Both operands K(m)-contiguous -> transposed LDS staging (pad 68).
// ---------------------------------------------------------------------------
__global__ __launch_bounds__(256) void feat_k(
    const float* __restrict__ v, const float* __restrict__ a,
    float* __restrict__ f)
{
    const int n0 = blockIdx.x * 64;
    const int c0 = blockIdx.y * 64;
    const int tid = threadIdx.x;
    const int tj = tid & 15;  // n
    const int ti = tid >> 4;  // c
    __shared__ alignas(16) float ls_v[16][68];  // [m][c]
    __shared__ alignas(16) float ls_a[16][68];  // [m][n]
    float acc[4][4] = {};

    for (int m0 = 0; m0 < NPIX; m0 += 16) {
        int el = tid;
#pragma unroll
        for (int r = 0; r < 4; ++r, el += 256) {
            int cc = el >> 4, mm = el & 15;
            ls_v[mm][cc] = v[(size_t)(c0 + cc) * NPIX + m0 + mm];
            ls_a[mm][cc] = a[(size_t)(n0 + cc) * NPIX + m0 + mm];
        }
        __syncthreads();
#pragma unroll
        for (int mm = 0; mm < 16; ++mm) {
            float4 vv = *(const float4*)&ls_v[mm][ti << 2];
            float4 av = *(const float4*)&ls_a[mm][tj << 2];
            float va[4] = {vv.x, vv.y, vv.z, vv.w};
            float aa[4] = {av.x, av.y, av.z, av.w};
#pragma unroll
            for (int i = 0; i < 4; ++i)
#pragma unroll
                for (int j = 0; j < 4; ++j)
                    acc[i][j] = fmaf(va[i], aa[j], acc[i][j]);
        }
        __syncthreads();
    }
#pragma unroll
    for (int i = 0; i < 4; ++i) {
        size_t base = (size_t)(c0 + (ti << 2) + i) * NPIX + n0 + (tj << 2);
        float4 res = make_float4(acc[i][0], acc[i][1], acc[i][2], acc[i][3]);
        *(float4*)(f + base) = res;
    }
}

// ---------------------------------------------------------------------------
// Direct 3x3 SAME conv + bn + relu. Block: 64co x 1h x 64w. 256 threads, 4co x 4w each.
// ---------------------------------------------------------------------------
__global__ __launch_bounds__(256) void conv3_k(
    const float* __restrict__ in, const float* __restrict__ w9,
    const float* __restrict__ bias,
    const float* __restrict__ bng, const float* __restrict__ bnb,
    const float* __restrict__ bnm, const float* __restrict__ bnv,
    float* __restrict__ out)
{
    const int bz = blockIdx.z;
    const int h = blockIdx.y;
    const int co0 = blockIdx.x * 64;
    const int tid = threadIdx.x;
    const int tj = tid & 15;  // w
    const int ti = tid >> 4;  // co
    __shared__ float ls_in[16][3][66];           // [ci][dy][w+halo]
    __shared__ alignas(16) float ls_w[16][9][68]; // [ci][tap][co]
    float acc[4][4] = {};

    for (int c0 = 0; c0 < 256; c0 += 16) {
        for (int el = tid; el < 16 * 3 * 66; el += 256) {
            int ci = el / 198;
            int r = el - ci * 198;
            int dy = r / 66;
            int col = r - dy * 66;
            int hh = h + dy - 1;
            int wg = col - 1;
            float val = 0.f;
            if (hh >= 0 && hh < 64 && wg >= 0 && wg < 64)
                val = in[((size_t)(bz * 256 + c0 + ci) * 64 + hh) * 64 + wg];
            ls_in[ci][dy][col] = val;
        }
        for (int el = tid; el < 16 * 9 * 64; el += 256) {
            int cc = el / 144;
            int r = el - cc * 144;
            int ci = r / 9;
            int tap = r - ci * 9;
            ls_w[ci][tap][cc] = w9[((size_t)(co0 + cc) * 256 + c0 + ci) * 9 + tap];
        }
        __syncthreads();
        for (int ci = 0; ci < 16; ++ci) {
#pragma unroll
            for (int dy = 0; dy < 3; ++dy) {
                float in6[6];
#pragma unroll
                for (int t = 0; t < 6; ++t) in6[t] = ls_in[ci][dy][(tj << 2) + t];
#pragma unroll
                for (int dx = 0; dx < 3; ++dx) {
                    float4 wv = *(const float4*)&ls_w[ci][dy * 3 + dx][ti << 2];
                    float wa[4] = {wv.x, wv.y, wv.z, wv.w};
#pragma unroll
                    for (int i = 0; i < 4; ++i)
#pragma unroll
                        for (int j = 0; j < 4; ++j)
                            acc[i][j] = fmaf(wa[i], in6[j + dx], acc[i][j]);
                }
            }
        }
        __syncthreads();
    }
#pragma unroll
    for (int i = 0; i < 4; ++i) {
        int co = co0 + (ti << 2) + i;
        float s = bng[co] * rsqrtf(bnv[co] + EPSBN);
        float t = bnb[co] - bnm[co] * s;
        float bi = bias[co];
        size_t base = ((size_t)(bz * 256 + co) * 64 + h) * 64 + (tj << 2);
        float4 res;
        float* rp = &res.x;
#pragma unroll
        for (int j = 0; j < 4; ++j) rp[j] = fmaxf(s * (acc[i][j] + bi) + t, 0.f);
        *(float4*)(out + base) = res;
    }
}

// ---------------------------------------------------------------------------
// pooled[b*256+c] = mean_n y[b][c][n]
// ---------------------------------------------------------------------------
__global__ __launch_bounds__(256) void pool_k(const float* __restrict__ y,
                                              float* __restrict__ pooled)
{
    const int bc = blockIdx.x;
    const float* r = y + (size_t)bc * NPIX;
    float s = 0.f;
    for (int i = threadIdx.x; i < NPIX; i += 256) s += r[i];
#pragma unroll
    for (int o = 32; o; o >>= 1) s += __shfl_xor(s, o);
    __shared__ float sm[4];
    if ((threadIdx.x & 63) == 0) sm[threadIdx.x >> 6] = s;
    __syncthreads();
    if (threadIdx.x == 0) pooled[bc] = (sm[0] + sm[1] + sm[2] + sm[3]) * (1.0f / NPIX);
}

// ---------------------------------------------------------------------------
// SE branch: yr[b][c] = r2( relu(bn(r1(pooled))) )   — one block per batch
// ---------------------------------------------------------------------------
__global__ __launch_bounds__(256) void se_k(
    const float* __restrict__ pooled,
    const float* __restrict__ r1w, const float* __restrict__ r1b,
    const float* __restrict__ g, const float* __restrict__ bb,
    const float* __restrict__ m, const float* __restrict__ vv,
    const float* __restrict__ r2w, const float* __restrict__ r2b,
    float* __restrict__ yr)
{
    const int b = blockIdx.x;
    const int tid = threadIdx.x;
    __shared__ float p[256], hbuf[128];
    p[tid] = pooled[b * 256 + tid];
    __syncthreads();
    if (tid < 128) {
        float a = r1b[tid];
        for (int ci = 0; ci < 256; ++ci) a = fmaf(r1w[tid * 256 + ci], p[ci], a);
        float s = g[tid] * rsqrtf(vv[tid] + EPSBN);
        float t = bb[tid] - m[tid] * s;
        hbuf[tid] = fmaxf(s * a + t, 0.f);
    }
    __syncthreads();
    float a = r2b[tid];
    for (int c2 = 0; c2 < 128; ++c2) a = fmaf(r2w[tid * 128 + c2], hbuf[c2], a);
    yr[b * 256 + tid] = a;
}

// ---------------------------------------------------------------------------
extern "C" void kernel_launch(void* const* d_in, const int* in_sizes, int n_in,
                              void* d_out, int out_size, void* d_ws, size_t ws_size,
                              hipStream_t stream)
{
    const float* x    = (const float*)d_in[0];
    const float* wq   = (const float*)d_in[1];
    const float* bq   = (const float*)d_in[2];
    const float* wk   = (const float*)d_in[3];
    const float* bk   = (const float*)d_in[4];
    const float* wv   = (const float*)d_in[5];
    const float* bv   = (const float*)d_in[6];
    const float* d1w  = (const float*)d_in[7];
    const float* d1b  = (const float*)d_in[8];
    const float* bn1g = (const float*)d_in[9];
    const float* bn1b = (const float*)d_in[10];
    const float* bn1m = (const float*)d_in[11];
    const float* bn1v = (const float*)d_in[12];
    const float* lbn1g = (const float*)d_in[13];
    const float* lbn1b = (const float*)d_in[14];
    const float* lbn1m = (const float*)d_in[15];
    const float* lbn1v = (const float*)d_in[16];
    const float* lbn2g = (const float*)d_in[17];
    const float* lbn2b = (const float*)d_in[18];
    const float* lbn2m = (const float*)d_in[19];
    const float* lbn2v = (const float*)d_in[20];
    const float* lbn3g = (const float*)d_in[21];
    const float* lbn3b = (const float*)d_in[22];
    const float* lbn3m = (const float*)d_in[23];
    const float* lbn3v = (const float*)d_in[24];
    const float* l1w  = (const float*)d_in[25];
    const float* l1b  = (const float*)d_in[26];
    const float* l2w  = (const float*)d_in[27];
    const float* l2b  = (const float*)d_in[28];
    const float* l3w  = (const float*)d_in[29];
    const float* l3b  = (const float*)d_in[30];
    const float* r1w  = (const float*)d_in[31];
    const float* r1b  = (const float*)d_in[32];
    const float* rbng = (const float*)d_in[33];
    const float* rbnb = (const float*)d_in[34];
    const float* rbnm = (const float*)d_in[35];
    const float* rbnv = (const float*)d_in[36];
    const float* r2w  = (const float*)d_in[37];
    const float* r2b  = (const float*)d_in[38];

    float* out = (float*)d_out;
    float* ws = (float*)d_ws;

    // workspace layout (floats); attn region is reused for y/t1/t2/pooled/yr
    float* qb   = ws;                                   // [4][128][4096]  8 MB
    float* kb   = qb + (size_t)4 * 128 * NPIX;          // 8 MB
    float* vb   = kb + (size_t)4 * 128 * NPIX;          // [4][256][4096] 16 MB
    float* feat = vb + (size_t)4 * 256 * NPIX;          // 16 MB
    float* attn = feat + (size_t)4 * 256 * NPIX;        // [4096][4096]   64 MB (per-batch)
    float* yb   = attn;                                 // alias: live after attn is dead
    float* t1   = yb + (size_t)4 * 256 * NPIX;
    float* t2   = t1 + (size_t)4 * 256 * NPIX;
    float* pooled = t2 + (size_t)4 * 256 * NPIX;        // [4][256]
    float* yrb  = pooled + 1024;                        // [4][256]
    // total ws requirement ≈ 118 MB

    dim3 blk(256);

    // q, k, v projections
    conv1x1_k<0><<<dim3(64, 2, 4), blk, 0, stream>>>(x, wq, bq, qb, 256, 128,
        nullptr, nullptr, nullptr, nullptr, nullptr, nullptr);
    conv1x1_k<0><<<dim3(64, 2, 4), blk, 0, stream>>>(x, wk, bk, kb, 256, 128,
        nullptr, nullptr, nullptr, nullptr, nullptr, nullptr);
    conv1x1_k<0><<<dim3(64, 4, 4), blk, 0, stream>>>(x, wv, bv, vb, 256, 256,
        nullptr, nullptr, nullptr, nullptr, nullptr, nullptr);

    // attention, one batch at a time (attn buffer reused)
    for (int b = 0; b < 4; ++b) {
        const float* qp = qb + (size_t)b * 128 * NPIX;
        const float* kp = kb + (size_t)b * 128 * NPIX;
        const float* vp = vb + (size_t)b * 256 * NPIX;
        float* fp = feat + (size_t)b * 256 * NPIX;
        energy_k<<<dim3(64, 64), blk, 0, stream>>>(qp, kp, attn);
        softmax_k<<<dim3(4096), blk, 0, stream>>>(attn);
        feat_k<<<dim3(64, 4), blk, 0, stream>>>(vp, attn, fp);
    }

    // y = feat * sigmoid(relu(bn1(d1(feat))))
    conv1x1_k<2><<<dim3(64, 4, 4), blk, 0, stream>>>(feat, d1w, d1b, yb, 256, 256,
        bn1g, bn1b, bn1m, bn1v, feat, nullptr);

    // SE branch (needs only y)
    pool_k<<<dim3(1024), blk, 0, stream>>>(yb, pooled);
    se_k<<<dim3(4), blk, 0, stream>>>(pooled, r1w, r1b, rbng, rbnb, rbnm, rbnv,
                                      r2w, r2b, yrb);

    // left branch
    conv1x1_k<1><<<dim3(64, 4, 4), blk, 0, stream>>>(yb, l1w, l1b, t1, 256, 256,
        lbn1g, lbn1b, lbn1m, lbn1v, nullptr, nullptr);
    conv3_k<<<dim3(4, 64, 4), blk, 0, stream>>>(t1, l2w, l2b,
        lbn2g, lbn2b, lbn2m, lbn2v, t2);
    // l3 + final fusion: out = feat * sigmoid(relu(bn(l3(t2))) + yr)
    conv1x1_k<3><<<dim3(64, 4, 4), blk, 0, stream>>>(t2, l3w, l3b, out, 256, 256,
        lbn3g, lbn3b, lbn3m, lbn3v, feat, yrb);
}

// Round 3
// 554.639 us; speedup vs baseline: 3.2942x; 3.2942x over previous
//
#include <hip/hip_runtime.h>
#include <math.h>

#define NPIX 4096
#define EPSBN 1e-5f

typedef __attribute__((ext_vector_type(8))) short bf16x8;
typedef __attribute__((ext_vector_type(4))) float f32x4;

__device__ __forceinline__ float sigmoidf_(float x) { return 1.0f / (1.0f + expf(-x)); }

__device__ __forceinline__ short f2bf(float f) {
    unsigned u = __float_as_uint(f);
    u += 0x7fffu + ((u >> 16) & 1u);
    return (short)(u >> 16);
}
__device__ __forceinline__ float bf2f(short s) {
    return __uint_as_float(((unsigned)(unsigned short)s) << 16);
}

__device__ __forceinline__ void gl_lds16(const short* g, short* l) {
    __builtin_amdgcn_global_load_lds(
        (const __attribute__((address_space(1))) void*)g,
        (__attribute__((address_space(3))) void*)l, 16, 0, 0);
}

// ---------------------------------------------------------------------------
// Universal bf16 GEMM-BT:  C = epi( A[M][K] * B[N][K]^T )
// 128x128 tile, 4 waves, mfma_f32_16x16x32_bf16, global_load_lds w/ swizzle.
// EPI 0: energy   -> fp32 E[row*4096+col]
// EPI 1: qkT      -> hi/lo split into qbuf [qh qh ql] / kbuf [kh kl kh]
// EPI 2: v        -> bf16 v[b][row][n], bias[row], b=col>>12, n=col&4095
// EPI 3: gate/y   -> yT bf16 = feat * sigmoid(relu(bn(acc+bias)))  (per col)
// EPI 4: l1->pad  -> relu(bn) bf16 at padded row
// EPI 5: conv3    -> A addressed via padded-image row map + tap offsets
// EPI 6: final    -> fp32 out = feat * sigmoid(relu(bn)+yr)   (bn per row)
// EPI 7: featsplit-> fp32 partial slice per blockIdx.z
// ---------------------------------------------------------------------------
template <int EPI>
__global__ __launch_bounds__(256) void gbt_k(
    const short* __restrict__ A, int lda,
    const short* __restrict__ B, int ldb,
    void* __restrict__ Cv, void* __restrict__ Cv2, int Ktot,
    const float* __restrict__ bias, const float* __restrict__ bias2,
    const float* __restrict__ bng, const float* __restrict__ bnb,
    const float* __restrict__ bnm, const float* __restrict__ bnv,
    const short* __restrict__ aux, const float* __restrict__ yrp)
{
    __shared__ alignas(16) short lsA[128 * 32];
    __shared__ alignas(16) short lsB[128 * 32];

    const int tid = threadIdx.x;
    const int l = tid & 63;
    const int wv = tid >> 6;
    const int wm = wv >> 1, wn = wv & 1;
    const int m0 = blockIdx.y * 128;
    const int n0 = blockIdx.x * 128;

    int kb = 0;
    if (EPI == 7) kb = blockIdx.z * 1024;

    // ---- staging geometry (2 insts per wave per operand) ----
    const int r0 = wv * 32 + (l >> 2);
    const int r1 = r0 + 16;
    const int sl = l & 3;
    const int sd0 = sl ^ ((r0 >> 1) & 3);
    const int sd1 = sl ^ ((r1 >> 1) & 3);

    const short *arow0, *arow1;
    if (EPI == 5) {
        int g0 = m0 + r0, g1 = m0 + r1;
        int p0 = (g0 >> 12) * 4356 + (((g0 & 4095) >> 6) + 1) * 66 + ((g0 & 63) + 1);
        int p1 = (g1 >> 12) * 4356 + (((g1 & 4095) >> 6) + 1) * 66 + ((g1 & 63) + 1);
        arow0 = A + (size_t)p0 * 256 + (sd0 << 3);
        arow1 = A + (size_t)p1 * 256 + (sd1 << 3);
    } else {
        arow0 = A + (size_t)(m0 + r0) * lda + kb + (sd0 << 3);
        arow1 = A + (size_t)(m0 + r1) * lda + kb + (sd1 << 3);
    }
    const short* brow0;
    const short* brow1;
    if (EPI == 5) {
        brow0 = B + (size_t)(n0 + r0) * 256 + (sd0 << 3);
        brow1 = B + (size_t)(n0 + r1) * 256 + (sd1 << 3);
    } else {
        brow0 = B + (size_t)(n0 + r0) * ldb + kb + (sd0 << 3);
        brow1 = B + (size_t)(n0 + r1) * ldb + kb + (sd1 << 3);
    }

    short* ldsA0 = lsA + wv * 1024;
    short* ldsA1 = lsA + wv * 1024 + 512;
    short* ldsB0 = lsB + wv * 1024;
    short* ldsB1 = lsB + wv * 1024 + 512;

    // ---- fragment read offsets (bytes, constant over K) ----
    const int ks = l >> 4;
    const int lc = l & 15;
    int aoff[4], boff[4];
#pragma unroll
    for (int f = 0; f < 4; ++f) {
        int ra = wm * 64 + f * 16 + lc;
        aoff[f] = ra * 64 + ((ks ^ ((ra >> 1) & 3)) << 4);
        int rb = wn * 64 + f * 16 + lc;
        boff[f] = rb * 64 + ((ks ^ ((rb >> 1) & 3)) << 4);
    }

    f32x4 acc[4][4] = {};

    for (int k0 = 0; k0 < Ktot; k0 += 32) {
        const short *pa0, *pa1, *pb0, *pb1;
        if (EPI == 5) {
            int t = k0 >> 8;
            int ci0 = k0 & 255;
            int eA = ((t / 3) * 66 + (t % 3) - 67) * 256 + ci0;
            int eB = t * 65536 + ci0;
            pa0 = arow0 + eA; pa1 = arow1 + eA;
            pb0 = brow0 + eB; pb1 = brow1 + eB;
        } else {
            pa0 = arow0 + k0; pa1 = arow1 + k0;
            pb0 = brow0 + k0; pb1 = brow1 + k0;
        }
        gl_lds16(pa0, ldsA0);
        gl_lds16(pa1, ldsA1);
        gl_lds16(pb0, ldsB0);
        gl_lds16(pb1, ldsB1);
        __syncthreads();
        bf16x8 af[4], bfr[4];
#pragma unroll
        for (int f = 0; f < 4; ++f) {
            af[f]  = *(const bf16x8*)((const char*)lsA + aoff[f]);
            bfr[f] = *(const bf16x8*)((const char*)lsB + boff[f]);
        }
#pragma unroll
        for (int i = 0; i < 4; ++i)
#pragma unroll
            for (int j = 0; j < 4; ++j)
                acc[i][j] = __builtin_amdgcn_mfma_f32_16x16x32_bf16(af[i], bfr[j], acc[i][j], 0, 0, 0);
        __syncthreads();
    }

    // ---- epilogue ----
    const int lr = (l >> 4) << 2;
#pragma unroll
    for (int i = 0; i < 4; ++i) {
        const int rowl = wm * 64 + i * 16 + lr;
#pragma unroll
        for (int j = 0; j < 4; ++j) {
            const int coll = n0 + wn * 64 + j * 16 + lc;

            float sc = 0.f, tc = 0.f, bi = 0.f;
            if constexpr (EPI == 1) {
                bi = (coll < 128) ? bias[coll] : bias2[coll - 128];
            } else if constexpr (EPI == 3 || EPI == 4 || EPI == 5) {
                sc = bng[coll] * rsqrtf(bnv[coll] + EPSBN);
                tc = bnb[coll] - bnm[coll] * sc;
                bi = bias[coll];
            }

#pragma unroll
            for (int r = 0; r < 4; ++r) {
                const int row = m0 + rowl + r;
                float vvv = acc[i][j][r];
                if constexpr (EPI == 0) {
                    ((float*)Cv)[(size_t)row * 4096 + coll] = vvv;
                } else if constexpr (EPI == 1) {
                    float val = vvv + bi;
                    short hi = f2bf(val);
                    short lo = f2bf(val - bf2f(hi));
                    size_t rb = (size_t)row * 384;
                    if (coll < 128) {
                        short* qb_ = (short*)Cv;
                        qb_[rb + coll] = hi;
                        qb_[rb + 128 + coll] = hi;
                        qb_[rb + 256 + coll] = lo;
                    } else {
                        short* kb_ = (short*)Cv2;
                        int c = coll - 128;
                        kb_[rb + c] = hi;
                        kb_[rb + 128 + c] = lo;
                        kb_[rb + 256 + c] = hi;
                    }
                } else if constexpr (EPI == 2) {
                    int bb = coll >> 12;
                    ((short*)Cv)[((size_t)bb * 256 + row) * 4096 + (coll & 4095)] = f2bf(vvv + bias[row]);
                } else if constexpr (EPI == 3) {
                    float g = sigmoidf_(fmaxf(sc * (vvv + bi) + tc, 0.f));
                    float fv = bf2f(aux[(size_t)row * 256 + coll]);
                    ((short*)Cv)[(size_t)row * 256 + coll] = f2bf(fv * g);
                } else if constexpr (EPI == 4) {
                    float rv = fmaxf(sc * (vvv + bi) + tc, 0.f);
                    int bb = row >> 12, n = row & 4095;
                    int pr = bb * 4356 + ((n >> 6) + 1) * 66 + (n & 63) + 1;
                    ((short*)Cv)[(size_t)pr * 256 + coll] = f2bf(rv);
                } else if constexpr (EPI == 5) {
                    float rv = fmaxf(sc * (vvv + bi) + tc, 0.f);
                    ((short*)Cv)[(size_t)row * 256 + coll] = f2bf(rv);
                } else if constexpr (EPI == 6) {
                    float s6 = bng[row] * rsqrtf(bnv[row] + EPSBN);
                    float t6 = bnb[row] - bnm[row] * s6;
                    int bb = coll >> 12;
                    float yl = fmaxf(s6 * (vvv + bias[row]) + t6, 0.f);
                    float sg = sigmoidf_(yl + yrp[bb * 256 + row]);
                    float fv = bf2f(aux[(size_t)coll * 256 + row]);
                    ((float*)Cv)[((size_t)bb * 256 + row) * 4096 + (coll & 4095)] = fv * sg;
                } else if constexpr (EPI == 7) {
                    float* Cs = (float*)Cv + (size_t)blockIdx.z * 1048576;
                    Cs[(size_t)row * 256 + coll] = vvv;
                }
            }
        }
    }
}

// ---------------------------------------------------------------------------
// x [B][256][4096] fp32 -> xT3 [(b,n)][768] bf16 hi/lo: [xh(256) xh(256) xl(256)]
// ---------------------------------------------------------------------------
__global__ __launch_bounds__(256) void transpose_x_k(const float* __restrict__ x,
                                                     short* __restrict__ xT3)
{
    __shared__ float t[64][65];
    const int b = blockIdx.z, c0 = blockIdx.y * 64, n0 = blockIdx.x * 64;
    const int tid = threadIdx.x;
#pragma unroll
    for (int rep = 0; rep < 16; ++rep) {
        int idx = tid + rep * 256;
        int i = idx >> 6, j = idx & 63;
        t[i][j] = x[((size_t)(b * 256 + c0 + i)) * NPIX + n0 + j];
    }
    __syncthreads();
#pragma unroll
    for (int rep = 0; rep < 16; ++rep) {
        int idx = tid + rep * 256;
        int i = idx >> 6, j = idx & 63;
        float v = t[j][i];
        short hi = f2bf(v);
        short lo = f2bf(v - bf2f(hi));
        size_t rb = ((size_t)(b * NPIX + n0 + i)) * 768;
        xT3[rb + c0 + j] = hi;
        xT3[rb + 256 + c0 + j] = hi;
        xT3[rb + 512 + c0 + j] = lo;
    }
}

// src [rows][256] fp32 -> dst [rows][768]: [wh(256) wl(256) wh(256)]
__global__ __launch_bounds__(256) void cvt_hilo3_k(const float* __restrict__ src,
                                                   short* __restrict__ dst)
{
    int idx = blockIdx.x * 256 + threadIdx.x;
    int o = idx >> 8, c = idx & 255;
    float v = src[idx];
    short hi = f2bf(v);
    short lo = f2bf(v - bf2f(hi));
    size_t rb = (size_t)o * 768;
    dst[rb + c] = hi;
    dst[rb + 256 + c] = lo;
    dst[rb + 512 + c] = hi;
}

__global__ __launch_bounds__(256) void cvt_k(const float* __restrict__ s,
                                             short* __restrict__ d, int n)
{
    int i = blockIdx.x * 256 + threadIdx.x;
    if (i < n) d[i] = f2bf(s[i]);
}

// w2[t][co][ci] = l2w[co][ci][t]
__global__ __launch_bounds__(256) void permw2_k(const float* __restrict__ l2w,
                                                short* __restrict__ w2)
{
    int idx = blockIdx.x * 256 + threadIdx.x;
    int t = idx >> 16;
    int rem = idx & 65535;
    int co = rem >> 8, ci = rem & 255;
    w2[idx] = f2bf(l2w[((size_t)(co * 256 + ci)) * 9 + t]);
}

// ---------------------------------------------------------------------------
// Row softmax over 4096 fp32, writes bf16 probs in-place (row stride 8192 bf16)
// ---------------------------------------------------------------------------
__global__ __launch_bounds__(256) void softmax_k(float* __restrict__ e)
{
    const size_t row = blockIdx.x;
    float* r = e + row * NPIX;
    short* arow = (short*)e + row * 8192;
    const int tid = threadIdx.x;
    float vals[16];
    float mx = -1e30f;
#pragma unroll
    for (int i = 0; i < 16; ++i) {
        vals[i] = r[tid + (i << 8)];
        mx = fmaxf(mx, vals[i]);
    }
#pragma unroll
    for (int o = 32; o; o >>= 1) mx = fmaxf(mx, __shfl_xor(mx, o));
    __shared__ float sm[4], ss[4];
    if ((tid & 63) == 0) sm[tid >> 6] = mx;
    __syncthreads();
    mx = fmaxf(fmaxf(sm[0], sm[1]), fmaxf(sm[2], sm[3]));
    float s = 0.f;
#pragma unroll
    for (int i = 0; i < 16; ++i) {
        vals[i] = expf(vals[i] - mx);
        s += vals[i];
    }
#pragma unroll
    for (int o = 32; o; o >>= 1) s += __shfl_xor(s, o);
    if ((tid & 63) == 0) ss[tid >> 6] = s;
    __syncthreads();
    s = ss[0] + ss[1] + ss[2] + ss[3];
    float inv = 1.0f / s;
#pragma unroll
    for (int i = 0; i < 16; ++i) arow[tid + (i << 8)] = f2bf(vals[i] * inv);
}

// sum 4 split-K partials -> bf16
__global__ __launch_bounds__(256) void feat_reduce_k(const float* __restrict__ p,
                                                     short* __restrict__ o)
{
    size_t i = (size_t)blockIdx.x * 256 + threadIdx.x;
    float v = p[i] + p[i + 1048576] + p[i + 2097152] + p[i + 3145728];
    o[i] = f2bf(v);
}

// pooled[b*256+c] = mean_n yT[(b,n)][c]
__global__ __launch_bounds__(256) void pool_k(const short* __restrict__ yT,
                                              float* __restrict__ pooled)
{
    const int b = blockIdx.x >> 2, cg = (blockIdx.x & 3) * 64;
    const int tid = threadIdx.x;
    const int c = cg + (tid & 63), ph = tid >> 6;
    float s = 0.f;
    for (int n = ph * 4; n < NPIX; n += 16) {
        size_t base = ((size_t)(b * NPIX + n)) * 256 + c;
        s += bf2f(yT[base]) + bf2f(yT[base + 256]) +
             bf2f(yT[base + 512]) + bf2f(yT[base + 768]);
    }
    __shared__ float ls[4][64];
    ls[ph][tid & 63] = s;
    __syncthreads();
    if (ph == 0)
        pooled[b * 256 + c] =
            (ls[0][tid & 63] + ls[1][tid & 63] + ls[2][tid & 63] + ls[3][tid & 63]) * (1.0f / NPIX);
}

__global__ __launch_bounds__(256) void se_k(
    const float* __restrict__ pooled,
    const float* __restrict__ r1w, const float* __restrict__ r1b,
    const float* __restrict__ g, const float* __restrict__ bb,
    const float* __restrict__ m, const float* __restrict__ vv,
    const float* __restrict__ r2w, const float* __restrict__ r2b,
    float* __restrict__ yr)
{
    const int b = blockIdx.x;
    const int tid = threadIdx.x;
    __shared__ float p[256], hbuf[128];
    p[tid] = pooled[b * 256 + tid];
    __syncthreads();
    if (tid < 128) {
        float a = r1b[tid];
        for (int ci = 0; ci < 256; ++ci) a = fmaf(r1w[tid * 256 + ci], p[ci], a);
        float s = g[tid] * rsqrtf(vv[tid] + EPSBN);
        float t = bb[tid] - m[tid] * s;
        hbuf[tid] = fmaxf(s * a + t, 0.f);
    }
    __syncthreads();
    float a = r2b[tid];
    for (int c2 = 0; c2 < 128; ++c2) a = fmaf(r2w[tid * 128 + c2], hbuf[c2], a);
    yr[b * 256 + tid] = a;
}

// ---------------------------------------------------------------------------
extern "C" void kernel_launch(void* const* d_in, const int* in_sizes, int n_in,
                              void* d_out, int out_size, void* d_ws, size_t ws_size,
                              hipStream_t stream)
{
    const float* x    = (const float*)d_in[0];
    const float* wq   = (const float*)d_in[1];
    const float* bq   = (const float*)d_in[2];
    const float* wk   = (const float*)d_in[3];
    const float* bk   = (const float*)d_in[4];
    const float* wvp  = (const float*)d_in[5];
    const float* bv   = (const float*)d_in[6];
    const float* d1w  = (const float*)d_in[7];
    const float* d1b  = (const float*)d_in[8];
    const float* bn1g = (const float*)d_in[9];
    const float* bn1b = (const float*)d_in[10];
    const float* bn1m = (const float*)d_in[11];
    const float* bn1v = (const float*)d_in[12];
    const float* lbn1g = (const float*)d_in[13];
    const float* lbn1b = (const float*)d_in[14];
    const float* lbn1m = (const float*)d_in[15];
    const float* lbn1v = (const float*)d_in[16];
    const float* lbn2g = (const float*)d_in[17];
    const float* lbn2b = (const float*)d_in[18];
    const float* lbn2m = (const float*)d_in[19];
    const float* lbn2v = (const float*)d_in[20];
    const float* lbn3g = (const float*)d_in[21];
    const float* lbn3b = (const float*)d_in[22];
    const float* lbn3m = (const float*)d_in[23];
    const float* lbn3v = (const float*)d_in[24];
    const float* l1w  = (const float*)d_in[25];
    const float* l1b  = (const float*)d_in[26];
    const float* l2w  = (const float*)d_in[27];
    const float* l2b  = (const float*)d_in[28];
    const float* l3w  = (const float*)d_in[29];
    const float* l3b  = (const float*)d_in[30];
    const float* r1w  = (const float*)d_in[31];
    const float* r1b  = (const float*)d_in[32];
    const float* rbng = (const float*)d_in[33];
    const float* rbnb = (const float*)d_in[34];
    const float* rbnm = (const float*)d_in[35];
    const float* rbnv = (const float*)d_in[36];
    const float* r2w  = (const float*)d_in[37];
    const float* r2b  = (const float*)d_in[38];

    float* out = (float*)d_out;
    char* wsb = (char*)d_ws;

    // ---- workspace layout (peak ~131 MB; round-1 proved >=144 MB usable) ----
    short* xT3  = (short*)(wsb);                    // [16384][768]  24 MB (dead after projections)
    float* fpart= (float*)(wsb);                    // 16 MB overlay during attn loop
    short* qbuf = (short*)(wsb + (24ull << 20));    // [16384][384]  12 MB
    short* kbuf = (short*)(wsb + (36ull << 20));    // [16384][384]  12 MB
    short* vbuf = (short*)(wsb + (48ull << 20));    // [4][256][4096] 8 MB
    float* E    = (float*)(wsb + (56ull << 20));    // [4096][4096]  64 MB
    short* yT   = (short*)(wsb + (56ull << 20));    // overlay E post-attn, 8 MB
    short* featT= (short*)(wsb + (120ull << 20));   // [16384][256]   8 MB
    short* t1pad= (short*)(wsb + (24ull << 20));    // overlay qbuf post-attn, 8.51 MB
    short* t2T  = (short*)(wsb + (36ull << 20));    // overlay kbuf post-attn, 8 MB
    float* pooled = (float*)(wsb + (128ull << 20)); // 1 KB
    float* yrb  = pooled + 1024;                    // 1 KB
    short* wqk3 = (short*)(wsb + (129ull << 20));   // [256][768] 384 KB
    short* wvb  = wqk3 + 196608;                    // 128 KB
    short* d1wb = wvb + 65536;
    short* l1wb = d1wb + 65536;
    short* l3wb = l1wb + 65536;
    short* w2b  = l3wb + 65536;                     // [9][256][256] 1.125 MB

    dim3 blk(256);

    // ---- setup: transpose/convert ----
    transpose_x_k<<<dim3(64, 4, 4), blk, 0, stream>>>(x, xT3);
    cvt_hilo3_k<<<128, blk, 0, stream>>>(wq, wqk3);
    cvt_hilo3_k<<<128, blk, 0, stream>>>(wk, wqk3 + (size_t)128 * 768);
    cvt_k<<<256, blk, 0, stream>>>(wvp, wvb, 65536);
    cvt_k<<<256, blk, 0, stream>>>(d1w, d1wb, 65536);
    cvt_k<<<256, blk, 0, stream>>>(l1w, l1wb, 65536);
    cvt_k<<<256, blk, 0, stream>>>(l3w, l3wb, 65536);
    permw2_k<<<2304, blk, 0, stream>>>(l2w, w2b);

    // ---- projections ----
    // q/k: K=768 3-term hi/lo ([xh xh xl]·[wh wl wh]) -> hi/lo split outputs
    gbt_k<1><<<dim3(2, 128), blk, 0, stream>>>(xT3, 768, wqk3, 768, qbuf, kbuf, 768,
        bq, bk, nullptr, nullptr, nullptr, nullptr, nullptr, nullptr);
    // v: plain bf16, B = hi half of xT3
    gbt_k<2><<<dim3(128, 2), blk, 0, stream>>>(wvb, 256, xT3, 768, vbuf, nullptr, 256,
        bv, nullptr, nullptr, nullptr, nullptr, nullptr, nullptr, nullptr);

    // ---- attention, per batch ----
    for (int b = 0; b < 4; ++b) {
        const short* qp = qbuf + (size_t)b * 4096 * 384;
        const short* kp = kbuf + (size_t)b * 4096 * 384;
        gbt_k<0><<<dim3(32, 32), blk, 0, stream>>>(qp, 384, kp, 384, E, nullptr, 384,
            nullptr, nullptr, nullptr, nullptr, nullptr, nullptr, nullptr, nullptr);
        softmax_k<<<4096, blk, 0, stream>>>(E);
        gbt_k<7><<<dim3(2, 32, 4), blk, 0, stream>>>((const short*)E, 8192,
            vbuf + (size_t)b * 1048576, 4096, fpart, nullptr, 1024,
            nullptr, nullptr, nullptr, nullptr, nullptr, nullptr, nullptr, nullptr);
        feat_reduce_k<<<4096, blk, 0, stream>>>(fpart, featT + (size_t)b * 1048576);
    }

    // ---- gate: yT = feat * sigmoid(relu(bn1(d1(feat)))) ----
    gbt_k<3><<<dim3(2, 128), blk, 0, stream>>>(featT, 256, d1wb, 256, yT, nullptr, 256,
        d1b, nullptr, bn1g, bn1b, bn1m, bn1v, featT, nullptr);

    hipMemsetAsync(t1pad, 0, (size_t)4 * 4356 * 256 * 2, stream);

    // ---- SE branch ----
    pool_k<<<16, blk, 0, stream>>>(yT, pooled);
    se_k<<<4, blk, 0, stream>>>(pooled, r1w, r1b, rbng, rbnb, rbnm, rbnv, r2w, r2b, yrb);

    // ---- left branch ----
    gbt_k<4><<<dim3(2, 128), blk, 0, stream>>>(yT, 256, l1wb, 256, t1pad, nullptr, 256,
        l1b, nullptr, lbn1g, lbn1b, lbn1m, lbn1v, nullptr, nullptr);
    gbt_k<5><<<dim3(2, 128), blk, 0, stream>>>(t1pad, 256, w2b, 256, t2T, nullptr, 2304,
        l2b, nullptr, lbn2g, lbn2b, lbn2m, lbn2v, nullptr, nullptr);

    // ---- final: out = feat * sigmoid(relu(bn3(l3(t2))) + yr) ----
    gbt_k<6><<<dim3(128, 2), blk, 0, stream>>>(l3wb, 256, t2T, 256, out, nullptr, 256,
        l3b, nullptr, lbn3g, lbn3b, lbn3m, lbn3v, featT, yrb);
}

// Round 4
// 502.185 us; speedup vs baseline: 3.6383x; 1.1045x over previous
//
#include <hip/hip_runtime.h>
#include <math.h>

#define NPIX 4096
#define EPSBN 1e-5f

typedef __attribute__((ext_vector_type(8))) short bf16x8;
typedef __attribute__((ext_vector_type(4))) float f32x4;

__device__ __forceinline__ float sigmoidf_(float x) { return 1.0f / (1.0f + expf(-x)); }

__device__ __forceinline__ short f2bf(float f) {
    unsigned u = __float_as_uint(f);
    u += 0x7fffu + ((u >> 16) & 1u);
    return (short)(u >> 16);
}
__device__ __forceinline__ float bf2f(short s) {
    return __uint_as_float(((unsigned)(unsigned short)s) << 16);
}

__device__ __forceinline__ void gl_lds16(const short* g, short* l) {
    __builtin_amdgcn_global_load_lds(
        (const __attribute__((address_space(1))) void*)g,
        (__attribute__((address_space(3))) void*)l, 16, 0, 0);
}

// ---------------------------------------------------------------------------
// Universal bf16 GEMM-BT:  C = epi( A[M][K] * B[N][K]^T )
// 128x128 tile, 4 waves, mfma_f32_16x16x32_bf16, global_load_lds w/ swizzle.
// EPI 0: energy   -> fp32 E[row*4096+col]
// EPI 1: qkT      -> hi/lo split into qbuf [qh qh ql] / kbuf [kh kl kh]
// EPI 2: v        -> bf16 v[b][row][n], bias[row], b=col>>12, n=col&4095
// EPI 3: gate/y   -> yT bf16 = feat * sigmoid(relu(bn(acc+bias)))  (per col)
// EPI 4: l1->pad  -> relu(bn) bf16 at padded row
// EPI 5: conv3    -> A addressed via padded-image row map + tap offsets
// EPI 6: final    -> fp32 out = feat * sigmoid(relu(bn)+yr)   (bn per row)
// EPI 7: featsplit-> fp32 partial slice per blockIdx.z
// ---------------------------------------------------------------------------
template <int EPI>
__global__ __launch_bounds__(256) void gbt_k(
    const short* __restrict__ A, int lda,
    const short* __restrict__ B, int ldb,
    void* __restrict__ Cv, void* __restrict__ Cv2, int Ktot,
    const float* __restrict__ bias, const float* __restrict__ bias2,
    const float* __restrict__ bng, const float* __restrict__ bnb,
    const float* __restrict__ bnm, const float* __restrict__ bnv,
    const short* __restrict__ aux, const float* __restrict__ yrp)
{
    __shared__ alignas(16) short lsA[128 * 32];
    __shared__ alignas(16) short lsB[128 * 32];

    const int tid = threadIdx.x;
    const int l = tid & 63;
    const int wv = tid >> 6;
    const int wm = wv >> 1, wn = wv & 1;
    const int m0 = blockIdx.y * 128;
    const int n0 = blockIdx.x * 128;

    int kb = 0;
    if (EPI == 7) kb = blockIdx.z * 1024;

    // ---- staging geometry (2 insts per wave per operand) ----
    const int r0 = wv * 32 + (l >> 2);
    const int r1 = r0 + 16;
    const int sl = l & 3;
    const int sd0 = sl ^ ((r0 >> 1) & 3);
    const int sd1 = sl ^ ((r1 >> 1) & 3);

    const short *arow0, *arow1;
    if (EPI == 5) {
        int g0 = m0 + r0, g1 = m0 + r1;
        int p0 = (g0 >> 12) * 4356 + (((g0 & 4095) >> 6) + 1) * 66 + ((g0 & 63) + 1);
        int p1 = (g1 >> 12) * 4356 + (((g1 & 4095) >> 6) + 1) * 66 + ((g1 & 63) + 1);
        arow0 = A + (size_t)p0 * 256 + (sd0 << 3);
        arow1 = A + (size_t)p1 * 256 + (sd1 << 3);
    } else {
        arow0 = A + (size_t)(m0 + r0) * lda + kb + (sd0 << 3);
        arow1 = A + (size_t)(m0 + r1) * lda + kb + (sd1 << 3);
    }
    const short* brow0;
    const short* brow1;
    if (EPI == 5) {
        brow0 = B + (size_t)(n0 + r0) * 256 + (sd0 << 3);
        brow1 = B + (size_t)(n0 + r1) * 256 + (sd1 << 3);
    } else {
        brow0 = B + (size_t)(n0 + r0) * ldb + kb + (sd0 << 3);
        brow1 = B + (size_t)(n0 + r1) * ldb + kb + (sd1 << 3);
    }

    short* ldsA0 = lsA + wv * 1024;
    short* ldsA1 = lsA + wv * 1024 + 512;
    short* ldsB0 = lsB + wv * 1024;
    short* ldsB1 = lsB + wv * 1024 + 512;

    // ---- fragment read offsets (bytes, constant over K) ----
    const int ks = l >> 4;
    const int lc = l & 15;
    int aoff[4], boff[4];
#pragma unroll
    for (int f = 0; f < 4; ++f) {
        int ra = wm * 64 + f * 16 + lc;
        aoff[f] = ra * 64 + ((ks ^ ((ra >> 1) & 3)) << 4);
        int rb = wn * 64 + f * 16 + lc;
        boff[f] = rb * 64 + ((ks ^ ((rb >> 1) & 3)) << 4);
    }

    f32x4 acc[4][4] = {};

    for (int k0 = 0; k0 < Ktot; k0 += 32) {
        const short *pa0, *pa1, *pb0, *pb1;
        if (EPI == 5) {
            int t = k0 >> 8;
            int ci0 = k0 & 255;
            int eA = ((t / 3) * 66 + (t % 3) - 67) * 256 + ci0;
            int eB = t * 65536 + ci0;
            pa0 = arow0 + eA; pa1 = arow1 + eA;
            pb0 = brow0 + eB; pb1 = brow1 + eB;
        } else {
            pa0 = arow0 + k0; pa1 = arow1 + k0;
            pb0 = brow0 + k0; pb1 = brow1 + k0;
        }
        gl_lds16(pa0, ldsA0);
        gl_lds16(pa1, ldsA1);
        gl_lds16(pb0, ldsB0);
        gl_lds16(pb1, ldsB1);
        __syncthreads();
        bf16x8 af[4], bfr[4];
#pragma unroll
        for (int f = 0; f < 4; ++f) {
            af[f]  = *(const bf16x8*)((const char*)lsA + aoff[f]);
            bfr[f] = *(const bf16x8*)((const char*)lsB + boff[f]);
        }
#pragma unroll
        for (int i = 0; i < 4; ++i)
#pragma unroll
            for (int j = 0; j < 4; ++j)
                acc[i][j] = __builtin_amdgcn_mfma_f32_16x16x32_bf16(af[i], bfr[j], acc[i][j], 0, 0, 0);
        __syncthreads();
    }

    // ---- epilogue ----
    const int lr = (l >> 4) << 2;
#pragma unroll
    for (int i = 0; i < 4; ++i) {
        const int rowl = wm * 64 + i * 16 + lr;
#pragma unroll
        for (int j = 0; j < 4; ++j) {
            const int coll = n0 + wn * 64 + j * 16 + lc;

            float sc = 0.f, tc = 0.f, bi = 0.f;
            if constexpr (EPI == 1) {
                bi = (coll < 128) ? bias[coll] : bias2[coll - 128];
            } else if constexpr (EPI == 3 || EPI == 4 || EPI == 5) {
                sc = bng[coll] * rsqrtf(bnv[coll] + EPSBN);
                tc = bnb[coll] - bnm[coll] * sc;
                bi = bias[coll];
            }

#pragma unroll
            for (int r = 0; r < 4; ++r) {
                const int row = m0 + rowl + r;
                float vvv = acc[i][j][r];
                if constexpr (EPI == 0) {
                    ((float*)Cv)[(size_t)row * 4096 + coll] = vvv;
                } else if constexpr (EPI == 1) {
                    float val = vvv + bi;
                    short hi = f2bf(val);
                    short lo = f2bf(val - bf2f(hi));
                    size_t rb = (size_t)row * 384;
                    if (coll < 128) {
                        short* qb_ = (short*)Cv;
                        qb_[rb + coll] = hi;
                        qb_[rb + 128 + coll] = hi;
                        qb_[rb + 256 + coll] = lo;
                    } else {
                        short* kb_ = (short*)Cv2;
                        int c = coll - 128;
                        kb_[rb + c] = hi;
                        kb_[rb + 128 + c] = lo;
                        kb_[rb + 256 + c] = hi;
                    }
                } else if constexpr (EPI == 2) {
                    int bb = coll >> 12;
                    ((short*)Cv)[((size_t)bb * 256 + row) * 4096 + (coll & 4095)] = f2bf(vvv + bias[row]);
                } else if constexpr (EPI == 3) {
                    float g = sigmoidf_(fmaxf(sc * (vvv + bi) + tc, 0.f));
                    float fv = bf2f(aux[(size_t)row * 256 + coll]);
                    ((short*)Cv)[(size_t)row * 256 + coll] = f2bf(fv * g);
                } else if constexpr (EPI == 4) {
                    float rv = fmaxf(sc * (vvv + bi) + tc, 0.f);
                    int bb = row >> 12, n = row & 4095;
                    int pr = bb * 4356 + ((n >> 6) + 1) * 66 + (n & 63) + 1;
                    ((short*)Cv)[(size_t)pr * 256 + coll] = f2bf(rv);
                } else if constexpr (EPI == 5) {
                    float rv = fmaxf(sc * (vvv + bi) + tc, 0.f);
                    ((short*)Cv)[(size_t)row * 256 + coll] = f2bf(rv);
                } else if constexpr (EPI == 6) {
                    float s6 = bng[row] * rsqrtf(bnv[row] + EPSBN);
                    float t6 = bnb[row] - bnm[row] * s6;
                    int bb = coll >> 12;
                    float yl = fmaxf(s6 * (vvv + bias[row]) + t6, 0.f);
                    float sg = sigmoidf_(yl + yrp[bb * 256 + row]);
                    float fv = bf2f(aux[(size_t)coll * 256 + row]);
                    ((float*)Cv)[((size_t)bb * 256 + row) * 4096 + (coll & 4095)] = fv * sg;
                } else if constexpr (EPI == 7) {
                    float* Cs = (float*)Cv + (size_t)blockIdx.z * 1048576;
                    Cs[(size_t)row * 256 + coll] = vvv;
                }
            }
        }
    }
}

// ---------------------------------------------------------------------------
// x [B][256][4096] fp32 -> xT3 [(b,n)][768] bf16 hi/lo: [xh(256) xh(256) xl(256)]
// ---------------------------------------------------------------------------
__global__ __launch_bounds__(256) void transpose_x_k(const float* __restrict__ x,
                                                     short* __restrict__ xT3)
{
    __shared__ float t[64][65];
    const int b = blockIdx.z, c0 = blockIdx.y * 64, n0 = blockIdx.x * 64;
    const int tid = threadIdx.x;
#pragma unroll
    for (int rep = 0; rep < 16; ++rep) {
        int idx = tid + rep * 256;
        int i = idx >> 6, j = idx & 63;
        t[i][j] = x[((size_t)(b * 256 + c0 + i)) * NPIX + n0 + j];
    }
    __syncthreads();
#pragma unroll
    for (int rep = 0; rep < 16; ++rep) {
        int idx = tid + rep * 256;
        int i = idx >> 6, j = idx & 63;
        float v = t[j][i];
        short hi = f2bf(v);
        short lo = f2bf(v - bf2f(hi));
        size_t rb = ((size_t)(b * NPIX + n0 + i)) * 768;
        xT3[rb + c0 + j] = hi;
        xT3[rb + 256 + c0 + j] = hi;
        xT3[rb + 512 + c0 + j] = lo;
    }
}

// src [rows][256] fp32 -> dst [rows][768]: [wh(256) wl(256) wh(256)]
__global__ __launch_bounds__(256) void cvt_hilo3_k(const float* __restrict__ src,
                                                   short* __restrict__ dst)
{
    int idx = blockIdx.x * 256 + threadIdx.x;
    int o = idx >> 8, c = idx & 255;
    float v = src[idx];
    short hi = f2bf(v);
    short lo = f2bf(v - bf2f(hi));
    size_t rb = (size_t)o * 768;
    dst[rb + c] = hi;
    dst[rb + 256 + c] = lo;
    dst[rb + 512 + c] = hi;
}

__global__ __launch_bounds__(256) void cvt_k(const float* __restrict__ s,
                                             short* __restrict__ d, int n)
{
    int i = blockIdx.x * 256 + threadIdx.x;
    if (i < n) d[i] = f2bf(s[i]);
}

// w2[t][co][ci] = l2w[co][ci][t]
__global__ __launch_bounds__(256) void permw2_k(const float* __restrict__ l2w,
                                                short* __restrict__ w2)
{
    int idx = blockIdx.x * 256 + threadIdx.x;
    int t = idx >> 16;
    int rem = idx & 65535;
    int co = rem >> 8, ci = rem & 255;
    w2[idx] = f2bf(l2w[((size_t)(co * 256 + ci)) * 9 + t]);
}

// ---------------------------------------------------------------------------
// Row softmax over 4096 fp32, writes bf16 probs in-place (row stride 8192 bf16)
// Vectorized: float4 loads, short4 stores.
// ---------------------------------------------------------------------------
__global__ __launch_bounds__(256) void softmax_k(float* __restrict__ e)
{
    const size_t row = blockIdx.x;
    const float4* r4 = (const float4*)(e + row * NPIX);
    short* arow = (short*)e + row * 8192;
    const int tid = threadIdx.x;
    float4 v4[4];
    float mx = -1e30f;
#pragma unroll
    for (int i = 0; i < 4; ++i) {
        v4[i] = r4[tid + (i << 8)];
        mx = fmaxf(mx, fmaxf(fmaxf(v4[i].x, v4[i].y), fmaxf(v4[i].z, v4[i].w)));
    }
#pragma unroll
    for (int o = 32; o; o >>= 1) mx = fmaxf(mx, __shfl_xor(mx, o));
    __shared__ float sm[4], ss[4];
    if ((tid & 63) == 0) sm[tid >> 6] = mx;
    __syncthreads();
    mx = fmaxf(fmaxf(sm[0], sm[1]), fmaxf(sm[2], sm[3]));
    float s = 0.f;
#pragma unroll
    for (int i = 0; i < 4; ++i) {
        float* p = &v4[i].x;
#pragma unroll
        for (int c = 0; c < 4; ++c) {
            p[c] = expf(p[c] - mx);
            s += p[c];
        }
    }
#pragma unroll
    for (int o = 32; o; o >>= 1) s += __shfl_xor(s, o);
    if ((tid & 63) == 0) ss[tid >> 6] = s;
    __syncthreads();
    s = ss[0] + ss[1] + ss[2] + ss[3];
    float inv = 1.0f / s;
#pragma unroll
    for (int i = 0; i < 4; ++i) {
        float* p = &v4[i].x;
        short4 o4;
        o4.x = f2bf(p[0] * inv);
        o4.y = f2bf(p[1] * inv);
        o4.z = f2bf(p[2] * inv);
        o4.w = f2bf(p[3] * inv);
        *(short4*)(arow + ((tid + (i << 8)) << 2)) = o4;
    }
}

// sum 4 split-K partials -> bf16 (vectorized)
__global__ __launch_bounds__(256) void feat_reduce_k(const float* __restrict__ p,
                                                     short* __restrict__ o)
{
    size_t i = ((size_t)blockIdx.x * 256 + threadIdx.x) * 4;
    const float4 a = *(const float4*)(p + i);
    const float4 b = *(const float4*)(p + i + 1048576);
    const float4 c = *(const float4*)(p + i + 2097152);
    const float4 d = *(const float4*)(p + i + 3145728);
    short4 o4;
    o4.x = f2bf(a.x + b.x + c.x + d.x);
    o4.y = f2bf(a.y + b.y + c.y + d.y);
    o4.z = f2bf(a.z + b.z + c.z + d.z);
    o4.w = f2bf(a.w + b.w + c.w + d.w);
    *(short4*)(o + i) = o4;
}

// ---------------------------------------------------------------------------
// Pool stage 1: ppart[((b*4+cg)*16+ns)*64 + cl] = sum over 256 n-rows
// grid (16 ns, 4 cg, 4 b), 256 threads: cl = tid&63, ph = tid>>6
// ---------------------------------------------------------------------------
__global__ __launch_bounds__(256) void pool_s1_k(const short* __restrict__ yT,
                                                 float* __restrict__ ppart)
{
    const int ns = blockIdx.x, cg = blockIdx.y, b = blockIdx.z;
    const int tid = threadIdx.x;
    const int cl = tid & 63, ph = tid >> 6;
    float s = 0.f;
    const int nbase = ns * 256;
    for (int n = ph; n < 256; n += 4)
        s += bf2f(yT[((size_t)(b * NPIX + nbase + n)) * 256 + cg * 64 + cl]);
    __shared__ float ls[4][64];
    ls[ph][cl] = s;
    __syncthreads();
    if (ph == 0)
        ppart[((size_t)(b * 4 + cg) * 16 + ns) * 64 + cl] =
            ls[0][cl] + ls[1][cl] + ls[2][cl] + ls[3][cl];
}

// Pool stage 2: pooled[b*256+c] = (sum over 16 ns partials)/4096
__global__ __launch_bounds__(256) void pool_s2_k(const float* __restrict__ ppart,
                                                 float* __restrict__ pooled)
{
    const int b = blockIdx.x;
    const int c = threadIdx.x;
    const int cg = c >> 6, cl = c & 63;
    float s = 0.f;
#pragma unroll
    for (int ns = 0; ns < 16; ++ns)
        s += ppart[((size_t)(b * 4 + cg) * 16 + ns) * 64 + cl];
    pooled[b * 256 + c] = s * (1.0f / NPIX);
}

__global__ __launch_bounds__(256) void se_k(
    const float* __restrict__ pooled,
    const float* __restrict__ r1w, const float* __restrict__ r1b,
    const float* __restrict__ g, const float* __restrict__ bb,
    const float* __restrict__ m, const float* __restrict__ vv,
    const float* __restrict__ r2w, const float* __restrict__ r2b,
    float* __restrict__ yr)
{
    const int b = blockIdx.x;
    const int tid = threadIdx.x;
    __shared__ float p[256], hbuf[128];
    p[tid] = pooled[b * 256 + tid];
    __syncthreads();
    if (tid < 128) {
        float a = r1b[tid];
        for (int ci = 0; ci < 256; ++ci) a = fmaf(r1w[tid * 256 + ci], p[ci], a);
        float s = g[tid] * rsqrtf(vv[tid] + EPSBN);
        float t = bb[tid] - m[tid] * s;
        hbuf[tid] = fmaxf(s * a + t, 0.f);
    }
    __syncthreads();
    float a = r2b[tid];
    for (int c2 = 0; c2 < 128; ++c2) a = fmaf(r2w[tid * 128 + c2], hbuf[c2], a);
    yr[b * 256 + tid] = a;
}

// ---------------------------------------------------------------------------
extern "C" void kernel_launch(void* const* d_in, const int* in_sizes, int n_in,
                              void* d_out, int out_size, void* d_ws, size_t ws_size,
                              hipStream_t stream)
{
    const float* x    = (const float*)d_in[0];
    const float* wq   = (const float*)d_in[1];
    const float* bq   = (const float*)d_in[2];
    const float* wk   = (const float*)d_in[3];
    const float* bk   = (const float*)d_in[4];
    const float* wvp  = (const float*)d_in[5];
    const float* bv   = (const float*)d_in[6];
    const float* d1w  = (const float*)d_in[7];
    const float* d1b  = (const float*)d_in[8];
    const float* bn1g = (const float*)d_in[9];
    const float* bn1b = (const float*)d_in[10];
    const float* bn1m = (const float*)d_in[11];
    const float* bn1v = (const float*)d_in[12];
    const float* lbn1g = (const float*)d_in[13];
    const float* lbn1b = (const float*)d_in[14];
    const float* lbn1m = (const float*)d_in[15];
    const float* lbn1v = (const float*)d_in[16];
    const float* lbn2g = (const float*)d_in[17];
    const float* lbn2b = (const float*)d_in[18];
    const float* lbn2m = (const float*)d_in[19];
    const float* lbn2v = (const float*)d_in[20];
    const float* lbn3g = (const float*)d_in[21];
    const float* lbn3b = (const float*)d_in[22];
    const float* lbn3m = (const float*)d_in[23];
    const float* lbn3v = (const float*)d_in[24];
    const float* l1w  = (const float*)d_in[25];
    const float* l1b  = (const float*)d_in[26];
    const float* l2w  = (const float*)d_in[27];
    const float* l2b  = (const float*)d_in[28];
    const float* l3w  = (const float*)d_in[29];
    const float* l3b  = (const float*)d_in[30];
    const float* r1w  = (const float*)d_in[31];
    const float* r1b  = (const float*)d_in[32];
    const float* rbng = (const float*)d_in[33];
    const float* rbnb = (const float*)d_in[34];
    const float* rbnm = (const float*)d_in[35];
    const float* rbnv = (const float*)d_in[36];
    const float* r2w  = (const float*)d_in[37];
    const float* r2b  = (const float*)d_in[38];

    float* out = (float*)d_out;
    char* wsb = (char*)d_ws;

    // ---- workspace layout (peak ~131 MB) ----
    short* xT3  = (short*)(wsb);                    // [16384][768]  24 MB (dead after projections)
    float* fpart= (float*)(wsb);                    // 16 MB overlay during attn loop
    short* qbuf = (short*)(wsb + (24ull << 20));    // [16384][384]  12 MB
    short* kbuf = (short*)(wsb + (36ull << 20));    // [16384][384]  12 MB
    short* vbuf = (short*)(wsb + (48ull << 20));    // [4][256][4096] 8 MB
    float* E    = (float*)(wsb + (56ull << 20));    // [4096][4096]  64 MB
    short* yT   = (short*)(wsb + (56ull << 20));    // overlay E post-attn, 8 MB
    short* featT= (short*)(wsb + (120ull << 20));   // [16384][256]   8 MB
    short* t1pad= (short*)(wsb + (24ull << 20));    // overlay qbuf post-attn, 8.51 MB
    short* t2T  = (short*)(wsb + (36ull << 20));    // overlay kbuf post-attn, 8 MB
    float* pooled = (float*)(wsb + (128ull << 20)); // 1 KB
    float* yrb  = pooled + 1024;                    // 1 KB
    float* ppart= yrb + 1024;                       // 64 KB [4][4][16][64]
    short* wqk3 = (short*)(wsb + (129ull << 20));   // [256][768] 384 KB
    short* wvb  = wqk3 + 196608;                    // 128 KB
    short* d1wb = wvb + 65536;
    short* l1wb = d1wb + 65536;
    short* l3wb = l1wb + 65536;
    short* w2b  = l3wb + 65536;                     // [9][256][256] 1.125 MB

    dim3 blk(256);

    // ---- setup: transpose/convert ----
    transpose_x_k<<<dim3(64, 4, 4), blk, 0, stream>>>(x, xT3);
    cvt_hilo3_k<<<128, blk, 0, stream>>>(wq, wqk3);
    cvt_hilo3_k<<<128, blk, 0, stream>>>(wk, wqk3 + (size_t)128 * 768);
    cvt_k<<<256, blk, 0, stream>>>(wvp, wvb, 65536);
    cvt_k<<<256, blk, 0, stream>>>(d1w, d1wb, 65536);
    cvt_k<<<256, blk, 0, stream>>>(l1w, l1wb, 65536);
    cvt_k<<<256, blk, 0, stream>>>(l3w, l3wb, 65536);
    permw2_k<<<2304, blk, 0, stream>>>(l2w, w2b);

    // ---- projections ----
    // q/k: K=768 3-term hi/lo ([xh xh xl]·[wh wl wh]) -> hi/lo split outputs
    gbt_k<1><<<dim3(2, 128), blk, 0, stream>>>(xT3, 768, wqk3, 768, qbuf, kbuf, 768,
        bq, bk, nullptr, nullptr, nullptr, nullptr, nullptr, nullptr);
    // v: plain bf16, B = hi half of xT3
    gbt_k<2><<<dim3(128, 2), blk, 0, stream>>>(wvb, 256, xT3, 768, vbuf, nullptr, 256,
        bv, nullptr, nullptr, nullptr, nullptr, nullptr, nullptr, nullptr);

    // ---- attention, per batch ----
    for (int b = 0; b < 4; ++b) {
        const short* qp = qbuf + (size_t)b * 4096 * 384;
        const short* kp = kbuf + (size_t)b * 4096 * 384;
        gbt_k<0><<<dim3(32, 32), blk, 0, stream>>>(qp, 384, kp, 384, E, nullptr, 384,
            nullptr, nullptr, nullptr, nullptr, nullptr, nullptr, nullptr, nullptr);
        softmax_k<<<4096, blk, 0, stream>>>(E);
        gbt_k<7><<<dim3(2, 32, 4), blk, 0, stream>>>((const short*)E, 8192,
            vbuf + (size_t)b * 1048576, 4096, fpart, nullptr, 1024,
            nullptr, nullptr, nullptr, nullptr, nullptr, nullptr, nullptr, nullptr);
        feat_reduce_k<<<1024, blk, 0, stream>>>(fpart, featT + (size_t)b * 1048576);
    }

    // ---- gate: yT = feat * sigmoid(relu(bn1(d1(feat)))) ----
    gbt_k<3><<<dim3(2, 128), blk, 0, stream>>>(featT, 256, d1wb, 256, yT, nullptr, 256,
        d1b, nullptr, bn1g, bn1b, bn1m, bn1v, featT, nullptr);

    hipMemsetAsync(t1pad, 0, (size_t)4 * 4356 * 256 * 2, stream);

    // ---- SE branch ----
    pool_s1_k<<<dim3(16, 4, 4), blk, 0, stream>>>(yT, ppart);
    pool_s2_k<<<4, blk, 0, stream>>>(ppart, pooled);
    se_k<<<4, blk, 0, stream>>>(pooled, r1w, r1b, rbng, rbnb, rbnm, rbnv, r2w, r2b, yrb);

    // ---- left branch ----
    gbt_k<4><<<dim3(2, 128), blk, 0, stream>>>(yT, 256, l1wb, 256, t1pad, nullptr, 256,
        l1b, nullptr, lbn1g, lbn1b, lbn1m, lbn1v, nullptr, nullptr);
    gbt_k<5><<<dim3(2, 128), blk, 0, stream>>>(t1pad, 256, w2b, 256, t2T, nullptr, 2304,
        l2b, nullptr, lbn2g, lbn2b, lbn2m, lbn2v, nullptr, nullptr);

    // ---- final: out = feat * sigmoid(relu(bn3(l3(t2))) + yr) ----
    gbt_k<6><<<dim3(128, 2), blk, 0, stream>>>(l3wb, 256, t2T, 256, out, nullptr, 256,
        l3b, nullptr, lbn3g, lbn3b, lbn3m, lbn3v, featT, yrb);
}

// Round 5
// 481.857 us; speedup vs baseline: 3.7918x; 1.0422x over previous
//
#include <hip/hip_runtime.h>
#include <math.h>

#define NPIX 4096
#define EPSBN 1e-5f

typedef __attribute__((ext_vector_type(8))) short bf16x8;
typedef __attribute__((ext_vector_type(4))) float f32x4;

__device__ __forceinline__ float sigmoidf_(float x) { return 1.0f / (1.0f + expf(-x)); }

__device__ __forceinline__ short f2bf(float f) {
    unsigned u = __float_as_uint(f);
    u += 0x7fffu + ((u >> 16) & 1u);
    return (short)(u >> 16);
}
__device__ __forceinline__ float bf2f(short s) {
    return __uint_as_float(((unsigned)(unsigned short)s) << 16);
}

__device__ __forceinline__ void gl_lds16(const short* g, short* l) {
    __builtin_amdgcn_global_load_lds(
        (const __attribute__((address_space(1))) void*)g,
        (__attribute__((address_space(3))) void*)l, 16, 0, 0);
}

// ---------------------------------------------------------------------------
// Universal bf16 GEMM-BT:  C = epi( A[M][K] * B[N][K]^T )
// Tile BM x BN (template), 4 waves (each owns BM/2 x BN/2), double-buffered
// LDS with 1-deep prefetch (stage next K-step before computing current).
// EPI 0: energy   -> fp32 E[row*4096+col]
// EPI 1: qkT      -> hi/lo split into qbuf [qh qh ql] / kbuf [kh kl kh]
// EPI 2: v        -> bf16 v[b][row][n], bias[row], b=col>>12, n=col&4095
// EPI 3: gate/y   -> yT bf16 = feat * sigmoid(relu(bn(acc+bias)))  (per col)
// EPI 4: l1->pad  -> relu(bn) bf16 at padded row
// EPI 5: conv3    -> A addressed via padded-image row map + tap offsets
// EPI 6: final    -> fp32 out = feat * sigmoid(relu(bn)+yr)   (bn per row)
// EPI 7: featsplit-> fp32 partial slice per blockIdx.z
// ---------------------------------------------------------------------------
template <int EPI, int BM, int BN>
__global__ __launch_bounds__(256) void gbt_k(
    const short* __restrict__ A, int lda,
    const short* __restrict__ B, int ldb,
    void* __restrict__ Cv, void* __restrict__ Cv2, int Ktot,
    const float* __restrict__ bias, const float* __restrict__ bias2,
    const float* __restrict__ bng, const float* __restrict__ bnb,
    const float* __restrict__ bnm, const float* __restrict__ bnv,
    const short* __restrict__ aux, const float* __restrict__ yrp)
{
    constexpr int FI = BM / 32, FJ = BN / 32;   // frags per wave (M,N)
    constexpr int SA = BM / 64, SB = BN / 64;   // gl_lds segs per wave
    __shared__ alignas(16) short lsA[2 * BM * 32];
    __shared__ alignas(16) short lsB[2 * BN * 32];

    const int tid = threadIdx.x;
    const int l = tid & 63;
    const int wv = tid >> 6;
    const int wm = wv >> 1, wn = wv & 1;
    const int m0 = blockIdx.y * BM;
    const int n0 = blockIdx.x * BN;

    int kb = 0;
    if (EPI == 7) kb = blockIdx.z * 1024;

    // ---- staging base pointers (pre-swizzled global source) ----
    const short* arow[2];
    const short* brow[2];
#pragma unroll
    for (int s = 0; s < SA; ++s) {
        int r = wv * (16 * SA) + s * 16 + (l >> 2);
        int sd = (l & 3) ^ ((r >> 1) & 3);
        if (EPI == 5) {
            int g = m0 + r;
            int p = (g >> 12) * 4356 + (((g & 4095) >> 6) + 1) * 66 + ((g & 63) + 1);
            arow[s] = A + (size_t)p * 256 + (sd << 3);
        } else {
            arow[s] = A + (size_t)(m0 + r) * lda + kb + (sd << 3);
        }
    }
#pragma unroll
    for (int s = 0; s < SB; ++s) {
        int r = wv * (16 * SB) + s * 16 + (l >> 2);
        int sd = (l & 3) ^ ((r >> 1) & 3);
        brow[s] = B + (size_t)(n0 + r) * ldb + (EPI == 5 ? 0 : kb) + (sd << 3);
    }

    // ---- fragment read offsets (bytes, constant over K) ----
    const int ks = l >> 4;
    const int lc = l & 15;
    int aoff[FI], boff[FJ];
#pragma unroll
    for (int f = 0; f < FI; ++f) {
        int ra = wm * (BM / 2) + f * 16 + lc;
        aoff[f] = ra * 64 + ((ks ^ ((ra >> 1) & 3)) << 4);
    }
#pragma unroll
    for (int f = 0; f < FJ; ++f) {
        int rb = wn * (BN / 2) + f * 16 + lc;
        boff[f] = rb * 64 + ((ks ^ ((rb >> 1) & 3)) << 4);
    }

    auto stage = [&](int d, int k0l) {
        int eA, eB;
        if (EPI == 5) {
            int t = k0l >> 8, ci0 = k0l & 255;
            eA = ((t / 3) * 66 + (t % 3) - 67) * 256 + ci0;
            eB = t * 65536 + ci0;
        } else {
            eA = k0l; eB = k0l;
        }
        short* dA = lsA + d * (BM * 32) + wv * (SA * 512);
        short* dB = lsB + d * (BN * 32) + wv * (SB * 512);
#pragma unroll
        for (int s = 0; s < SA; ++s) gl_lds16(arow[s] + eA, dA + s * 512);
#pragma unroll
        for (int s = 0; s < SB; ++s) gl_lds16(brow[s] + eB, dB + s * 512);
    };

    f32x4 acc[FI][FJ] = {};
    const int nt = Ktot >> 5;

    stage(0, 0);
    __syncthreads();                       // drains vmcnt(0) before first read
    int cur = 0;
    for (int t = 0; t < nt; ++t) {
        if (t + 1 < nt) stage(cur ^ 1, (t + 1) << 5);   // prefetch next K-step
        bf16x8 af[FI], bfr[FJ];
#pragma unroll
        for (int f = 0; f < FI; ++f)
            af[f] = *(const bf16x8*)((const char*)lsA + cur * (BM * 64) + aoff[f]);
#pragma unroll
        for (int f = 0; f < FJ; ++f)
            bfr[f] = *(const bf16x8*)((const char*)lsB + cur * (BN * 64) + boff[f]);
#pragma unroll
        for (int i = 0; i < FI; ++i)
#pragma unroll
            for (int j = 0; j < FJ; ++j)
                acc[i][j] = __builtin_amdgcn_mfma_f32_16x16x32_bf16(af[i], bfr[j], acc[i][j], 0, 0, 0);
        __syncthreads();                   // drains prefetch; read-done before overwrite
        cur ^= 1;
    }

    // ---- epilogue ----
    const int lr = (l >> 4) << 2;
#pragma unroll
    for (int i = 0; i < FI; ++i) {
        const int rowl = wm * (BM / 2) + i * 16 + lr;
#pragma unroll
        for (int j = 0; j < FJ; ++j) {
            const int coll = n0 + wn * (BN / 2) + j * 16 + lc;

            float sc = 0.f, tc = 0.f, bi = 0.f;
            if constexpr (EPI == 1) {
                bi = (coll < 128) ? bias[coll] : bias2[coll - 128];
            } else if constexpr (EPI == 3 || EPI == 4 || EPI == 5) {
                sc = bng[coll] * rsqrtf(bnv[coll] + EPSBN);
                tc = bnb[coll] - bnm[coll] * sc;
                bi = bias[coll];
            }

#pragma unroll
            for (int r = 0; r < 4; ++r) {
                const int row = m0 + rowl + r;
                float vvv = acc[i][j][r];
                if constexpr (EPI == 0) {
                    ((float*)Cv)[(size_t)row * 4096 + coll] = vvv;
                } else if constexpr (EPI == 1) {
                    float val = vvv + bi;
                    short hi = f2bf(val);
                    short lo = f2bf(val - bf2f(hi));
                    size_t rb = (size_t)row * 384;
                    if (coll < 128) {
                        short* qb_ = (short*)Cv;
                        qb_[rb + coll] = hi;
                        qb_[rb + 128 + coll] = hi;
                        qb_[rb + 256 + coll] = lo;
                    } else {
                        short* kb_ = (short*)Cv2;
                        int c = coll - 128;
                        kb_[rb + c] = hi;
                        kb_[rb + 128 + c] = lo;
                        kb_[rb + 256 + c] = hi;
                    }
                } else if constexpr (EPI == 2) {
                    int bb = coll >> 12;
                    ((short*)Cv)[((size_t)bb * 256 + row) * 4096 + (coll & 4095)] = f2bf(vvv + bias[row]);
                } else if constexpr (EPI == 3) {
                    float g = sigmoidf_(fmaxf(sc * (vvv + bi) + tc, 0.f));
                    float fv = bf2f(aux[(size_t)row * 256 + coll]);
                    ((short*)Cv)[(size_t)row * 256 + coll] = f2bf(fv * g);
                } else if constexpr (EPI == 4) {
                    float rv = fmaxf(sc * (vvv + bi) + tc, 0.f);
                    int bb = row >> 12, n = row & 4095;
                    int pr = bb * 4356 + ((n >> 6) + 1) * 66 + (n & 63) + 1;
                    ((short*)Cv)[(size_t)pr * 256 + coll] = f2bf(rv);
                } else if constexpr (EPI == 5) {
                    float rv = fmaxf(sc * (vvv + bi) + tc, 0.f);
                    ((short*)Cv)[(size_t)row * 256 + coll] = f2bf(rv);
                } else if constexpr (EPI == 6) {
                    float s6 = bng[row] * rsqrtf(bnv[row] + EPSBN);
                    float t6 = bnb[row] - bnm[row] * s6;
                    int bb = coll >> 12;
                    float yl = fmaxf(s6 * (vvv + bias[row]) + t6, 0.f);
                    float sg = sigmoidf_(yl + yrp[bb * 256 + row]);
                    float fv = bf2f(aux[(size_t)coll * 256 + row]);
                    ((float*)Cv)[((size_t)bb * 256 + row) * 4096 + (coll & 4095)] = fv * sg;
                } else if constexpr (EPI == 7) {
                    float* Cs = (float*)Cv + (size_t)blockIdx.z * 1048576;
                    Cs[(size_t)row * 256 + coll] = vvv;
                }
            }
        }
    }
}

// ---------------------------------------------------------------------------
// x [B][256][4096] fp32 -> xT3 [(b,n)][768] bf16 hi/lo: [xh(256) xh(256) xl(256)]
// ---------------------------------------------------------------------------
__global__ __launch_bounds__(256) void transpose_x_k(const float* __restrict__ x,
                                                     short* __restrict__ xT3)
{
    __shared__ float t[64][65];
    const int b = blockIdx.z, c0 = blockIdx.y * 64, n0 = blockIdx.x * 64;
    const int tid = threadIdx.x;
#pragma unroll
    for (int rep = 0; rep < 16; ++rep) {
        int idx = tid + rep * 256;
        int i = idx >> 6, j = idx & 63;
        t[i][j] = x[((size_t)(b * 256 + c0 + i)) * NPIX + n0 + j];
    }
    __syncthreads();
#pragma unroll
    for (int rep = 0; rep < 16; ++rep) {
        int idx = tid + rep * 256;
        int i = idx >> 6, j = idx & 63;
        float v = t[j][i];
        short hi = f2bf(v);
        short lo = f2bf(v - bf2f(hi));
        size_t rb = ((size_t)(b * NPIX + n0 + i)) * 768;
        xT3[rb + c0 + j] = hi;
        xT3[rb + 256 + c0 + j] = hi;
        xT3[rb + 512 + c0 + j] = lo;
    }
}

// src [rows][256] fp32 -> dst [rows][768]: [wh(256) wl(256) wh(256)]
__global__ __launch_bounds__(256) void cvt_hilo3_k(const float* __restrict__ src,
                                                   short* __restrict__ dst)
{
    int idx = blockIdx.x * 256 + threadIdx.x;
    int o = idx >> 8, c = idx & 255;
    float v = src[idx];
    short hi = f2bf(v);
    short lo = f2bf(v - bf2f(hi));
    size_t rb = (size_t)o * 768;
    dst[rb + c] = hi;
    dst[rb + 256 + c] = lo;
    dst[rb + 512 + c] = hi;
}

__global__ __launch_bounds__(256) void cvt_k(const float* __restrict__ s,
                                             short* __restrict__ d, int n)
{
    int i = blockIdx.x * 256 + threadIdx.x;
    if (i < n) d[i] = f2bf(s[i]);
}

// w2[t][co][ci] = l2w[co][ci][t]
__global__ __launch_bounds__(256) void permw2_k(const float* __restrict__ l2w,
                                                short* __restrict__ w2)
{
    int idx = blockIdx.x * 256 + threadIdx.x;
    int t = idx >> 16;
    int rem = idx & 65535;
    int co = rem >> 8, ci = rem & 255;
    w2[idx] = f2bf(l2w[((size_t)(co * 256 + ci)) * 9 + t]);
}

// ---------------------------------------------------------------------------
// Row softmax over 4096 fp32, writes bf16 probs in-place (row stride 8192 bf16)
// ---------------------------------------------------------------------------
__global__ __launch_bounds__(256) void softmax_k(float* __restrict__ e)
{
    const size_t row = blockIdx.x;
    const float4* r4 = (const float4*)(e + row * NPIX);
    short* arow = (short*)e + row * 8192;
    const int tid = threadIdx.x;
    float4 v4[4];
    float mx = -1e30f;
#pragma unroll
    for (int i = 0; i < 4; ++i) {
        v4[i] = r4[tid + (i << 8)];
        mx = fmaxf(mx, fmaxf(fmaxf(v4[i].x, v4[i].y), fmaxf(v4[i].z, v4[i].w)));
    }
#pragma unroll
    for (int o = 32; o; o >>= 1) mx = fmaxf(mx, __shfl_xor(mx, o));
    __shared__ float sm[4], ss[4];
    if ((tid & 63) == 0) sm[tid >> 6] = mx;
    __syncthreads();
    mx = fmaxf(fmaxf(sm[0], sm[1]), fmaxf(sm[2], sm[3]));
    float s = 0.f;
#pragma unroll
    for (int i = 0; i < 4; ++i) {
        float* p = &v4[i].x;
#pragma unroll
        for (int c = 0; c < 4; ++c) {
            p[c] = expf(p[c] - mx);
            s += p[c];
        }
    }
#pragma unroll
    for (int o = 32; o; o >>= 1) s += __shfl_xor(s, o);
    if ((tid & 63) == 0) ss[tid >> 6] = s;
    __syncthreads();
    s = ss[0] + ss[1] + ss[2] + ss[3];
    float inv = 1.0f / s;
#pragma unroll
    for (int i = 0; i < 4; ++i) {
        float* p = &v4[i].x;
        short4 o4;
        o4.x = f2bf(p[0] * inv);
        o4.y = f2bf(p[1] * inv);
        o4.z = f2bf(p[2] * inv);
        o4.w = f2bf(p[3] * inv);
        *(short4*)(arow + ((tid + (i << 8)) << 2)) = o4;
    }
}

// sum 4 split-K partials -> bf16 (vectorized)
__global__ __launch_bounds__(256) void feat_reduce_k(const float* __restrict__ p,
                                                     short* __restrict__ o)
{
    size_t i = ((size_t)blockIdx.x * 256 + threadIdx.x) * 4;
    const float4 a = *(const float4*)(p + i);
    const float4 b = *(const float4*)(p + i + 1048576);
    const float4 c = *(const float4*)(p + i + 2097152);
    const float4 d = *(const float4*)(p + i + 3145728);
    short4 o4;
    o4.x = f2bf(a.x + b.x + c.x + d.x);
    o4.y = f2bf(a.y + b.y + c.y + d.y);
    o4.z = f2bf(a.z + b.z + c.z + d.z);
    o4.w = f2bf(a.w + b.w + c.w + d.w);
    *(short4*)(o + i) = o4;
}

// ---------------------------------------------------------------------------
// Pool stage 1: ppart[((b*4+cg)*16+ns)*64 + cl] = sum over 256 n-rows
// ---------------------------------------------------------------------------
__global__ __launch_bounds__(256) void pool_s1_k(const short* __restrict__ yT,
                                                 float* __restrict__ ppart)
{
    const int ns = blockIdx.x, cg = blockIdx.y, b = blockIdx.z;
    const int tid = threadIdx.x;
    const int cl = tid & 63, ph = tid >> 6;
    float s = 0.f;
    const int nbase = ns * 256;
    for (int n = ph; n < 256; n += 4)
        s += bf2f(yT[((size_t)(b * NPIX + nbase + n)) * 256 + cg * 64 + cl]);
    __shared__ float ls[4][64];
    ls[ph][cl] = s;
    __syncthreads();
    if (ph == 0)
        ppart[((size_t)(b * 4 + cg) * 16 + ns) * 64 + cl] =
            ls[0][cl] + ls[1][cl] + ls[2][cl] + ls[3][cl];
}

// Pool stage 2: pooled[b*256+c] = (sum over 16 ns partials)/4096
__global__ __launch_bounds__(256) void pool_s2_k(const float* __restrict__ ppart,
                                                 float* __restrict__ pooled)
{
    const int b = blockIdx.x;
    const int c = threadIdx.x;
    const int cg = c >> 6, cl = c & 63;
    float s = 0.f;
#pragma unroll
    for (int ns = 0; ns < 16; ++ns)
        s += ppart[((size_t)(b * 4 + cg) * 16 + ns) * 64 + cl];
    pooled[b * 256 + c] = s * (1.0f / NPIX);
}

__global__ __launch_bounds__(256) void se_k(
    const float* __restrict__ pooled,
    const float* __restrict__ r1w, const float* __restrict__ r1b,
    const float* __restrict__ g, const float* __restrict__ bb,
    const float* __restrict__ m, const float* __restrict__ vv,
    const float* __restrict__ r2w, const float* __restrict__ r2b,
    float* __restrict__ yr)
{
    const int b = blockIdx.x;
    const int tid = threadIdx.x;
    __shared__ float p[256], hbuf[128];
    p[tid] = pooled[b * 256 + tid];
    __syncthreads();
    if (tid < 128) {
        float a = r1b[tid];
        for (int ci = 0; ci < 256; ++ci) a = fmaf(r1w[tid * 256 + ci], p[ci], a);
        float s = g[tid] * rsqrtf(vv[tid] + EPSBN);
        float t = bb[tid] - m[tid] * s;
        hbuf[tid] = fmaxf(s * a + t, 0.f);
    }
    __syncthreads();
    float a = r2b[tid];
    for (int c2 = 0; c2 < 128; ++c2) a = fmaf(r2w[tid * 128 + c2], hbuf[c2], a);
    yr[b * 256 + tid] = a;
}

// ---------------------------------------------------------------------------
extern "C" void kernel_launch(void* const* d_in, const int* in_sizes, int n_in,
                              void* d_out, int out_size, void* d_ws, size_t ws_size,
                              hipStream_t stream)
{
    const float* x    = (const float*)d_in[0];
    const float* wq   = (const float*)d_in[1];
    const float* bq   = (const float*)d_in[2];
    const float* wk   = (const float*)d_in[3];
    const float* bk   = (const float*)d_in[4];
    const float* wvp  = (const float*)d_in[5];
    const float* bv   = (const float*)d_in[6];
    const float* d1w  = (const float*)d_in[7];
    const float* d1b  = (const float*)d_in[8];
    const float* bn1g = (const float*)d_in[9];
    const float* bn1b = (const float*)d_in[10];
    const float* bn1m = (const float*)d_in[11];
    const float* bn1v = (const float*)d_in[12];
    const float* lbn1g = (const float*)d_in[13];
    const float* lbn1b = (const float*)d_in[14];
    const float* lbn1m = (const float*)d_in[15];
    const float* lbn1v = (const float*)d_in[16];
    const float* lbn2g = (const float*)d_in[17];
    const float* lbn2b = (const float*)d_in[18];
    const float* lbn2m = (const float*)d_in[19];
    const float* lbn2v = (const float*)d_in[20];
    const float* lbn3g = (const float*)d_in[21];
    const float* lbn3b = (const float*)d_in[22];
    const float* lbn3m = (const float*)d_in[23];
    const float* lbn3v = (const float*)d_in[24];
    const float* l1w  = (const float*)d_in[25];
    const float* l1b  = (const float*)d_in[26];
    const float* l2w  = (const float*)d_in[27];
    const float* l2b  = (const float*)d_in[28];
    const float* l3w  = (const float*)d_in[29];
    const float* l3b  = (const float*)d_in[30];
    const float* r1w  = (const float*)d_in[31];
    const float* r1b  = (const float*)d_in[32];
    const float* rbng = (const float*)d_in[33];
    const float* rbnb = (const float*)d_in[34];
    const float* rbnm = (const float*)d_in[35];
    const float* rbnv = (const float*)d_in[36];
    const float* r2w  = (const float*)d_in[37];
    const float* r2b  = (const float*)d_in[38];

    float* out = (float*)d_out;
    char* wsb = (char*)d_ws;

    // ---- workspace layout (peak ~131 MB) ----
    short* xT3  = (short*)(wsb);                    // [16384][768]  24 MB (dead after projections)
    float* fpart= (float*)(wsb);                    // 16 MB overlay during attn loop
    short* qbuf = (short*)(wsb + (24ull << 20));    // [16384][384]  12 MB
    short* kbuf = (short*)(wsb + (36ull << 20));    // [16384][384]  12 MB
    short* vbuf = (short*)(wsb + (48ull << 20));    // [4][256][4096] 8 MB
    float* E    = (float*)(wsb + (56ull << 20));    // [4096][4096]  64 MB
    short* yT   = (short*)(wsb + (56ull << 20));    // overlay E post-attn, 8 MB
    short* featT= (short*)(wsb + (120ull << 20));   // [16384][256]   8 MB
    short* t1pad= (short*)(wsb + (24ull << 20));    // overlay qbuf post-attn, 8.51 MB
    short* t2T  = (short*)(wsb + (36ull << 20));    // overlay kbuf post-attn, 8 MB
    float* pooled = (float*)(wsb + (128ull << 20)); // 1 KB
    float* yrb  = pooled + 1024;                    // 1 KB
    float* ppart= yrb + 1024;                       // 64 KB [4][4][16][64]
    short* wqk3 = (short*)(wsb + (129ull << 20));   // [256][768] 384 KB
    short* wvb  = wqk3 + 196608;                    // 128 KB
    short* d1wb = wvb + 65536;
    short* l1wb = d1wb + 65536;
    short* l3wb = l1wb + 65536;
    short* w2b  = l3wb + 65536;                     // [9][256][256] 1.125 MB

    dim3 blk(256);

    // ---- setup: transpose/convert ----
    transpose_x_k<<<dim3(64, 4, 4), blk, 0, stream>>>(x, xT3);
    cvt_hilo3_k<<<128, blk, 0, stream>>>(wq, wqk3);
    cvt_hilo3_k<<<128, blk, 0, stream>>>(wk, wqk3 + (size_t)128 * 768);
    cvt_k<<<256, blk, 0, stream>>>(wvp, wvb, 65536);
    cvt_k<<<256, blk, 0, stream>>>(d1w, d1wb, 65536);
    cvt_k<<<256, blk, 0, stream>>>(l1w, l1wb, 65536);
    cvt_k<<<256, blk, 0, stream>>>(l3w, l3wb, 65536);
    permw2_k<<<2304, blk, 0, stream>>>(l2w, w2b);

    // ---- projections ----
    // q/k: K=768 3-term hi/lo ([xh xh xl]·[wh wl wh]) -> hi/lo split outputs
    gbt_k<1, 64, 64><<<dim3(4, 256), blk, 0, stream>>>(xT3, 768, wqk3, 768, qbuf, kbuf, 768,
        bq, bk, nullptr, nullptr, nullptr, nullptr, nullptr, nullptr);
    // v: plain bf16, B = hi half of xT3
    gbt_k<2, 64, 64><<<dim3(256, 4), blk, 0, stream>>>(wvb, 256, xT3, 768, vbuf, nullptr, 256,
        bv, nullptr, nullptr, nullptr, nullptr, nullptr, nullptr, nullptr);

    // ---- attention, per batch ----
    for (int b = 0; b < 4; ++b) {
        const short* qp = qbuf + (size_t)b * 4096 * 384;
        const short* kp = kbuf + (size_t)b * 4096 * 384;
        gbt_k<0, 128, 128><<<dim3(32, 32), blk, 0, stream>>>(qp, 384, kp, 384, E, nullptr, 384,
            nullptr, nullptr, nullptr, nullptr, nullptr, nullptr, nullptr, nullptr);
        softmax_k<<<4096, blk, 0, stream>>>(E);
        gbt_k<7, 64, 128><<<dim3(2, 64, 4), blk, 0, stream>>>((const short*)E, 8192,
            vbuf + (size_t)b * 1048576, 4096, fpart, nullptr, 1024,
            nullptr, nullptr, nullptr, nullptr, nullptr, nullptr, nullptr, nullptr);
        feat_reduce_k<<<1024, blk, 0, stream>>>(fpart, featT + (size_t)b * 1048576);
    }

    // ---- gate: yT = feat * sigmoid(relu(bn1(d1(feat)))) ----
    gbt_k<3, 64, 64><<<dim3(4, 256), blk, 0, stream>>>(featT, 256, d1wb, 256, yT, nullptr, 256,
        d1b, nullptr, bn1g, bn1b, bn1m, bn1v, featT, nullptr);

    hipMemsetAsync(t1pad, 0, (size_t)4 * 4356 * 256 * 2, stream);

    // ---- SE branch ----
    pool_s1_k<<<dim3(16, 4, 4), blk, 0, stream>>>(yT, ppart);
    pool_s2_k<<<4, blk, 0, stream>>>(ppart, pooled);
    se_k<<<4, blk, 0, stream>>>(pooled, r1w, r1b, rbng, rbnb, rbnm, rbnv, r2w, r2b, yrb);

    // ---- left branch ----
    gbt_k<4, 64, 64><<<dim3(4, 256), blk, 0, stream>>>(yT, 256, l1wb, 256, t1pad, nullptr, 256,
        l1b, nullptr, lbn1g, lbn1b, lbn1m, lbn1v, nullptr, nullptr);
    gbt_k<5, 128, 64><<<dim3(4, 128), blk, 0, stream>>>(t1pad, 256, w2b, 256, t2T, nullptr, 2304,
        l2b, nullptr, lbn2g, lbn2b, lbn2m, lbn2v, nullptr, nullptr);

    // ---- final: out = feat * sigmoid(relu(bn3(l3(t2))) + yr) ----
    gbt_k<6, 64, 64><<<dim3(256, 4), blk, 0, stream>>>(l3wb, 256, t2T, 256, out, nullptr, 256,
        l3b, nullptr, lbn3g, lbn3b, lbn3m, lbn3v, featT, yrb);
}

// Round 6
// 409.766 us; speedup vs baseline: 4.4588x; 1.1759x over previous
//
#include <hip/hip_runtime.h>
#include <math.h>

#define NPIX 4096
#define EPSBN 1e-5f

typedef __attribute__((ext_vector_type(8))) short bf16x8;
typedef __attribute__((ext_vector_type(4))) float f32x4;

__device__ __forceinline__ float sigmoidf_(float x) { return 1.0f / (1.0f + expf(-x)); }

__device__ __forceinline__ short f2bf(float f) {
    unsigned u = __float_as_uint(f);
    u += 0x7fffu + ((u >> 16) & 1u);
    return (short)(u >> 16);
}
__device__ __forceinline__ float bf2f(short s) {
    return __uint_as_float(((unsigned)(unsigned short)s) << 16);
}

__device__ __forceinline__ void gl_lds16(const short* g, short* l) {
    __builtin_amdgcn_global_load_lds(
        (const __attribute__((address_space(1))) void*)g,
        (__attribute__((address_space(3))) void*)l, 16, 0, 0);
}

// ---------------------------------------------------------------------------
// Universal bf16 GEMM-BT:  C = epi( A[M][K] * B[N][K]^T )
// Tile BM x BN, 4 waves, double-buffered LDS, 1-deep prefetch.
// EPI 1: qkT      -> hi/lo rows: qbuf [qh(128) ql(128)], kbuf [kh kl]
// EPI 2: v        -> bf16 v[b][row][n], bias[row], b=col>>12, n=col&4095
// EPI 3: gate/y   -> yT bf16 = feat * sigmoid(relu(bn(acc+bias)))  (per col)
// EPI 4: l1->pad  -> relu(bn) bf16 at padded row
// EPI 5: conv3    -> A addressed via padded-image row map + tap offsets
// EPI 6: final    -> fp32 out = feat * sigmoid(relu(bn)+yr)   (bn per row)
// ---------------------------------------------------------------------------
template <int EPI, int BM, int BN>
__global__ __launch_bounds__(256) void gbt_k(
    const short* __restrict__ A, int lda,
    const short* __restrict__ B, int ldb,
    void* __restrict__ Cv, void* __restrict__ Cv2, int Ktot,
    const float* __restrict__ bias, const float* __restrict__ bias2,
    const float* __restrict__ bng, const float* __restrict__ bnb,
    const float* __restrict__ bnm, const float* __restrict__ bnv,
    const short* __restrict__ aux, const float* __restrict__ yrp)
{
    constexpr int FI = BM / 32, FJ = BN / 32;
    constexpr int SA = BM / 64, SB = BN / 64;
    __shared__ alignas(16) short lsA[2 * BM * 32];
    __shared__ alignas(16) short lsB[2 * BN * 32];

    const int tid = threadIdx.x;
    const int l = tid & 63;
    const int wv = tid >> 6;
    const int wm = wv >> 1, wn = wv & 1;
    const int m0 = blockIdx.y * BM;
    const int n0 = blockIdx.x * BN;

    const short* arow[2];
    const short* brow[2];
#pragma unroll
    for (int s = 0; s < SA; ++s) {
        int r = wv * (16 * SA) + s * 16 + (l >> 2);
        int sd = (l & 3) ^ ((r >> 1) & 3);
        if (EPI == 5) {
            int g = m0 + r;
            int p = (g >> 12) * 4356 + (((g & 4095) >> 6) + 1) * 66 + ((g & 63) + 1);
            arow[s] = A + (size_t)p * 256 + (sd << 3);
        } else {
            arow[s] = A + (size_t)(m0 + r) * lda + (sd << 3);
        }
    }
#pragma unroll
    for (int s = 0; s < SB; ++s) {
        int r = wv * (16 * SB) + s * 16 + (l >> 2);
        int sd = (l & 3) ^ ((r >> 1) & 3);
        brow[s] = B + (size_t)(n0 + r) * ldb + (sd << 3);
    }

    const int ks = l >> 4;
    const int lc = l & 15;
    int aoff[FI], boff[FJ];
#pragma unroll
    for (int f = 0; f < FI; ++f) {
        int ra = wm * (BM / 2) + f * 16 + lc;
        aoff[f] = ra * 64 + ((ks ^ ((ra >> 1) & 3)) << 4);
    }
#pragma unroll
    for (int f = 0; f < FJ; ++f) {
        int rb = wn * (BN / 2) + f * 16 + lc;
        boff[f] = rb * 64 + ((ks ^ ((rb >> 1) & 3)) << 4);
    }

    auto stage = [&](int d, int k0l) {
        int eA, eB;
        if (EPI == 5) {
            int t = k0l >> 8, ci0 = k0l & 255;
            eA = ((t / 3) * 66 + (t % 3) - 67) * 256 + ci0;
            eB = t * 65536 + ci0;
        } else {
            eA = k0l; eB = k0l;
        }
        short* dA = lsA + d * (BM * 32) + wv * (SA * 512);
        short* dB = lsB + d * (BN * 32) + wv * (SB * 512);
#pragma unroll
        for (int s = 0; s < SA; ++s) gl_lds16(arow[s] + eA, dA + s * 512);
#pragma unroll
        for (int s = 0; s < SB; ++s) gl_lds16(brow[s] + eB, dB + s * 512);
    };

    f32x4 acc[FI][FJ] = {};
    const int nt = Ktot >> 5;

    stage(0, 0);
    __syncthreads();
    int cur = 0;
    for (int t = 0; t < nt; ++t) {
        if (t + 1 < nt) stage(cur ^ 1, (t + 1) << 5);
        bf16x8 af[FI], bfr[FJ];
#pragma unroll
        for (int f = 0; f < FI; ++f)
            af[f] = *(const bf16x8*)((const char*)lsA + cur * (BM * 64) + aoff[f]);
#pragma unroll
        for (int f = 0; f < FJ; ++f)
            bfr[f] = *(const bf16x8*)((const char*)lsB + cur * (BN * 64) + boff[f]);
#pragma unroll
        for (int i = 0; i < FI; ++i)
#pragma unroll
            for (int j = 0; j < FJ; ++j)
                acc[i][j] = __builtin_amdgcn_mfma_f32_16x16x32_bf16(af[i], bfr[j], acc[i][j], 0, 0, 0);
        __syncthreads();
        cur ^= 1;
    }

    const int lr = (l >> 4) << 2;
#pragma unroll
    for (int i = 0; i < FI; ++i) {
        const int rowl = wm * (BM / 2) + i * 16 + lr;
#pragma unroll
        for (int j = 0; j < FJ; ++j) {
            const int coll = n0 + wn * (BN / 2) + j * 16 + lc;

            float sc = 0.f, tc = 0.f, bi = 0.f;
            if constexpr (EPI == 1) {
                bi = (coll < 128) ? bias[coll] : bias2[coll - 128];
            } else if constexpr (EPI == 3 || EPI == 4 || EPI == 5) {
                sc = bng[coll] * rsqrtf(bnv[coll] + EPSBN);
                tc = bnb[coll] - bnm[coll] * sc;
                bi = bias[coll];
            }

#pragma unroll
            for (int r = 0; r < 4; ++r) {
                const int row = m0 + rowl + r;
                float vvv = acc[i][j][r];
                if constexpr (EPI == 1) {
                    float val = vvv + bi;
                    short hi = f2bf(val);
                    short lo = f2bf(val - bf2f(hi));
                    size_t rb = (size_t)row * 256;
                    if (coll < 128) {
                        short* qb_ = (short*)Cv;
                        qb_[rb + coll] = hi;
                        qb_[rb + 128 + coll] = lo;
                    } else {
                        short* kb_ = (short*)Cv2;
                        int c = coll - 128;
                        kb_[rb + c] = hi;
                        kb_[rb + 128 + c] = lo;
                    }
                } else if constexpr (EPI == 2) {
                    int bb = coll >> 12;
                    ((short*)Cv)[((size_t)bb * 256 + row) * 4096 + (coll & 4095)] = f2bf(vvv + bias[row]);
                } else if constexpr (EPI == 3) {
                    float g = sigmoidf_(fmaxf(sc * (vvv + bi) + tc, 0.f));
                    float fv = bf2f(aux[(size_t)row * 256 + coll]);
                    ((short*)Cv)[(size_t)row * 256 + coll] = f2bf(fv * g);
                } else if constexpr (EPI == 4) {
                    float rv = fmaxf(sc * (vvv + bi) + tc, 0.f);
                    int bb = row >> 12, n = row & 4095;
                    int pr = bb * 4356 + ((n >> 6) + 1) * 66 + (n & 63) + 1;
                    ((short*)Cv)[(size_t)pr * 256 + coll] = f2bf(rv);
                } else if constexpr (EPI == 5) {
                    float rv = fmaxf(sc * (vvv + bi) + tc, 0.f);
                    ((short*)Cv)[(size_t)row * 256 + coll] = f2bf(rv);
                } else if constexpr (EPI == 6) {
                    float s6 = bng[row] * rsqrtf(bnv[row] + EPSBN);
                    float t6 = bnb[row] - bnm[row] * s6;
                    int bb = coll >> 12;
                    float yl = fmaxf(s6 * (vvv + bias[row]) + t6, 0.f);
                    float sg = sigmoidf_(yl + yrp[bb * 256 + row]);
                    float fv = bf2f(aux[(size_t)coll * 256 + row]);
                    ((float*)Cv)[((size_t)bb * 256 + row) * 4096 + (coll & 4095)] = fv * sg;
                }
            }
        }
    }
}

// ---------------------------------------------------------------------------
// Fused flash attention: featT[(b,q)][c] = softmax_row(Q Kh/l^T) · V^T
// Q,K: [4][4096][256] bf16 rows [hi(128) lo(128)]; V: [4][256][4096] bf16.
// Grid 256 blocks = 64 q-blocks x 4 batches (XCD-pinned), 4 waves,
// wave owns 16 q-rows. KVBLK=32, double-buffered K/V staging.
// ---------------------------------------------------------------------------
__global__ __launch_bounds__(256) void flash_k(
    const short* __restrict__ Q, const short* __restrict__ K,
    const short* __restrict__ V, short* __restrict__ O)
{
    __shared__ alignas(16) short Qs[8 * 64 * 32];     // 32 KB [chunk][row64][32]
    __shared__ alignas(16) short KsF[2 * 8 * 32 * 32]; // 32 KB [buf][chunk][row32][32]
    __shared__ alignas(16) short VsF[2 * 256 * 32];    // 32 KB [buf][chan][32]
    __shared__ alignas(16) short Ps[4 * 512];          // 4 KB per-wave P relay

    const int tid = threadIdx.x;
    const int l = tid & 63;
    const int wv = tid >> 6;
    const int bid = blockIdx.x;
    const int batch = (bid >> 1) & 3;                 // 2 XCDs per batch (bid%8 heuristic)
    const int qblk = ((bid >> 3) << 1) | (bid & 1);
    const int q0 = qblk * 64;

    const short* Qb = Q + (size_t)batch * 4096 * 256;
    const short* Kb = K + (size_t)batch * 4096 * 256;
    const short* Vb = V + (size_t)batch * 256 * 4096;

    const int srow = l >> 2;
    const int sl = l & 3;

    // ---- Q: one-time staging (8 chunks) ----
    {
        int r = wv * 16 + srow;
        int sd = sl ^ ((r >> 1) & 3);
        const short* src = Qb + (size_t)(q0 + r) * 256 + sd * 8;
#pragma unroll
        for (int c = 0; c < 8; ++c)
            gl_lds16(src + c * 32, Qs + c * 2048 + wv * 512);
    }

    // ---- K/V staging bases ----
    const short* ksrc[4]; short* kdst[4];
    const short* vsrc[4]; short* vdst[4];
#pragma unroll
    for (int p = 0; p < 4; ++p) {
        int c = 2 * p + (wv >> 1);
        int row = (wv & 1) * 16 + srow;
        int sd = sl ^ ((row >> 1) & 3);
        ksrc[p] = Kb + (size_t)row * 256 + c * 32 + sd * 8;
        kdst[p] = KsF + c * 1024 + (wv & 1) * 512;
        int cr = p * 64 + wv * 16 + srow;
        int sdv = sl ^ ((cr >> 1) & 3);
        vsrc[p] = Vb + (size_t)cr * 4096 + sdv * 8;
        vdst[p] = VsF + (p * 64 + wv * 16) * 32;
    }
    auto stageKV = [&](int buf, int kv0) {
#pragma unroll
        for (int p = 0; p < 4; ++p)
            gl_lds16(ksrc[p] + (size_t)kv0 * 256, kdst[p] + buf * 8192);
#pragma unroll
        for (int p = 0; p < 4; ++p)
            gl_lds16(vsrc[p] + kv0, vdst[p] + buf * 8192);
    };

    stageKV(0, 0);
    __syncthreads();

    const int lc = l & 15, ks = l >> 4;
    const int sw = ks ^ ((lc >> 1) & 3);

    // Q A-fragments (persistent)
    bf16x8 af[8];
#pragma unroll
    for (int c = 0; c < 8; ++c)
        af[c] = *(const bf16x8*)((const char*)Qs + c * 4096 + (wv * 16 + lc) * 64 + (sw << 4));

    float m_r[4], l_r[4];
#pragma unroll
    for (int r = 0; r < 4; ++r) { m_r[r] = -3e38f; l_r[r] = 0.f; }
    f32x4 acc_o[16] = {};

    const int poff = lc * 64 + ((ks ^ ((lc >> 2) & 3)) << 4);  // P-relay read offset
    int cur = 0;
    for (int t = 0; t < 128; ++t) {
        if (t + 1 < 128) stageKV(cur ^ 1, (t + 1) * 32);

        // ---- S = Q·K^T (hi/lo 3-term over 8 chunks) ----
        f32x4 s0 = {}, s1 = {};
        const char* kbase = (const char*)KsF + cur * 16384 + lc * 64 + (sw << 4);
#pragma unroll
        for (int b = 0; b < 8; ++b) {
            bf16x8 k0 = *(const bf16x8*)(kbase + b * 2048);
            bf16x8 k1 = *(const bf16x8*)(kbase + b * 2048 + 1024);
            if (b < 4) {
                s0 = __builtin_amdgcn_mfma_f32_16x16x32_bf16(af[b], k0, s0, 0, 0, 0);
                s1 = __builtin_amdgcn_mfma_f32_16x16x32_bf16(af[b], k1, s1, 0, 0, 0);
                s0 = __builtin_amdgcn_mfma_f32_16x16x32_bf16(af[b + 4], k0, s0, 0, 0, 0);
                s1 = __builtin_amdgcn_mfma_f32_16x16x32_bf16(af[b + 4], k1, s1, 0, 0, 0);
            } else {
                s0 = __builtin_amdgcn_mfma_f32_16x16x32_bf16(af[b - 4], k0, s0, 0, 0, 0);
                s1 = __builtin_amdgcn_mfma_f32_16x16x32_bf16(af[b - 4], k1, s1, 0, 0, 0);
            }
        }

        // ---- online softmax (rows = ks*4+r within wave's 16) ----
        float rmax[4], scale[4], rsum[4];
#pragma unroll
        for (int r = 0; r < 4; ++r) rmax[r] = fmaxf(s0[r], s1[r]);
#pragma unroll
        for (int off = 1; off <= 8; off <<= 1)
#pragma unroll
            for (int r = 0; r < 4; ++r)
                rmax[r] = fmaxf(rmax[r], __shfl_xor(rmax[r], off));
#pragma unroll
        for (int r = 0; r < 4; ++r) {
            float mn = fmaxf(m_r[r], rmax[r]);
            scale[r] = __expf(m_r[r] - mn);
            m_r[r] = mn;
            s0[r] = __expf(s0[r] - mn);
            s1[r] = __expf(s1[r] - mn);
            rsum[r] = s0[r] + s1[r];
        }
#pragma unroll
        for (int off = 1; off <= 8; off <<= 1)
#pragma unroll
            for (int r = 0; r < 4; ++r)
                rsum[r] += __shfl_xor(rsum[r], off);
#pragma unroll
        for (int r = 0; r < 4; ++r) l_r[r] = l_r[r] * scale[r] + rsum[r];
#pragma unroll
        for (int j = 0; j < 16; ++j)
#pragma unroll
            for (int r = 0; r < 4; ++r) acc_o[j][r] *= scale[r];

        // ---- P -> bf16 relay through wave-private LDS ----
        short* pw = Ps + wv * 512;
#pragma unroll
        for (int r = 0; r < 4; ++r) {
            int row = ks * 4 + r;
            pw[row * 32 + (((lc >> 3) ^ ks) * 8) + (lc & 7)] = f2bf(s0[r]);
            pw[row * 32 + (((2 + (lc >> 3)) ^ ks) * 8) + (lc & 7)] = f2bf(s1[r]);
        }
        asm volatile("s_waitcnt lgkmcnt(0)" ::: "memory");
        __builtin_amdgcn_sched_barrier(0);
        bf16x8 pa = *(const bf16x8*)((const char*)(Ps + wv * 512) + poff);

        // ---- O += P·V ----
        const char* vbase = (const char*)VsF + cur * 16384 + lc * 64 + (sw << 4);
#pragma unroll
        for (int j = 0; j < 16; ++j) {
            bf16x8 vb = *(const bf16x8*)(vbase + j * 1024);
            acc_o[j] = __builtin_amdgcn_mfma_f32_16x16x32_bf16(pa, vb, acc_o[j], 0, 0, 0);
        }
        __syncthreads();
        cur ^= 1;
    }

    // ---- epilogue: O /= l, store bf16 ----
    float linv[4];
#pragma unroll
    for (int r = 0; r < 4; ++r) linv[r] = 1.0f / l_r[r];
    short* Ob = O + (size_t)(batch * 4096 + q0) * 256;
#pragma unroll
    for (int j = 0; j < 16; ++j) {
        int col = j * 16 + lc;
#pragma unroll
        for (int r = 0; r < 4; ++r) {
            int row = wv * 16 + ks * 4 + r;
            Ob[(size_t)row * 256 + col] = f2bf(acc_o[j][r] * linv[r]);
        }
    }
}

// ---------------------------------------------------------------------------
// x [B][256][4096] fp32 -> xT3 [(b,n)][768] bf16 hi/lo: [xh xh xl]
// ---------------------------------------------------------------------------
__global__ __launch_bounds__(256) void transpose_x_k(const float* __restrict__ x,
                                                     short* __restrict__ xT3)
{
    __shared__ float t[64][65];
    const int b = blockIdx.z, c0 = blockIdx.y * 64, n0 = blockIdx.x * 64;
    const int tid = threadIdx.x;
#pragma unroll
    for (int rep = 0; rep < 16; ++rep) {
        int idx = tid + rep * 256;
        int i = idx >> 6, j = idx & 63;
        t[i][j] = x[((size_t)(b * 256 + c0 + i)) * NPIX + n0 + j];
    }
    __syncthreads();
#pragma unroll
    for (int rep = 0; rep < 16; ++rep) {
        int idx = tid + rep * 256;
        int i = idx >> 6, j = idx & 63;
        float v = t[j][i];
        short hi = f2bf(v);
        short lo = f2bf(v - bf2f(hi));
        size_t rb = ((size_t)(b * NPIX + n0 + i)) * 768;
        xT3[rb + c0 + j] = hi;
        xT3[rb + 256 + c0 + j] = hi;
        xT3[rb + 512 + c0 + j] = lo;
    }
}

// src [rows][256] fp32 -> dst [rows][768]: [wh wl wh]
__global__ __launch_bounds__(256) void cvt_hilo3_k(const float* __restrict__ src,
                                                   short* __restrict__ dst)
{
    int idx = blockIdx.x * 256 + threadIdx.x;
    int o = idx >> 8, c = idx & 255;
    float v = src[idx];
    short hi = f2bf(v);
    short lo = f2bf(v - bf2f(hi));
    size_t rb = (size_t)o * 768;
    dst[rb + c] = hi;
    dst[rb + 256 + c] = lo;
    dst[rb + 512 + c] = hi;
}

__global__ __launch_bounds__(256) void cvt_k(const float* __restrict__ s,
                                             short* __restrict__ d, int n)
{
    int i = blockIdx.x * 256 + threadIdx.x;
    if (i < n) d[i] = f2bf(s[i]);
}

__global__ __launch_bounds__(256) void permw2_k(const float* __restrict__ l2w,
                                                short* __restrict__ w2)
{
    int idx = blockIdx.x * 256 + threadIdx.x;
    int t = idx >> 16;
    int rem = idx & 65535;
    int co = rem >> 8, ci = rem & 255;
    w2[idx] = f2bf(l2w[((size_t)(co * 256 + ci)) * 9 + t]);
}

// ---------------------------------------------------------------------------
__global__ __launch_bounds__(256) void pool_s1_k(const short* __restrict__ yT,
                                                 float* __restrict__ ppart)
{
    const int ns = blockIdx.x, cg = blockIdx.y, b = blockIdx.z;
    const int tid = threadIdx.x;
    const int cl = tid & 63, ph = tid >> 6;
    float s = 0.f;
    const int nbase = ns * 256;
    for (int n = ph; n < 256; n += 4)
        s += bf2f(yT[((size_t)(b * NPIX + nbase + n)) * 256 + cg * 64 + cl]);
    __shared__ float ls[4][64];
    ls[ph][cl] = s;
    __syncthreads();
    if (ph == 0)
        ppart[((size_t)(b * 4 + cg) * 16 + ns) * 64 + cl] =
            ls[0][cl] + ls[1][cl] + ls[2][cl] + ls[3][cl];
}

__global__ __launch_bounds__(256) void pool_s2_k(const float* __restrict__ ppart,
                                                 float* __restrict__ pooled)
{
    const int b = blockIdx.x;
    const int c = threadIdx.x;
    const int cg = c >> 6, cl = c & 63;
    float s = 0.f;
#pragma unroll
    for (int ns = 0; ns < 16; ++ns)
        s += ppart[((size_t)(b * 4 + cg) * 16 + ns) * 64 + cl];
    pooled[b * 256 + c] = s * (1.0f / NPIX);
}

__global__ __launch_bounds__(256) void se_k(
    const float* __restrict__ pooled,
    const float* __restrict__ r1w, const float* __restrict__ r1b,
    const float* __restrict__ g, const float* __restrict__ bb,
    const float* __restrict__ m, const float* __restrict__ vv,
    const float* __restrict__ r2w, const float* __restrict__ r2b,
    float* __restrict__ yr)
{
    const int b = blockIdx.x;
    const int tid = threadIdx.x;
    __shared__ float p[256], hbuf[128];
    p[tid] = pooled[b * 256 + tid];
    __syncthreads();
    if (tid < 128) {
        float a = r1b[tid];
        for (int ci = 0; ci < 256; ++ci) a = fmaf(r1w[tid * 256 + ci], p[ci], a);
        float s = g[tid] * rsqrtf(vv[tid] + EPSBN);
        float t = bb[tid] - m[tid] * s;
        hbuf[tid] = fmaxf(s * a + t, 0.f);
    }
    __syncthreads();
    float a = r2b[tid];
    for (int c2 = 0; c2 < 128; ++c2) a = fmaf(r2w[tid * 128 + c2], hbuf[c2], a);
    yr[b * 256 + tid] = a;
}

// ---------------------------------------------------------------------------
extern "C" void kernel_launch(void* const* d_in, const int* in_sizes, int n_in,
                              void* d_out, int out_size, void* d_ws, size_t ws_size,
                              hipStream_t stream)
{
    const float* x    = (const float*)d_in[0];
    const float* wq   = (const float*)d_in[1];
    const float* bq   = (const float*)d_in[2];
    const float* wk   = (const float*)d_in[3];
    const float* bk   = (const float*)d_in[4];
    const float* wvp  = (const float*)d_in[5];
    const float* bv   = (const float*)d_in[6];
    const float* d1w  = (const float*)d_in[7];
    const float* d1b  = (const float*)d_in[8];
    const float* bn1g = (const float*)d_in[9];
    const float* bn1b = (const float*)d_in[10];
    const float* bn1m = (const float*)d_in[11];
    const float* bn1v = (const float*)d_in[12];
    const float* lbn1g = (const float*)d_in[13];
    const float* lbn1b = (const float*)d_in[14];
    const float* lbn1m = (const float*)d_in[15];
    const float* lbn1v = (const float*)d_in[16];
    const float* lbn2g = (const float*)d_in[17];
    const float* lbn2b = (const float*)d_in[18];
    const float* lbn2m = (const float*)d_in[19];
    const float* lbn2v = (const float*)d_in[20];
    const float* lbn3g = (const float*)d_in[21];
    const float* lbn3b = (const float*)d_in[22];
    const float* lbn3m = (const float*)d_in[23];
    const float* lbn3v = (const float*)d_in[24];
    const float* l1w  = (const float*)d_in[25];
    const float* l1b  = (const float*)d_in[26];
    const float* l2w  = (const float*)d_in[27];
    const float* l2b  = (const float*)d_in[28];
    const float* l3w  = (const float*)d_in[29];
    const float* l3b  = (const float*)d_in[30];
    const float* r1w  = (const float*)d_in[31];
    const float* r1b  = (const float*)d_in[32];
    const float* rbng = (const float*)d_in[33];
    const float* rbnb = (const float*)d_in[34];
    const float* rbnm = (const float*)d_in[35];
    const float* rbnv = (const float*)d_in[36];
    const float* r2w  = (const float*)d_in[37];
    const float* r2b  = (const float*)d_in[38];

    float* out = (float*)d_out;
    char* wsb = (char*)d_ws;

    // ---- workspace layout (peak ~85 MB) ----
    short* xT3  = (short*)(wsb);                    // [16384][768]  24 MB (dead after proj)
    short* qbuf = (short*)(wsb + (24ull << 20));    // [16384][256]   8 MB
    short* kbuf = (short*)(wsb + (32ull << 20));    // [16384][256]   8 MB
    short* vbuf = (short*)(wsb + (40ull << 20));    // [4][256][4096] 8 MB
    short* featT= (short*)(wsb + (48ull << 20));    // [16384][256]   8 MB
    short* yT   = (short*)(wsb + (56ull << 20));    // 8 MB
    short* t1pad= (short*)(wsb + (64ull << 20));    // [4][4356][256] 8.51 MB
    short* t2T  = (short*)(wsb + (73ull << 20));    // 8 MB
    float* pooled = (float*)(wsb + (82ull << 20));  // 1 KB
    float* yrb  = pooled + 1024;
    float* ppart= yrb + 1024;                       // 64 KB
    short* wqk3 = (short*)(wsb + (83ull << 20));    // [256][768] 384 KB
    short* wvb  = wqk3 + 196608;
    short* d1wb = wvb + 65536;
    short* l1wb = d1wb + 65536;
    short* l3wb = l1wb + 65536;
    short* w2b  = l3wb + 65536;                     // [9][256][256] 1.125 MB

    dim3 blk(256);

    // ---- setup: transpose/convert ----
    transpose_x_k<<<dim3(64, 4, 4), blk, 0, stream>>>(x, xT3);
    cvt_hilo3_k<<<128, blk, 0, stream>>>(wq, wqk3);
    cvt_hilo3_k<<<128, blk, 0, stream>>>(wk, wqk3 + (size_t)128 * 768);
    cvt_k<<<256, blk, 0, stream>>>(wvp, wvb, 65536);
    cvt_k<<<256, blk, 0, stream>>>(d1w, d1wb, 65536);
    cvt_k<<<256, blk, 0, stream>>>(l1w, l1wb, 65536);
    cvt_k<<<256, blk, 0, stream>>>(l3w, l3wb, 65536);
    permw2_k<<<2304, blk, 0, stream>>>(l2w, w2b);

    // ---- projections ----
    gbt_k<1, 64, 64><<<dim3(4, 256), blk, 0, stream>>>(xT3, 768, wqk3, 768, qbuf, kbuf, 768,
        bq, bk, nullptr, nullptr, nullptr, nullptr, nullptr, nullptr);
    gbt_k<2, 64, 64><<<dim3(256, 4), blk, 0, stream>>>(wvb, 256, xT3, 768, vbuf, nullptr, 256,
        bv, nullptr, nullptr, nullptr, nullptr, nullptr, nullptr, nullptr);

    // ---- fused flash attention (all batches, one dispatch) ----
    flash_k<<<256, blk, 0, stream>>>(qbuf, kbuf, vbuf, featT);

    // ---- gate: yT = feat * sigmoid(relu(bn1(d1(feat)))) ----
    gbt_k<3, 64, 64><<<dim3(4, 256), blk, 0, stream>>>(featT, 256, d1wb, 256, yT, nullptr, 256,
        d1b, nullptr, bn1g, bn1b, bn1m, bn1v, featT, nullptr);

    hipMemsetAsync(t1pad, 0, (size_t)4 * 4356 * 256 * 2, stream);

    // ---- SE branch ----
    pool_s1_k<<<dim3(16, 4, 4), blk, 0, stream>>>(yT, ppart);
    pool_s2_k<<<4, blk, 0, stream>>>(ppart, pooled);
    se_k<<<4, blk, 0, stream>>>(pooled, r1w, r1b, rbng, rbnb, rbnm, rbnv, r2w, r2b, yrb);

    // ---- left branch ----
    gbt_k<4, 64, 64><<<dim3(4, 256), blk, 0, stream>>>(yT, 256, l1wb, 256, t1pad, nullptr, 256,
        l1b, nullptr, lbn1g, lbn1b, lbn1m, lbn1v, nullptr, nullptr);
    gbt_k<5, 128, 64><<<dim3(4, 128), blk, 0, stream>>>(t1pad, 256, w2b, 256, t2T, nullptr, 2304,
        l2b, nullptr, lbn2g, lbn2b, lbn2m, lbn2v, nullptr, nullptr);

    // ---- final: out = feat * sigmoid(relu(bn3(l3(t2))) + yr) ----
    gbt_k<6, 64, 64><<<dim3(256, 4), blk, 0, stream>>>(l3wb, 256, t2T, 256, out, nullptr, 256,
        l3b, nullptr, lbn3g, lbn3b, lbn3m, lbn3v, featT, yrb);
}

// Round 7
// 275.755 us; speedup vs baseline: 6.6257x; 1.4860x over previous
//
#include <hip/hip_runtime.h>
#include <math.h>

#define NPIX 4096
#define EPSBN 1e-5f

typedef __attribute__((ext_vector_type(8))) short bf16x8;
typedef __attribute__((ext_vector_type(4))) float f32x4;

__device__ __forceinline__ float sigmoidf_(float x) { return 1.0f / (1.0f + expf(-x)); }

__device__ __forceinline__ short f2bf(float f) {
    unsigned u = __float_as_uint(f);
    u += 0x7fffu + ((u >> 16) & 1u);
    return (short)(u >> 16);
}
__device__ __forceinline__ float bf2f(short s) {
    return __uint_as_float(((unsigned)(unsigned short)s) << 16);
}

__device__ __forceinline__ void gl_lds16(const short* g, short* l) {
    __builtin_amdgcn_global_load_lds(
        (const __attribute__((address_space(1))) void*)g,
        (__attribute__((address_space(3))) void*)l, 16, 0, 0);
}

// ---------------------------------------------------------------------------
// Universal bf16 GEMM-BT:  C = epi( A[M][K] * B[N][K]^T )
// Tile BM x BN, 4 waves, double-buffered LDS, 1-deep prefetch.
// EPI 1: qkT      -> hi/lo rows: qbuf [qh(128) ql(128)], kbuf [kh kl]
// EPI 2: v        -> bf16 v[b][row][n], bias[row], b=col>>12, n=col&4095
// EPI 3: gate/y   -> yT bf16 = feat * sigmoid(relu(bn(acc+bias)))  (per col)
// EPI 4: l1->pad  -> relu(bn) bf16 at padded row
// EPI 5: conv3    -> A addressed via padded-image row map + tap offsets
// EPI 6: final    -> fp32 out = feat * sigmoid(relu(bn)+yr)   (bn per row)
// ---------------------------------------------------------------------------
template <int EPI, int BM, int BN>
__global__ __launch_bounds__(256) void gbt_k(
    const short* __restrict__ A, int lda,
    const short* __restrict__ B, int ldb,
    void* __restrict__ Cv, void* __restrict__ Cv2, int Ktot,
    const float* __restrict__ bias, const float* __restrict__ bias2,
    const float* __restrict__ bng, const float* __restrict__ bnb,
    const float* __restrict__ bnm, const float* __restrict__ bnv,
    const short* __restrict__ aux, const float* __restrict__ yrp)
{
    constexpr int FI = BM / 32, FJ = BN / 32;
    constexpr int SA = BM / 64, SB = BN / 64;
    __shared__ alignas(16) short lsA[2 * BM * 32];
    __shared__ alignas(16) short lsB[2 * BN * 32];

    const int tid = threadIdx.x;
    const int l = tid & 63;
    const int wv = tid >> 6;
    const int wm = wv >> 1, wn = wv & 1;
    const int m0 = blockIdx.y * BM;
    const int n0 = blockIdx.x * BN;

    const short* arow[2];
    const short* brow[2];
#pragma unroll
    for (int s = 0; s < SA; ++s) {
        int r = wv * (16 * SA) + s * 16 + (l >> 2);
        int sd = (l & 3) ^ ((r >> 1) & 3);
        if (EPI == 5) {
            int g = m0 + r;
            int p = (g >> 12) * 4356 + (((g & 4095) >> 6) + 1) * 66 + ((g & 63) + 1);
            arow[s] = A + (size_t)p * 256 + (sd << 3);
        } else {
            arow[s] = A + (size_t)(m0 + r) * lda + (sd << 3);
        }
    }
#pragma unroll
    for (int s = 0; s < SB; ++s) {
        int r = wv * (16 * SB) + s * 16 + (l >> 2);
        int sd = (l & 3) ^ ((r >> 1) & 3);
        brow[s] = B + (size_t)(n0 + r) * ldb + (sd << 3);
    }

    const int ks = l >> 4;
    const int lc = l & 15;
    int aoff[FI], boff[FJ];
#pragma unroll
    for (int f = 0; f < FI; ++f) {
        int ra = wm * (BM / 2) + f * 16 + lc;
        aoff[f] = ra * 64 + ((ks ^ ((ra >> 1) & 3)) << 4);
    }
#pragma unroll
    for (int f = 0; f < FJ; ++f) {
        int rb = wn * (BN / 2) + f * 16 + lc;
        boff[f] = rb * 64 + ((ks ^ ((rb >> 1) & 3)) << 4);
    }

    auto stage = [&](int d, int k0l) {
        int eA, eB;
        if (EPI == 5) {
            int t = k0l >> 8, ci0 = k0l & 255;
            eA = ((t / 3) * 66 + (t % 3) - 67) * 256 + ci0;
            eB = t * 65536 + ci0;
        } else {
            eA = k0l; eB = k0l;
        }
        short* dA = lsA + d * (BM * 32) + wv * (SA * 512);
        short* dB = lsB + d * (BN * 32) + wv * (SB * 512);
#pragma unroll
        for (int s = 0; s < SA; ++s) gl_lds16(arow[s] + eA, dA + s * 512);
#pragma unroll
        for (int s = 0; s < SB; ++s) gl_lds16(brow[s] + eB, dB + s * 512);
    };

    f32x4 acc[FI][FJ] = {};
    const int nt = Ktot >> 5;

    stage(0, 0);
    __syncthreads();
    int cur = 0;
    for (int t = 0; t < nt; ++t) {
        if (t + 1 < nt) stage(cur ^ 1, (t + 1) << 5);
        bf16x8 af[FI], bfr[FJ];
#pragma unroll
        for (int f = 0; f < FI; ++f)
            af[f] = *(const bf16x8*)((const char*)lsA + cur * (BM * 64) + aoff[f]);
#pragma unroll
        for (int f = 0; f < FJ; ++f)
            bfr[f] = *(const bf16x8*)((const char*)lsB + cur * (BN * 64) + boff[f]);
#pragma unroll
        for (int i = 0; i < FI; ++i)
#pragma unroll
            for (int j = 0; j < FJ; ++j)
                acc[i][j] = __builtin_amdgcn_mfma_f32_16x16x32_bf16(af[i], bfr[j], acc[i][j], 0, 0, 0);
        __syncthreads();
        cur ^= 1;
    }

    const int lr = (l >> 4) << 2;
#pragma unroll
    for (int i = 0; i < FI; ++i) {
        const int rowl = wm * (BM / 2) + i * 16 + lr;
#pragma unroll
        for (int j = 0; j < FJ; ++j) {
            const int coll = n0 + wn * (BN / 2) + j * 16 + lc;

            float sc = 0.f, tc = 0.f, bi = 0.f;
            if constexpr (EPI == 1) {
                bi = (coll < 128) ? bias[coll] : bias2[coll - 128];
            } else if constexpr (EPI == 3 || EPI == 4 || EPI == 5) {
                sc = bng[coll] * rsqrtf(bnv[coll] + EPSBN);
                tc = bnb[coll] - bnm[coll] * sc;
                bi = bias[coll];
            }

#pragma unroll
            for (int r = 0; r < 4; ++r) {
                const int row = m0 + rowl + r;
                float vvv = acc[i][j][r];
                if constexpr (EPI == 1) {
                    float val = vvv + bi;
                    short hi = f2bf(val);
                    short lo = f2bf(val - bf2f(hi));
                    size_t rb = (size_t)row * 256;
                    if (coll < 128) {
                        short* qb_ = (short*)Cv;
                        qb_[rb + coll] = hi;
                        qb_[rb + 128 + coll] = lo;
                    } else {
                        short* kb_ = (short*)Cv2;
                        int c = coll - 128;
                        kb_[rb + c] = hi;
                        kb_[rb + 128 + c] = lo;
                    }
                } else if constexpr (EPI == 2) {
                    int bb = coll >> 12;
                    ((short*)Cv)[((size_t)bb * 256 + row) * 4096 + (coll & 4095)] = f2bf(vvv + bias[row]);
                } else if constexpr (EPI == 3) {
                    float g = sigmoidf_(fmaxf(sc * (vvv + bi) + tc, 0.f));
                    float fv = bf2f(aux[(size_t)row * 256 + coll]);
                    ((short*)Cv)[(size_t)row * 256 + coll] = f2bf(fv * g);
                } else if constexpr (EPI == 4) {
                    float rv = fmaxf(sc * (vvv + bi) + tc, 0.f);
                    int bb = row >> 12, n = row & 4095;
                    int pr = bb * 4356 + ((n >> 6) + 1) * 66 + (n & 63) + 1;
                    ((short*)Cv)[(size_t)pr * 256 + coll] = f2bf(rv);
                } else if constexpr (EPI == 5) {
                    float rv = fmaxf(sc * (vvv + bi) + tc, 0.f);
                    ((short*)Cv)[(size_t)row * 256 + coll] = f2bf(rv);
                } else if constexpr (EPI == 6) {
                    float s6 = bng[row] * rsqrtf(bnv[row] + EPSBN);
                    float t6 = bnb[row] - bnm[row] * s6;
                    int bb = coll >> 12;
                    float yl = fmaxf(s6 * (vvv + bias[row]) + t6, 0.f);
                    float sg = sigmoidf_(yl + yrp[bb * 256 + row]);
                    float fv = bf2f(aux[(size_t)coll * 256 + row]);
                    ((float*)Cv)[((size_t)bb * 256 + row) * 4096 + (coll & 4095)] = fv * sg;
                }
            }
        }
    }
}

// ---------------------------------------------------------------------------
// Fused flash attention, no-max softmax, KV-split halves.
// Q,K: [4][4096][256] bf16 rows [hi(128) lo(128)]; V: [4][256][4096] bf16.
// Grid 512 = 64 qblk x (kvh,batch as bid&7 -> XCD-pinned). 4 waves x 16 q-rows.
// Per block: KV half (2048), 64 tiles of 32. Outputs UNNORMALIZED partials:
// Op[kvh][batch][q][c] fp32, lp[kvh][batch*4096+q] = row sums (via ones-MFMA).
// LDS 68KB -> 2 blocks/CU (8 waves/CU).
// ---------------------------------------------------------------------------
__global__ __launch_bounds__(256, 2) void flash_k(
    const short* __restrict__ Q, const short* __restrict__ K,
    const short* __restrict__ V, float* __restrict__ Op, float* __restrict__ lp)
{
    __shared__ alignas(16) short smem[34816];
    // shorts [0,16384): K dbuf (2 x 8192); Q staged here pre-loop
    // shorts [16384,32768): V dbuf (2 x 8192)
    // shorts [32768,34816): P relay (4 waves x 512)

    const int tid = threadIdx.x;
    const int l = tid & 63;
    const int wv = tid >> 6;
    const int bid = blockIdx.x;
    const int kvh = bid & 1;
    const int batch = (bid >> 1) & 3;
    const int q0 = (bid >> 3) * 64;
    const int kv00 = kvh * 2048;

    const short* Qb = Q + (size_t)batch * 4096 * 256;
    const short* Kb = K + (size_t)batch * 4096 * 256;
    const short* Vb = V + (size_t)batch * 256 * 4096;

    const int srow = l >> 2;
    const int sl = l & 3;

    // ---- Q: stage into K region, read frags to regs, then release ----
    {
        int r = wv * 16 + srow;
        int sd = sl ^ ((r >> 1) & 3);
        const short* src = Qb + (size_t)(q0 + r) * 256 + sd * 8;
#pragma unroll
        for (int c = 0; c < 8; ++c)
            gl_lds16(src + c * 32, smem + c * 2048 + wv * 512);
    }
    __syncthreads();

    const int lc = l & 15, ks = l >> 4;
    const int sw = ks ^ ((lc >> 1) & 3);

    bf16x8 af[8];
#pragma unroll
    for (int c = 0; c < 8; ++c)
        af[c] = *(const bf16x8*)((const char*)smem + c * 4096 + (wv * 16 + lc) * 64 + (sw << 4));
    __syncthreads();

    // ---- K/V staging bases ----
    const short* ksrc[4]; short* kdst[4];
    const short* vsrc[4]; short* vdst[4];
#pragma unroll
    for (int p = 0; p < 4; ++p) {
        int c = 2 * p + (wv >> 1);
        int row = (wv & 1) * 16 + srow;
        int sd = sl ^ ((row >> 1) & 3);
        ksrc[p] = Kb + (size_t)(kv00 + row) * 256 + c * 32 + sd * 8;
        kdst[p] = smem + c * 1024 + (wv & 1) * 512;
        int cr = p * 64 + wv * 16 + srow;
        int sdv = sl ^ ((cr >> 1) & 3);
        vsrc[p] = Vb + (size_t)cr * 4096 + kv00 + sdv * 8;
        vdst[p] = smem + 16384 + (p * 64 + wv * 16) * 32;
    }
    auto stageKV = [&](int buf, int kvoff) {
#pragma unroll
        for (int p = 0; p < 4; ++p)
            gl_lds16(ksrc[p] + (size_t)kvoff * 256, kdst[p] + buf * 8192);
#pragma unroll
        for (int p = 0; p < 4; ++p)
            gl_lds16(vsrc[p] + kvoff, vdst[p] + buf * 8192);
    };

    stageKV(0, 0);
    __syncthreads();

    bf16x8 ones;
#pragma unroll
    for (int e = 0; e < 8; ++e) ones[e] = (short)0x3F80;

    f32x4 acc_o[16] = {};
    f32x4 acc_l = {};
    const int poff = lc * 64 + ((ks ^ ((lc >> 2) & 3)) << 4);

    int cur = 0;
    for (int t = 0; t < 64; ++t) {
        if (t + 1 < 64) stageKV(cur ^ 1, (t + 1) * 32);

        // ---- S = Q·K^T (hi/lo 3-term, 4 independent chains of 6) ----
        const char* kb_ = (const char*)smem + cur * 16384 + lc * 64 + (sw << 4);
        f32x4 s0A = {}, s0B = {}, s1A = {}, s1B = {};
        __builtin_amdgcn_s_setprio(1);
#pragma unroll
        for (int b = 0; b < 4; ++b) {
            bf16x8 k0 = *(const bf16x8*)(kb_ + b * 2048);
            bf16x8 k1 = *(const bf16x8*)(kb_ + b * 2048 + 1024);
            s0A = __builtin_amdgcn_mfma_f32_16x16x32_bf16(af[b], k0, s0A, 0, 0, 0);
            s1A = __builtin_amdgcn_mfma_f32_16x16x32_bf16(af[b], k1, s1A, 0, 0, 0);
            s0B = __builtin_amdgcn_mfma_f32_16x16x32_bf16(af[b + 4], k0, s0B, 0, 0, 0);
            s1B = __builtin_amdgcn_mfma_f32_16x16x32_bf16(af[b + 4], k1, s1B, 0, 0, 0);
        }
#pragma unroll
        for (int b = 4; b < 8; ++b) {
            bf16x8 k0 = *(const bf16x8*)(kb_ + b * 2048);
            bf16x8 k1 = *(const bf16x8*)(kb_ + b * 2048 + 1024);
            if (b & 1) {
                s0B = __builtin_amdgcn_mfma_f32_16x16x32_bf16(af[b - 4], k0, s0B, 0, 0, 0);
                s1B = __builtin_amdgcn_mfma_f32_16x16x32_bf16(af[b - 4], k1, s1B, 0, 0, 0);
            } else {
                s0A = __builtin_amdgcn_mfma_f32_16x16x32_bf16(af[b - 4], k0, s0A, 0, 0, 0);
                s1A = __builtin_amdgcn_mfma_f32_16x16x32_bf16(af[b - 4], k1, s1A, 0, 0, 0);
            }
        }
        __builtin_amdgcn_s_setprio(0);

        // ---- P = exp(S), no max subtraction (fp32 range analysis: safe) ----
        float e0[4], e1[4];
#pragma unroll
        for (int r = 0; r < 4; ++r) {
            e0[r] = __expf(s0A[r] + s0B[r]);
            e1[r] = __expf(s1A[r] + s1B[r]);
        }

        // ---- P -> bf16 relay through wave-private LDS ----
        short* pw = smem + 32768 + wv * 512;
#pragma unroll
        for (int r = 0; r < 4; ++r) {
            int row = ks * 4 + r;
            pw[row * 32 + (((lc >> 3) ^ ks) * 8) + (lc & 7)] = f2bf(e0[r]);
            pw[row * 32 + (((2 + (lc >> 3)) ^ ks) * 8) + (lc & 7)] = f2bf(e1[r]);
        }
        asm volatile("s_waitcnt lgkmcnt(0)" ::: "memory");
        __builtin_amdgcn_sched_barrier(0);
        bf16x8 pa = *(const bf16x8*)((const char*)(smem + 32768 + wv * 512) + poff);

        // ---- O += P·V ; l += P·1 ----
        const char* vb_ = (const char*)smem + 32768 + cur * 16384 + lc * 64 + (sw << 4);
        __builtin_amdgcn_s_setprio(1);
#pragma unroll
        for (int j = 0; j < 16; ++j) {
            bf16x8 vv = *(const bf16x8*)(vb_ + j * 1024);
            acc_o[j] = __builtin_amdgcn_mfma_f32_16x16x32_bf16(pa, vv, acc_o[j], 0, 0, 0);
        }
        acc_l = __builtin_amdgcn_mfma_f32_16x16x32_bf16(pa, ones, acc_l, 0, 0, 0);
        __builtin_amdgcn_s_setprio(0);
        __syncthreads();
        cur ^= 1;
    }

    // ---- store unnormalized partials ----
    float* Ob = Op + ((size_t)(kvh * 4 + batch) * 4096 + q0) * 256;
#pragma unroll
    for (int j = 0; j < 16; ++j) {
        int col = j * 16 + lc;
#pragma unroll
        for (int r = 0; r < 4; ++r) {
            int row = wv * 16 + ks * 4 + r;
            Ob[(size_t)row * 256 + col] = acc_o[j][r];
        }
    }
    if (lc == 0) {
        float* lb = lp + (size_t)(kvh * 4 + batch) * 4096 + q0;
#pragma unroll
        for (int r = 0; r < 4; ++r)
            lb[wv * 16 + ks * 4 + r] = acc_l[r];
    }
}

// featT = (O0 + O1) / (l0 + l1), cast bf16. 4M elems, float4-vectorized.
__global__ __launch_bounds__(256) void combine_k(const float* __restrict__ Op,
                                                 const float* __restrict__ lp,
                                                 short* __restrict__ o)
{
    int idx = blockIdx.x * 256 + threadIdx.x;
    size_t e = (size_t)idx * 4;
    int row = (int)(e >> 8);
    float li = 1.0f / (lp[row] + lp[row + 16384]);
    const float4 a = *(const float4*)(Op + e);
    const float4 b = *(const float4*)(Op + e + 4194304);
    short4 o4;
    o4.x = f2bf((a.x + b.x) * li);
    o4.y = f2bf((a.y + b.y) * li);
    o4.z = f2bf((a.z + b.z) * li);
    o4.w = f2bf((a.w + b.w) * li);
    *(short4*)(o + e) = o4;
}

// ---------------------------------------------------------------------------
// x [B][256][4096] fp32 -> xT3 [(b,n)][768] bf16 hi/lo: [xh xh xl]
// ---------------------------------------------------------------------------
__global__ __launch_bounds__(256) void transpose_x_k(const float* __restrict__ x,
                                                     short* __restrict__ xT3)
{
    __shared__ float t[64][65];
    const int b = blockIdx.z, c0 = blockIdx.y * 64, n0 = blockIdx.x * 64;
    const int tid = threadIdx.x;
#pragma unroll
    for (int rep = 0; rep < 16; ++rep) {
        int idx = tid + rep * 256;
        int i = idx >> 6, j = idx & 63;
        t[i][j] = x[((size_t)(b * 256 + c0 + i)) * NPIX + n0 + j];
    }
    __syncthreads();
#pragma unroll
    for (int rep = 0; rep < 16; ++rep) {
        int idx = tid + rep * 256;
        int i = idx >> 6, j = idx & 63;
        float v = t[j][i];
        short hi = f2bf(v);
        short lo = f2bf(v - bf2f(hi));
        size_t rb = ((size_t)(b * NPIX + n0 + i)) * 768;
        xT3[rb + c0 + j] = hi;
        xT3[rb + 256 + c0 + j] = hi;
        xT3[rb + 512 + c0 + j] = lo;
    }
}

// src [rows][256] fp32 -> dst [rows][768]: [wh wl wh]
__global__ __launch_bounds__(256) void cvt_hilo3_k(const float* __restrict__ src,
                                                   short* __restrict__ dst)
{
    int idx = blockIdx.x * 256 + threadIdx.x;
    int o = idx >> 8, c = idx & 255;
    float v = src[idx];
    short hi = f2bf(v);
    short lo = f2bf(v - bf2f(hi));
    size_t rb = (size_t)o * 768;
    dst[rb + c] = hi;
    dst[rb + 256 + c] = lo;
    dst[rb + 512 + c] = hi;
}

__global__ __launch_bounds__(256) void cvt_k(const float* __restrict__ s,
                                             short* __restrict__ d, int n)
{
    int i = blockIdx.x * 256 + threadIdx.x;
    if (i < n) d[i] = f2bf(s[i]);
}

__global__ __launch_bounds__(256) void permw2_k(const float* __restrict__ l2w,
                                                short* __restrict__ w2)
{
    int idx = blockIdx.x * 256 + threadIdx.x;
    int t = idx >> 16;
    int rem = idx & 65535;
    int co = rem >> 8, ci = rem & 255;
    w2[idx] = f2bf(l2w[((size_t)(co * 256 + ci)) * 9 + t]);
}

// ---------------------------------------------------------------------------
__global__ __launch_bounds__(256) void pool_s1_k(const short* __restrict__ yT,
                                                 float* __restrict__ ppart)
{
    const int ns = blockIdx.x, cg = blockIdx.y, b = blockIdx.z;
    const int tid = threadIdx.x;
    const int cl = tid & 63, ph = tid >> 6;
    float s = 0.f;
    const int nbase = ns * 256;
    for (int n = ph; n < 256; n += 4)
        s += bf2f(yT[((size_t)(b * NPIX + nbase + n)) * 256 + cg * 64 + cl]);
    __shared__ float ls[4][64];
    ls[ph][cl] = s;
    __syncthreads();
    if (ph == 0)
        ppart[((size_t)(b * 4 + cg) * 16 + ns) * 64 + cl] =
            ls[0][cl] + ls[1][cl] + ls[2][cl] + ls[3][cl];
}

__global__ __launch_bounds__(256) void pool_s2_k(const float* __restrict__ ppart,
                                                 float* __restrict__ pooled)
{
    const int b = blockIdx.x;
    const int c = threadIdx.x;
    const int cg = c >> 6, cl = c & 63;
    float s = 0.f;
#pragma unroll
    for (int ns = 0; ns < 16; ++ns)
        s += ppart[((size_t)(b * 4 + cg) * 16 + ns) * 64 + cl];
    pooled[b * 256 + c] = s * (1.0f / NPIX);
}

__global__ __launch_bounds__(256) void se_k(
    const float* __restrict__ pooled,
    const float* __restrict__ r1w, const float* __restrict__ r1b,
    const float* __restrict__ g, const float* __restrict__ bb,
    const float* __restrict__ m, const float* __restrict__ vv,
    const float* __restrict__ r2w, const float* __restrict__ r2b,
    float* __restrict__ yr)
{
    const int b = blockIdx.x;
    const int tid = threadIdx.x;
    __shared__ float p[256], hbuf[128];
    p[tid] = pooled[b * 256 + tid];
    __syncthreads();
    if (tid < 128) {
        float a = r1b[tid];
        for (int ci = 0; ci < 256; ++ci) a = fmaf(r1w[tid * 256 + ci], p[ci], a);
        float s = g[tid] * rsqrtf(vv[tid] + EPSBN);
        float t = bb[tid] - m[tid] * s;
        hbuf[tid] = fmaxf(s * a + t, 0.f);
    }
    __syncthreads();
    float a = r2b[tid];
    for (int c2 = 0; c2 < 128; ++c2) a = fmaf(r2w[tid * 128 + c2], hbuf[c2], a);
    yr[b * 256 + tid] = a;
}

// ---------------------------------------------------------------------------
extern "C" void kernel_launch(void* const* d_in, const int* in_sizes, int n_in,
                              void* d_out, int out_size, void* d_ws, size_t ws_size,
                              hipStream_t stream)
{
    const float* x    = (const float*)d_in[0];
    const float* wq   = (const float*)d_in[1];
    const float* bq   = (const float*)d_in[2];
    const float* wk   = (const float*)d_in[3];
    const float* bk   = (const float*)d_in[4];
    const float* wvp  = (const float*)d_in[5];
    const float* bv   = (const float*)d_in[6];
    const float* d1w  = (const float*)d_in[7];
    const float* d1b  = (const float*)d_in[8];
    const float* bn1g = (const float*)d_in[9];
    const float* bn1b = (const float*)d_in[10];
    const float* bn1m = (const float*)d_in[11];
    const float* bn1v = (const float*)d_in[12];
    const float* lbn1g = (const float*)d_in[13];
    const float* lbn1b = (const float*)d_in[14];
    const float* lbn1m = (const float*)d_in[15];
    const float* lbn1v = (const float*)d_in[16];
    const float* lbn2g = (const float*)d_in[17];
    const float* lbn2b = (const float*)d_in[18];
    const float* lbn2m = (const float*)d_in[19];
    const float* lbn2v = (const float*)d_in[20];
    const float* lbn3g = (const float*)d_in[21];
    const float* lbn3b = (const float*)d_in[22];
    const float* lbn3m = (const float*)d_in[23];
    const float* lbn3v = (const float*)d_in[24];
    const float* l1w  = (const float*)d_in[25];
    const float* l1b  = (const float*)d_in[26];
    const float* l2w  = (const float*)d_in[27];
    const float* l2b  = (const float*)d_in[28];
    const float* l3w  = (const float*)d_in[29];
    const float* l3b  = (const float*)d_in[30];
    const float* r1w  = (const float*)d_in[31];
    const float* r1b  = (const float*)d_in[32];
    const float* rbng = (const float*)d_in[33];
    const float* rbnb = (const float*)d_in[34];
    const float* rbnm = (const float*)d_in[35];
    const float* rbnv = (const float*)d_in[36];
    const float* r2w  = (const float*)d_in[37];
    const float* r2b  = (const float*)d_in[38];

    float* out = (float*)d_out;
    char* wsb = (char*)d_ws;

    // ---- workspace layout (peak ~120 MB; >=131 MB proven usable) ----
    short* xT3  = (short*)(wsb);                    // [16384][768]  24 MB (dead after proj)
    short* qbuf = (short*)(wsb + (24ull << 20));    // [16384][256]   8 MB
    short* kbuf = (short*)(wsb + (32ull << 20));    // [16384][256]   8 MB
    short* vbuf = (short*)(wsb + (40ull << 20));    // [4][256][4096] 8 MB
    short* featT= (short*)(wsb + (48ull << 20));    // [16384][256]   8 MB
    short* yT   = (short*)(wsb + (56ull << 20));    // 8 MB
    short* t1pad= (short*)(wsb + (64ull << 20));    // [4][4356][256] 8.51 MB
    short* t2T  = (short*)(wsb + (73ull << 20));    // 8 MB
    float* pooled = (float*)(wsb + (82ull << 20));  // 1 KB
    float* yrb  = pooled + 1024;
    float* ppart= yrb + 1024;                       // 64 KB
    short* wqk3 = (short*)(wsb + (83ull << 20));    // [256][768] 384 KB
    short* wvb  = wqk3 + 196608;
    short* d1wb = wvb + 65536;
    short* l1wb = d1wb + 65536;
    short* l3wb = l1wb + 65536;
    short* w2b  = l3wb + 65536;                     // [9][256][256] 1.125 MB
    float* Opart= (float*)(wsb + (88ull << 20));    // [2][4][4096][256] fp32 32 MB
    float* lpart= (float*)(wsb + (120ull << 20));   // [2][16384] 128 KB

    dim3 blk(256);

    // ---- setup: transpose/convert ----
    transpose_x_k<<<dim3(64, 4, 4), blk, 0, stream>>>(x, xT3);
    cvt_hilo3_k<<<128, blk, 0, stream>>>(wq, wqk3);
    cvt_hilo3_k<<<128, blk, 0, stream>>>(wk, wqk3 + (size_t)128 * 768);
    cvt_k<<<256, blk, 0, stream>>>(wvp, wvb, 65536);
    cvt_k<<<256, blk, 0, stream>>>(d1w, d1wb, 65536);
    cvt_k<<<256, blk, 0, stream>>>(l1w, l1wb, 65536);
    cvt_k<<<256, blk, 0, stream>>>(l3w, l3wb, 65536);
    permw2_k<<<2304, blk, 0, stream>>>(l2w, w2b);

    // ---- projections ----
    gbt_k<1, 64, 64><<<dim3(4, 256), blk, 0, stream>>>(xT3, 768, wqk3, 768, qbuf, kbuf, 768,
        bq, bk, nullptr, nullptr, nullptr, nullptr, nullptr, nullptr);
    gbt_k<2, 64, 64><<<dim3(256, 4), blk, 0, stream>>>(wvb, 256, xT3, 768, vbuf, nullptr, 256,
        bv, nullptr, nullptr, nullptr, nullptr, nullptr, nullptr, nullptr);

    // ---- fused flash attention (KV-split halves) + combine ----
    flash_k<<<512, blk, 0, stream>>>(qbuf, kbuf, vbuf, Opart, lpart);
    combine_k<<<4096, blk, 0, stream>>>(Opart, lpart, featT);

    // ---- gate: yT = feat * sigmoid(relu(bn1(d1(feat)))) ----
    gbt_k<3, 64, 64><<<dim3(4, 256), blk, 0, stream>>>(featT, 256, d1wb, 256, yT, nullptr, 256,
        d1b, nullptr, bn1g, bn1b, bn1m, bn1v, featT, nullptr);

    hipMemsetAsync(t1pad, 0, (size_t)4 * 4356 * 256 * 2, stream);

    // ---- SE branch ----
    pool_s1_k<<<dim3(16, 4, 4), blk, 0, stream>>>(yT, ppart);
    pool_s2_k<<<4, blk, 0, stream>>>(ppart, pooled);
    se_k<<<4, blk, 0, stream>>>(pooled, r1w, r1b, rbng, rbnb, rbnm, rbnv, r2w, r2b, yrb);

    // ---- left branch ----
    gbt_k<4, 64, 64><<<dim3(4, 256), blk, 0, stream>>>(yT, 256, l1wb, 256, t1pad, nullptr, 256,
        l1b, nullptr, lbn1g, lbn1b, lbn1m, lbn1v, nullptr, nullptr);
    gbt_k<5, 128, 64><<<dim3(4, 128), blk, 0, stream>>>(t1pad, 256, w2b, 256, t2T, nullptr, 2304,
        l2b, nullptr, lbn2g, lbn2b, lbn2m, lbn2v, nullptr, nullptr);

    // ---- final: out = feat * sigmoid(relu(bn3(l3(t2))) + yr) ----
    gbt_k<6, 64, 64><<<dim3(256, 4), blk, 0, stream>>>(l3wb, 256, t2T, 256, out, nullptr, 256,
        l3b, nullptr, lbn3g, lbn3b, lbn3m, lbn3v, featT, yrb);
}

// Round 9
// 264.452 us; speedup vs baseline: 6.9090x; 1.0427x over previous
//
#include <hip/hip_runtime.h>
#include <math.h>

#define NPIX 4096
#define EPSBN 1e-5f

typedef __attribute__((ext_vector_type(8))) short bf16x8;
typedef __attribute__((ext_vector_type(4))) float f32x4;

__device__ __forceinline__ float sigmoidf_(float x) { return 1.0f / (1.0f + expf(-x)); }

__device__ __forceinline__ short f2bf(float f) {
    unsigned u = __float_as_uint(f);
    u += 0x7fffu + ((u >> 16) & 1u);
    return (short)(u >> 16);
}
__device__ __forceinline__ float bf2f(short s) {
    return __uint_as_float(((unsigned)(unsigned short)s) << 16);
}
__device__ __forceinline__ int pk2(float lo, float hi) {
    return (int)(unsigned short)f2bf(lo) | ((int)(unsigned short)f2bf(hi) << 16);
}

__device__ __forceinline__ void gl_lds16(const short* g, short* l) {
    __builtin_amdgcn_global_load_lds(
        (const __attribute__((address_space(1))) void*)g,
        (__attribute__((address_space(3))) void*)l, 16, 0, 0);
}

// ---------------------------------------------------------------------------
// Universal bf16 GEMM-BT:  C = epi( A[M][K] * B[N][K]^T )
// Tile BM x BN, 4 waves, double-buffered LDS, 1-deep prefetch.
// ---------------------------------------------------------------------------
template <int EPI, int BM, int BN>
__global__ __launch_bounds__(256) void gbt_k(
    const short* __restrict__ A, int lda,
    const short* __restrict__ B, int ldb,
    void* __restrict__ Cv, void* __restrict__ Cv2, int Ktot,
    const float* __restrict__ bias, const float* __restrict__ bias2,
    const float* __restrict__ bng, const float* __restrict__ bnb,
    const float* __restrict__ bnm, const float* __restrict__ bnv,
    const short* __restrict__ aux, const float* __restrict__ yrp)
{
    constexpr int FI = BM / 32, FJ = BN / 32;
    constexpr int SA = BM / 64, SB = BN / 64;
    __shared__ alignas(16) short lsA[2 * BM * 32];
    __shared__ alignas(16) short lsB[2 * BN * 32];

    const int tid = threadIdx.x;
    const int l = tid & 63;
    const int wv = tid >> 6;
    const int wm = wv >> 1, wn = wv & 1;
    const int m0 = blockIdx.y * BM;
    const int n0 = blockIdx.x * BN;

    const short* arow[2];
    const short* brow[2];
#pragma unroll
    for (int s = 0; s < SA; ++s) {
        int r = wv * (16 * SA) + s * 16 + (l >> 2);
        int sd = (l & 3) ^ ((r >> 1) & 3);
        if (EPI == 5) {
            int g = m0 + r;
            int p = (g >> 12) * 4356 + (((g & 4095) >> 6) + 1) * 66 + ((g & 63) + 1);
            arow[s] = A + (size_t)p * 256 + (sd << 3);
        } else {
            arow[s] = A + (size_t)(m0 + r) * lda + (sd << 3);
        }
    }
#pragma unroll
    for (int s = 0; s < SB; ++s) {
        int r = wv * (16 * SB) + s * 16 + (l >> 2);
        int sd = (l & 3) ^ ((r >> 1) & 3);
        brow[s] = B + (size_t)(n0 + r) * ldb + (sd << 3);
    }

    const int ks = l >> 4;
    const int lc = l & 15;
    int aoff[FI], boff[FJ];
#pragma unroll
    for (int f = 0; f < FI; ++f) {
        int ra = wm * (BM / 2) + f * 16 + lc;
        aoff[f] = ra * 64 + ((ks ^ ((ra >> 1) & 3)) << 4);
    }
#pragma unroll
    for (int f = 0; f < FJ; ++f) {
        int rb = wn * (BN / 2) + f * 16 + lc;
        boff[f] = rb * 64 + ((ks ^ ((rb >> 1) & 3)) << 4);
    }

    auto stage = [&](int d, int k0l) {
        int eA, eB;
        if (EPI == 5) {
            int t = k0l >> 8, ci0 = k0l & 255;
            eA = ((t / 3) * 66 + (t % 3) - 67) * 256 + ci0;
            eB = t * 65536 + ci0;
        } else {
            eA = k0l; eB = k0l;
        }
        short* dA = lsA + d * (BM * 32) + wv * (SA * 512);
        short* dB = lsB + d * (BN * 32) + wv * (SB * 512);
#pragma unroll
        for (int s = 0; s < SA; ++s) gl_lds16(arow[s] + eA, dA + s * 512);
#pragma unroll
        for (int s = 0; s < SB; ++s) gl_lds16(brow[s] + eB, dB + s * 512);
    };

    f32x4 acc[FI][FJ] = {};
    const int nt = Ktot >> 5;

    stage(0, 0);
    __syncthreads();
    int cur = 0;
    for (int t = 0; t < nt; ++t) {
        if (t + 1 < nt) stage(cur ^ 1, (t + 1) << 5);
        bf16x8 af[FI], bfr[FJ];
#pragma unroll
        for (int f = 0; f < FI; ++f)
            af[f] = *(const bf16x8*)((const char*)lsA + cur * (BM * 64) + aoff[f]);
#pragma unroll
        for (int f = 0; f < FJ; ++f)
            bfr[f] = *(const bf16x8*)((const char*)lsB + cur * (BN * 64) + boff[f]);
#pragma unroll
        for (int i = 0; i < FI; ++i)
#pragma unroll
            for (int j = 0; j < FJ; ++j)
                acc[i][j] = __builtin_amdgcn_mfma_f32_16x16x32_bf16(af[i], bfr[j], acc[i][j], 0, 0, 0);
        __syncthreads();
        cur ^= 1;
    }

    const int lr = (l >> 4) << 2;
#pragma unroll
    for (int i = 0; i < FI; ++i) {
        const int rowl = wm * (BM / 2) + i * 16 + lr;
#pragma unroll
        for (int j = 0; j < FJ; ++j) {
            const int coll = n0 + wn * (BN / 2) + j * 16 + lc;

            float sc = 0.f, tc = 0.f, bi = 0.f;
            if constexpr (EPI == 1) {
                bi = (coll < 128) ? bias[coll] : bias2[coll - 128];
            } else if constexpr (EPI == 3 || EPI == 4 || EPI == 5) {
                sc = bng[coll] * rsqrtf(bnv[coll] + EPSBN);
                tc = bnb[coll] - bnm[coll] * sc;
                bi = bias[coll];
            }

#pragma unroll
            for (int r = 0; r < 4; ++r) {
                const int row = m0 + rowl + r;
                float vvv = acc[i][j][r];
                if constexpr (EPI == 1) {
                    float val = vvv + bi;
                    short hi = f2bf(val);
                    short lo = f2bf(val - bf2f(hi));
                    size_t rb = (size_t)row * 256;
                    if (coll < 128) {
                        short* qb_ = (short*)Cv;
                        qb_[rb + coll] = hi;
                        qb_[rb + 128 + coll] = lo;
                    } else {
                        short* kb_ = (short*)Cv2;
                        int c = coll - 128;
                        kb_[rb + c] = hi;
                        kb_[rb + 128 + c] = lo;
                    }
                } else if constexpr (EPI == 2) {
                    int bb = coll >> 12;
                    ((short*)Cv)[((size_t)bb * 256 + row) * 4096 + (coll & 4095)] = f2bf(vvv + bias[row]);
                } else if constexpr (EPI == 3) {
                    float g = sigmoidf_(fmaxf(sc * (vvv + bi) + tc, 0.f));
                    float fv = bf2f(aux[(size_t)row * 256 + coll]);
                    ((short*)Cv)[(size_t)row * 256 + coll] = f2bf(fv * g);
                } else if constexpr (EPI == 4) {
                    float rv = fmaxf(sc * (vvv + bi) + tc, 0.f);
                    int bb = row >> 12, n = row & 4095;
                    int pr = bb * 4356 + ((n >> 6) + 1) * 66 + (n & 63) + 1;
                    ((short*)Cv)[(size_t)pr * 256 + coll] = f2bf(rv);
                } else if constexpr (EPI == 5) {
                    float rv = fmaxf(sc * (vvv + bi) + tc, 0.f);
                    ((short*)Cv)[(size_t)row * 256 + coll] = f2bf(rv);
                } else if constexpr (EPI == 6) {
                    float s6 = bng[row] * rsqrtf(bnv[row] + EPSBN);
                    float t6 = bnb[row] - bnm[row] * s6;
                    int bb = coll >> 12;
                    float yl = fmaxf(s6 * (vvv + bias[row]) + t6, 0.f);
                    float sg = sigmoidf_(yl + yrp[bb * 256 + row]);
                    float fv = bf2f(aux[(size_t)coll * 256 + row]);
                    ((float*)Cv)[((size_t)bb * 256 + row) * 4096 + (coll & 4095)] = fv * sg;
                }
            }
        }
    }
}

// ---------------------------------------------------------------------------
// Flash attention v2: swapped QK (S^T via mfma(K,Q)) + register P-transpose
// via ds_bpermute. 512 thr / 8 waves / 32 q-rows per wave / 256 q per block.
// Grid 256 = 16 qblk x (batch*4+kvq); kv-quarter per block (1024 kv, 32 iters).
// No-max softmax (fp32 range-safe). Outputs unnormalized partials per kvq.
// ---------------------------------------------------------------------------
__global__ __launch_bounds__(512, 2) void flash_k(
    const short* __restrict__ Q, const short* __restrict__ K,
    const short* __restrict__ V, float* __restrict__ Op, float* __restrict__ lp)
{
    __shared__ alignas(16) short smem[32768];
    // BYTES: K dbuf [0, 32768) | V dbuf [32768, 65536)

    const int tid = threadIdx.x;
    const int l = tid & 63;
    const int wv = tid >> 6;              // 0..7
    const int bid = blockIdx.x;
    const int combo = bid & 15;           // batch*4 + kvq
    const int batch = combo >> 2;
    const int kvq = combo & 3;
    const int q0 = (bid >> 4) * 256;
    const int kv0 = kvq * 1024;

    const short* Qb = Q + (size_t)batch * 4096 * 256;
    const short* Kb = K + (size_t)batch * 4096 * 256;
    const short* Vb = V + (size_t)batch * 256 * 4096;

    const int lc = l & 15, ks = l >> 4;

    // ---- Q fragments direct from global (B-operand: col=q=lc, k-chunk=ks) ----
    bf16x8 bq[2][8];
#pragma unroll
    for (int f = 0; f < 2; ++f)
#pragma unroll
        for (int cc = 0; cc < 8; ++cc)
            bq[f][cc] = *(const bf16x8*)(Qb +
                (size_t)(q0 + wv * 32 + f * 16 + lc) * 256 + cc * 32 + ks * 8);

    // ---- K staging: [32 kv][256 c] rows of 512B, slot s holds chunk s^(row&7) ----
    const short* ksrc[2]; short* kdst[2];
    const short* vsrc[2]; short* vdst[2];
#pragma unroll
    for (int i = 0; i < 2; ++i) {
        int row = wv * 4 + i * 2 + (l >> 5);
        int s = l & 31;
        int g = s ^ (row & 7);
        ksrc[i] = Kb + (size_t)(kv0 + row) * 256 + g * 8;
        kdst[i] = smem + wv * 1024 + i * 512;
        int c = wv * 32 + i * 16 + (l >> 2);
        int sv = l & 3;
        int gv = sv ^ ((c >> 1) & 3);
        vsrc[i] = Vb + (size_t)c * 4096 + kv0 + gv * 8;
        vdst[i] = smem + 16384 + wv * 1024 + i * 512;
    }
    auto stageKV = [&](int buf, int t) {
#pragma unroll
        for (int i = 0; i < 2; ++i) gl_lds16(ksrc[i] + (size_t)t * 8192, kdst[i] + buf * 8192);
#pragma unroll
        for (int i = 0; i < 2; ++i) gl_lds16(vsrc[i] + t * 32, vdst[i] + buf * 8192);
    };

    stageKV(0, 0);
    __syncthreads();

    const int kro = lc * 512;             // K row byte offset (kvf0); kvf1: +8192
    const int kxr = lc & 7;
    const int vb0 = lc * 64 + ((ks ^ ((lc >> 1) & 3)) << 4);  // V frag base (j: +1024)
    const int addrA = (((ks & 1) * 2) * 16 + lc) * 4;         // bpermute source lanes
    const int addrB = addrA + 64;

    bf16x8 ones;
#pragma unroll
    for (int e = 0; e < 8; ++e) ones[e] = (short)0x3F80;

    f32x4 acc_o[2][16] = {};
    f32x4 acc_l[2] = {};

    int cur = 0;
    for (int t = 0; t < 32; ++t) {
        if (t + 1 < 32) stageKV(cur ^ 1, t + 1);

        // ---- S^T = K·Q^T: 3-term hi/lo; K-frags read once, shared by 2 q-frags ----
        const char* kb_ = (const char*)smem + cur * 16384;
        f32x4 s00 = {}, s01 = {}, s10 = {}, s11 = {};   // s[f][kvf]
        __builtin_amdgcn_s_setprio(1);
#pragma unroll
        for (int jc = 0; jc < 4; ++jc) {
#pragma unroll
            for (int kvf = 0; kvf < 2; ++kvf) {
                const char* rb_ = kb_ + kro + kvf * 8192;
                bf16x8 kh_ = *(const bf16x8*)(rb_ + ((((jc * 4) + ks) ^ kxr) << 4));
                bf16x8 kl_ = *(const bf16x8*)(rb_ + (((((jc + 4) * 4) + ks) ^ kxr) << 4));
                f32x4& sA = kvf ? s01 : s00;
                f32x4& sB = kvf ? s11 : s10;
                sA = __builtin_amdgcn_mfma_f32_16x16x32_bf16(kh_, bq[0][jc], sA, 0, 0, 0);
                sB = __builtin_amdgcn_mfma_f32_16x16x32_bf16(kh_, bq[1][jc], sB, 0, 0, 0);
                sA = __builtin_amdgcn_mfma_f32_16x16x32_bf16(kl_, bq[0][jc], sA, 0, 0, 0);
                sB = __builtin_amdgcn_mfma_f32_16x16x32_bf16(kl_, bq[1][jc], sB, 0, 0, 0);
                sA = __builtin_amdgcn_mfma_f32_16x16x32_bf16(kh_, bq[0][jc + 4], sA, 0, 0, 0);
                sB = __builtin_amdgcn_mfma_f32_16x16x32_bf16(kh_, bq[1][jc + 4], sB, 0, 0, 0);
            }
        }
        __builtin_amdgcn_s_setprio(0);

        // ---- P = exp(S); register transpose via ds_bpermute -> PV A-operand ----
        bf16x8 pa[2];
#pragma unroll
        for (int f = 0; f < 2; ++f) {
            const f32x4& sa = f ? s10 : s00;   // kv local ks*4+r
            const f32x4& sb = f ? s11 : s01;   // kv local 16+ks*4+r
            int u0 = pk2(__expf(sa[0]), __expf(sa[1]));   // g = 2ks
            int u1 = pk2(__expf(sa[2]), __expf(sa[3]));   // g = 2ks+1
            int u2 = pk2(__expf(sb[0]), __expf(sb[1]));   // g = 8+2ks
            int u3 = pk2(__expf(sb[2]), __expf(sb[3]));   // g = 9+2ks
            int a0 = __builtin_amdgcn_ds_bpermute(addrA, u0);
            int b0 = __builtin_amdgcn_ds_bpermute(addrA, u2);
            int a1 = __builtin_amdgcn_ds_bpermute(addrA, u1);
            int b1 = __builtin_amdgcn_ds_bpermute(addrA, u3);
            int a2 = __builtin_amdgcn_ds_bpermute(addrB, u0);
            int b2 = __builtin_amdgcn_ds_bpermute(addrB, u2);
            int a3 = __builtin_amdgcn_ds_bpermute(addrB, u1);
            int b3 = __builtin_amdgcn_ds_bpermute(addrB, u3);
            union { int i4[4]; bf16x8 v; } un;
            un.i4[0] = (ks < 2) ? a0 : b0;
            un.i4[1] = (ks < 2) ? a1 : b1;
            un.i4[2] = (ks < 2) ? a2 : b2;
            un.i4[3] = (ks < 2) ? a3 : b3;
            pa[f] = un.v;
        }

        // ---- O += P·V ; l += P·1 ----
        const char* vbb = (const char*)smem + 32768 + cur * 16384;  // FIXED: V dbuf base (bytes)
        __builtin_amdgcn_s_setprio(1);
#pragma unroll
        for (int j = 0; j < 16; ++j) {
            bf16x8 vv = *(const bf16x8*)(vbb + vb0 + j * 1024);
            acc_o[0][j] = __builtin_amdgcn_mfma_f32_16x16x32_bf16(pa[0], vv, acc_o[0][j], 0, 0, 0);
            acc_o[1][j] = __builtin_amdgcn_mfma_f32_16x16x32_bf16(pa[1], vv, acc_o[1][j], 0, 0, 0);
        }
        acc_l[0] = __builtin_amdgcn_mfma_f32_16x16x32_bf16(pa[0], ones, acc_l[0], 0, 0, 0);
        acc_l[1] = __builtin_amdgcn_mfma_f32_16x16x32_bf16(pa[1], ones, acc_l[1], 0, 0, 0);
        __builtin_amdgcn_s_setprio(0);
        __syncthreads();
        cur ^= 1;
    }

    // ---- store unnormalized partials (O rows: q = f*16 + ks*4 + r) ----
    float* Ob = Op + ((size_t)combo * 4096 + q0 + wv * 32) * 256;
#pragma unroll
    for (int f = 0; f < 2; ++f)
#pragma unroll
        for (int j = 0; j < 16; ++j)
#pragma unroll
            for (int r = 0; r < 4; ++r)
                Ob[(size_t)(f * 16 + ks * 4 + r) * 256 + j * 16 + lc] = acc_o[f][j][r];
    if (lc == 0) {
        float* lb = lp + (size_t)combo * 4096 + q0 + wv * 32;
#pragma unroll
        for (int f = 0; f < 2; ++f)
#pragma unroll
            for (int r = 0; r < 4; ++r)
                lb[f * 16 + ks * 4 + r] = acc_l[f][r];
    }
}

// featT = (sum of 4 kvq partials) / (sum of l), cast bf16. float4-vectorized.
__global__ __launch_bounds__(256) void combine_k(const float* __restrict__ Op,
                                                 const float* __restrict__ lp,
                                                 short* __restrict__ o)
{
    int idx = blockIdx.x * 256 + threadIdx.x;
    size_t e = (size_t)idx * 4;
    int row = (int)(e >> 8);            // (b, q)
    int batch = row >> 12, ql = row & 4095;
    int c = (int)(e & 255);
    size_t lbase = (size_t)batch * 4 * 4096 + ql;
    float li = 1.0f / (lp[lbase] + lp[lbase + 4096] + lp[lbase + 8192] + lp[lbase + 12288]);
    size_t base = ((size_t)(batch * 4) * 4096 + ql) * 256 + c;
    const float4 a = *(const float4*)(Op + base);
    const float4 b = *(const float4*)(Op + base + 1048576);
    const float4 cc = *(const float4*)(Op + base + 2097152);
    const float4 d = *(const float4*)(Op + base + 3145728);
    short4 o4;
    o4.x = f2bf((a.x + b.x + cc.x + d.x) * li);
    o4.y = f2bf((a.y + b.y + cc.y + d.y) * li);
    o4.z = f2bf((a.z + b.z + cc.z + d.z) * li);
    o4.w = f2bf((a.w + b.w + cc.w + d.w) * li);
    *(short4*)(o + (size_t)row * 256 + c) = o4;
}

// ---------------------------------------------------------------------------
// x [B][256][4096] fp32 -> xT3 [(b,n)][768] bf16 hi/lo: [xh xh xl]
// ---------------------------------------------------------------------------
__global__ __launch_bounds__(256) void transpose_x_k(const float* __restrict__ x,
                                                     short* __restrict__ xT3)
{
    __shared__ float t[64][65];
    const int b = blockIdx.z, c0 = blockIdx.y * 64, n0 = blockIdx.x * 64;
    const int tid = threadIdx.x;
#pragma unroll
    for (int rep = 0; rep < 16; ++rep) {
        int idx = tid + rep * 256;
        int i = idx >> 6, j = idx & 63;
        t[i][j] = x[((size_t)(b * 256 + c0 + i)) * NPIX + n0 + j];
    }
    __syncthreads();
#pragma unroll
    for (int rep = 0; rep < 16; ++rep) {
        int idx = tid + rep * 256;
        int i = idx >> 6, j = idx & 63;
        float v = t[j][i];
        short hi = f2bf(v);
        short lo = f2bf(v - bf2f(hi));
        size_t rb = ((size_t)(b * NPIX + n0 + i)) * 768;
        xT3[rb + c0 + j] = hi;
        xT3[rb + 256 + c0 + j] = hi;
        xT3[rb + 512 + c0 + j] = lo;
    }
}

__global__ __launch_bounds__(256) void cvt_hilo3_k(const float* __restrict__ src,
                                                   short* __restrict__ dst)
{
    int idx = blockIdx.x * 256 + threadIdx.x;
    int o = idx >> 8, c = idx & 255;
    float v = src[idx];
    short hi = f2bf(v);
    short lo = f2bf(v - bf2f(hi));
    size_t rb = (size_t)o * 768;
    dst[rb + c] = hi;
    dst[rb + 256 + c] = lo;
    dst[rb + 512 + c] = hi;
}

__global__ __launch_bounds__(256) void cvt_k(const float* __restrict__ s,
                                             short* __restrict__ d, int n)
{
    int i = blockIdx.x * 256 + threadIdx.x;
    if (i < n) d[i] = f2bf(s[i]);
}

__global__ __launch_bounds__(256) void permw2_k(const float* __restrict__ l2w,
                                                short* __restrict__ w2)
{
    int idx = blockIdx.x * 256 + threadIdx.x;
    int t = idx >> 16;
    int rem = idx & 65535;
    int co = rem >> 8, ci = rem & 255;
    w2[idx] = f2bf(l2w[((size_t)(co * 256 + ci)) * 9 + t]);
}

// ---------------------------------------------------------------------------
__global__ __launch_bounds__(256) void pool_s1_k(const short* __restrict__ yT,
                                                 float* __restrict__ ppart)
{
    const int ns = blockIdx.x, cg = blockIdx.y, b = blockIdx.z;
    const int tid = threadIdx.x;
    const int cl = tid & 63, ph = tid >> 6;
    float s = 0.f;
    const int nbase = ns * 256;
    for (int n = ph; n < 256; n += 4)
        s += bf2f(yT[((size_t)(b * NPIX + nbase + n)) * 256 + cg * 64 + cl]);
    __shared__ float ls[4][64];
    ls[ph][cl] = s;
    __syncthreads();
    if (ph == 0)
        ppart[((size_t)(b * 4 + cg) * 16 + ns) * 64 + cl] =
            ls[0][cl] + ls[1][cl] + ls[2][cl] + ls[3][cl];
}

__global__ __launch_bounds__(256) void pool_s2_k(const float* __restrict__ ppart,
                                                 float* __restrict__ pooled)
{
    const int b = blockIdx.x;
    const int c = threadIdx.x;
    const int cg = c >> 6, cl = c & 63;
    float s = 0.f;
#pragma unroll
    for (int ns = 0; ns < 16; ++ns)
        s += ppart[((size_t)(b * 4 + cg) * 16 + ns) * 64 + cl];
    pooled[b * 256 + c] = s * (1.0f / NPIX);
}

__global__ __launch_bounds__(256) void se_k(
    const float* __restrict__ pooled,
    const float* __restrict__ r1w, const float* __restrict__ r1b,
    const float* __restrict__ g, const float* __restrict__ bb,
    const float* __restrict__ m, const float* __restrict__ vv,
    const float* __restrict__ r2w, const float* __restrict__ r2b,
    float* __restrict__ yr)
{
    const int b = blockIdx.x;
    const int tid = threadIdx.x;
    __shared__ float p[256], hbuf[128];
    p[tid] = pooled[b * 256 + tid];
    __syncthreads();
    if (tid < 128) {
        float a = r1b[tid];
        for (int ci = 0; ci < 256; ++ci) a = fmaf(r1w[tid * 256 + ci], p[ci], a);
        float s = g[tid] * rsqrtf(vv[tid] + EPSBN);
        float t = bb[tid] - m[tid] * s;
        hbuf[tid] = fmaxf(s * a + t, 0.f);
    }
    __syncthreads();
    float a = r2b[tid];
    for (int c2 = 0; c2 < 128; ++c2) a = fmaf(r2w[tid * 128 + c2], hbuf[c2], a);
    yr[b * 256 + tid] = a;
}

// ---------------------------------------------------------------------------
extern "C" void kernel_launch(void* const* d_in, const int* in_sizes, int n_in,
                              void* d_out, int out_size, void* d_ws, size_t ws_size,
                              hipStream_t stream)
{
    const float* x    = (const float*)d_in[0];
    const float* wq   = (const float*)d_in[1];
    const float* bq   = (const float*)d_in[2];
    const float* wk   = (const float*)d_in[3];
    const float* bk   = (const float*)d_in[4];
    const float* wvp  = (const float*)d_in[5];
    const float* bv   = (const float*)d_in[6];
    const float* d1w  = (const float*)d_in[7];
    const float* d1b  = (const float*)d_in[8];
    const float* bn1g = (const float*)d_in[9];
    const float* bn1b = (const float*)d_in[10];
    const float* bn1m = (const float*)d_in[11];
    const float* bn1v = (const float*)d_in[12];
    const float* lbn1g = (const float*)d_in[13];
    const float* lbn1b = (const float*)d_in[14];
    const float* lbn1m = (const float*)d_in[15];
    const float* lbn1v = (const float*)d_in[16];
    const float* lbn2g = (const float*)d_in[17];
    const float* lbn2b = (const float*)d_in[18];
    const float* lbn2m = (const float*)d_in[19];
    const float* lbn2v = (const float*)d_in[20];
    const float* lbn3g = (const float*)d_in[21];
    const float* lbn3b = (const float*)d_in[22];
    const float* lbn3m = (const float*)d_in[23];
    const float* lbn3v = (const float*)d_in[24];
    const float* l1w  = (const float*)d_in[25];
    const float* l1b  = (const float*)d_in[26];
    const float* l2w  = (const float*)d_in[27];
    const float* l2b  = (const float*)d_in[28];
    const float* l3w  = (const float*)d_in[29];
    const float* l3b  = (const float*)d_in[30];
    const float* r1w  = (const float*)d_in[31];
    const float* r1b  = (const float*)d_in[32];
    const float* rbng = (const float*)d_in[33];
    const float* rbnb = (const float*)d_in[34];
    const float* rbnm = (const float*)d_in[35];
    const float* rbnv = (const float*)d_in[36];
    const float* r2w  = (const float*)d_in[37];
    const float* r2b  = (const float*)d_in[38];

    float* out = (float*)d_out;
    char* wsb = (char*)d_ws;

    // ---- workspace layout (peak ~124 MB; >=131 MB proven usable) ----
    short* xT3  = (short*)(wsb);                    // 0-24 MB (dead after proj)
    short* qbuf = (short*)(wsb + (24ull << 20));    // 24-32
    short* kbuf = (short*)(wsb + (32ull << 20));    // 32-40
    short* vbuf = (short*)(wsb + (40ull << 20));    // 40-48
    float* Opart= (float*)(wsb + (48ull << 20));    // 48-112 (dead after combine)
    short* featT= (short*)(wsb + (112ull << 20));   // 112-120
    float* lpart= (float*)(wsb + (120ull << 20));   // 256 KB
    short* yT   = (short*)(wsb + (48ull << 20));    // overlay Opart post-combine
    short* t1pad= (short*)(wsb + (56ull << 20));    // overlay, 8.51 MB
    short* t2T  = (short*)(wsb + (65ull << 20));    // overlay
    short* wqk3 = (short*)(wsb + (121ull << 20));   // 384 KB
    short* wvb  = wqk3 + 196608;                    // 128 KB each
    short* d1wb = wvb + 65536;
    short* l1wb = d1wb + 65536;
    short* l3wb = l1wb + 65536;
    short* w2b  = l3wb + 65536;                     // 1.125 MB
    float* pooled = (float*)(wsb + (123ull << 20) + (512ull << 10));
    float* yrb  = pooled + 1024;
    float* ppart= yrb + 1024;                       // 64 KB

    dim3 blk(256);

    // ---- setup: transpose/convert ----
    transpose_x_k<<<dim3(64, 4, 4), blk, 0, stream>>>(x, xT3);
    cvt_hilo3_k<<<128, blk, 0, stream>>>(wq, wqk3);
    cvt_hilo3_k<<<128, blk, 0, stream>>>(wk, wqk3 + (size_t)128 * 768);
    cvt_k<<<256, blk, 0, stream>>>(wvp, wvb, 65536);
    cvt_k<<<256, blk, 0, stream>>>(d1w, d1wb, 65536);
    cvt_k<<<256, blk, 0, stream>>>(l1w, l1wb, 65536);
    cvt_k<<<256, blk, 0, stream>>>(l3w, l3wb, 65536);
    permw2_k<<<2304, blk, 0, stream>>>(l2w, w2b);

    // ---- projections ----
    gbt_k<1, 64, 64><<<dim3(4, 256), blk, 0, stream>>>(xT3, 768, wqk3, 768, qbuf, kbuf, 768,
        bq, bk, nullptr, nullptr, nullptr, nullptr, nullptr, nullptr);
    gbt_k<2, 64, 64><<<dim3(256, 4), blk, 0, stream>>>(wvb, 256, xT3, 768, vbuf, nullptr, 256,
        bv, nullptr, nullptr, nullptr, nullptr, nullptr, nullptr, nullptr);

    // ---- fused flash attention (kv-quarter partials) + combine ----
    flash_k<<<256, dim3(512), 0, stream>>>(qbuf, kbuf, vbuf, Opart, lpart);
    combine_k<<<4096, blk, 0, stream>>>(Opart, lpart, featT);

    // ---- gate: yT = feat * sigmoid(relu(bn1(d1(feat)))) ----
    gbt_k<3, 64, 64><<<dim3(4, 256), blk, 0, stream>>>(featT, 256, d1wb, 256, yT, nullptr, 256,
        d1b, nullptr, bn1g, bn1b, bn1m, bn1v, featT, nullptr);

    hipMemsetAsync(t1pad, 0, (size_t)4 * 4356 * 256 * 2, stream);

    // ---- SE branch ----
    pool_s1_k<<<dim3(16, 4, 4), blk, 0, stream>>>(yT, ppart);
    pool_s2_k<<<4, blk, 0, stream>>>(ppart, pooled);
    se_k<<<4, blk, 0, stream>>>(pooled, r1w, r1b, rbng, rbnb, rbnm, rbnv, r2w, r2b, yrb);

    // ---- left branch ----
    gbt_k<4, 64, 64><<<dim3(4, 256), blk, 0, stream>>>(yT, 256, l1wb, 256, t1pad, nullptr, 256,
        l1b, nullptr, lbn1g, lbn1b, lbn1m, lbn1v, nullptr, nullptr);
    gbt_k<5, 128, 64><<<dim3(4, 128), blk, 0, stream>>>(t1pad, 256, w2b, 256, t2T, nullptr, 2304,
        l2b, nullptr, lbn2g, lbn2b, lbn2m, lbn2v, nullptr, nullptr);

    // ---- final: out = feat * sigmoid(relu(bn3(l3(t2))) + yr) ----
    gbt_k<6, 64, 64><<<dim3(256, 4), blk, 0, stream>>>(l3wb, 256, t2T, 256, out, nullptr, 256,
        l3b, nullptr, lbn3g, lbn3b, lbn3m, lbn3v, featT, yrb);
}

// Round 10
// 250.483 us; speedup vs baseline: 7.2942x; 1.0558x over previous
//
#include <hip/hip_runtime.h>
#include <math.h>

#define NPIX 4096
#define EPSBN 1e-5f

typedef __attribute__((ext_vector_type(8))) short bf16x8;
typedef __attribute__((ext_vector_type(4))) float f32x4;

__device__ __forceinline__ float sigmoidf_(float x) { return 1.0f / (1.0f + expf(-x)); }

__device__ __forceinline__ short f2bf(float f) {
    unsigned u = __float_as_uint(f);
    u += 0x7fffu + ((u >> 16) & 1u);
    return (short)(u >> 16);
}
__device__ __forceinline__ float bf2f(short s) {
    return __uint_as_float(((unsigned)(unsigned short)s) << 16);
}
__device__ __forceinline__ int pk2(float lo, float hi) {
    return (int)(unsigned short)f2bf(lo) | ((int)(unsigned short)f2bf(hi) << 16);
}

__device__ __forceinline__ void gl_lds16(const short* g, short* l) {
    __builtin_amdgcn_global_load_lds(
        (const __attribute__((address_space(1))) void*)g,
        (__attribute__((address_space(3))) void*)l, 16, 0, 0);
}

// ---------------------------------------------------------------------------
// Universal bf16 GEMM-BT:  C = epi( A[M][K] * B[N][K]^T )
// Tile BM x BN, 4 waves, double-buffered LDS, 1-deep prefetch.
// ---------------------------------------------------------------------------
template <int EPI, int BM, int BN>
__global__ __launch_bounds__(256) void gbt_k(
    const short* __restrict__ A, int lda,
    const short* __restrict__ B, int ldb,
    void* __restrict__ Cv, void* __restrict__ Cv2, int Ktot,
    const float* __restrict__ bias, const float* __restrict__ bias2,
    const float* __restrict__ bng, const float* __restrict__ bnb,
    const float* __restrict__ bnm, const float* __restrict__ bnv,
    const short* __restrict__ aux, const float* __restrict__ yrp)
{
    constexpr int FI = BM / 32, FJ = BN / 32;
    constexpr int SA = BM / 64, SB = BN / 64;
    __shared__ alignas(16) short lsA[2 * BM * 32];
    __shared__ alignas(16) short lsB[2 * BN * 32];

    const int tid = threadIdx.x;
    const int l = tid & 63;
    const int wv = tid >> 6;
    const int wm = wv >> 1, wn = wv & 1;
    const int m0 = blockIdx.y * BM;
    const int n0 = blockIdx.x * BN;

    const short* arow[2];
    const short* brow[2];
#pragma unroll
    for (int s = 0; s < SA; ++s) {
        int r = wv * (16 * SA) + s * 16 + (l >> 2);
        int sd = (l & 3) ^ ((r >> 1) & 3);
        if (EPI == 5) {
            int g = m0 + r;
            int p = (g >> 12) * 4356 + (((g & 4095) >> 6) + 1) * 66 + ((g & 63) + 1);
            arow[s] = A + (size_t)p * 256 + (sd << 3);
        } else {
            arow[s] = A + (size_t)(m0 + r) * lda + (sd << 3);
        }
    }
#pragma unroll
    for (int s = 0; s < SB; ++s) {
        int r = wv * (16 * SB) + s * 16 + (l >> 2);
        int sd = (l & 3) ^ ((r >> 1) & 3);
        brow[s] = B + (size_t)(n0 + r) * ldb + (sd << 3);
    }

    const int ks = l >> 4;
    const int lc = l & 15;
    int aoff[FI], boff[FJ];
#pragma unroll
    for (int f = 0; f < FI; ++f) {
        int ra = wm * (BM / 2) + f * 16 + lc;
        aoff[f] = ra * 64 + ((ks ^ ((ra >> 1) & 3)) << 4);
    }
#pragma unroll
    for (int f = 0; f < FJ; ++f) {
        int rb = wn * (BN / 2) + f * 16 + lc;
        boff[f] = rb * 64 + ((ks ^ ((rb >> 1) & 3)) << 4);
    }

    auto stage = [&](int d, int k0l) {
        int eA, eB;
        if (EPI == 5) {
            int t = k0l >> 8, ci0 = k0l & 255;
            eA = ((t / 3) * 66 + (t % 3) - 67) * 256 + ci0;
            eB = t * 65536 + ci0;
        } else {
            eA = k0l; eB = k0l;
        }
        short* dA = lsA + d * (BM * 32) + wv * (SA * 512);
        short* dB = lsB + d * (BN * 32) + wv * (SB * 512);
#pragma unroll
        for (int s = 0; s < SA; ++s) gl_lds16(arow[s] + eA, dA + s * 512);
#pragma unroll
        for (int s = 0; s < SB; ++s) gl_lds16(brow[s] + eB, dB + s * 512);
    };

    f32x4 acc[FI][FJ] = {};
    const int nt = Ktot >> 5;

    stage(0, 0);
    __syncthreads();
    int cur = 0;
    for (int t = 0; t < nt; ++t) {
        if (t + 1 < nt) stage(cur ^ 1, (t + 1) << 5);
        bf16x8 af[FI], bfr[FJ];
#pragma unroll
        for (int f = 0; f < FI; ++f)
            af[f] = *(const bf16x8*)((const char*)lsA + cur * (BM * 64) + aoff[f]);
#pragma unroll
        for (int f = 0; f < FJ; ++f)
            bfr[f] = *(const bf16x8*)((const char*)lsB + cur * (BN * 64) + boff[f]);
#pragma unroll
        for (int i = 0; i < FI; ++i)
#pragma unroll
            for (int j = 0; j < FJ; ++j)
                acc[i][j] = __builtin_amdgcn_mfma_f32_16x16x32_bf16(af[i], bfr[j], acc[i][j], 0, 0, 0);
        __syncthreads();
        cur ^= 1;
    }

    const int lr = (l >> 4) << 2;
#pragma unroll
    for (int i = 0; i < FI; ++i) {
        const int rowl = wm * (BM / 2) + i * 16 + lr;
#pragma unroll
        for (int j = 0; j < FJ; ++j) {
            const int coll = n0 + wn * (BN / 2) + j * 16 + lc;

            float sc = 0.f, tc = 0.f, bi = 0.f;
            if constexpr (EPI == 1) {
                bi = (coll < 128) ? bias[coll] : bias2[coll - 128];
            } else if constexpr (EPI == 3 || EPI == 4 || EPI == 5) {
                sc = bng[coll] * rsqrtf(bnv[coll] + EPSBN);
                tc = bnb[coll] - bnm[coll] * sc;
                bi = bias[coll];
            }

#pragma unroll
            for (int r = 0; r < 4; ++r) {
                const int row = m0 + rowl + r;
                float vvv = acc[i][j][r];
                if constexpr (EPI == 1) {
                    float val = vvv + bi;
                    short hi = f2bf(val);
                    short lo = f2bf(val - bf2f(hi));
                    size_t rb = (size_t)row * 256;
                    if (coll < 128) {
                        short* qb_ = (short*)Cv;
                        qb_[rb + coll] = hi;
                        qb_[rb + 128 + coll] = lo;
                    } else {
                        short* kb_ = (short*)Cv2;
                        int c = coll - 128;
                        kb_[rb + c] = hi;
                        kb_[rb + 128 + c] = lo;
                    }
                } else if constexpr (EPI == 2) {
                    int bb = coll >> 12;
                    ((short*)Cv)[((size_t)bb * 256 + row) * 4096 + (coll & 4095)] = f2bf(vvv + bias[row]);
                } else if constexpr (EPI == 3) {
                    float g = sigmoidf_(fmaxf(sc * (vvv + bi) + tc, 0.f));
                    float fv = bf2f(aux[(size_t)row * 256 + coll]);
                    ((short*)Cv)[(size_t)row * 256 + coll] = f2bf(fv * g);
                } else if constexpr (EPI == 4) {
                    float rv = fmaxf(sc * (vvv + bi) + tc, 0.f);
                    int bb = row >> 12, n = row & 4095;
                    int pr = bb * 4356 + ((n >> 6) + 1) * 66 + (n & 63) + 1;
                    ((short*)Cv)[(size_t)pr * 256 + coll] = f2bf(rv);
                } else if constexpr (EPI == 5) {
                    float rv = fmaxf(sc * (vvv + bi) + tc, 0.f);
                    ((short*)Cv)[(size_t)row * 256 + coll] = f2bf(rv);
                } else if constexpr (EPI == 6) {
                    float s6 = bng[row] * rsqrtf(bnv[row] + EPSBN);
                    float t6 = bnb[row] - bnm[row] * s6;
                    int bb = coll >> 12;
                    float yl = fmaxf(s6 * (vvv + bias[row]) + t6, 0.f);
                    float sg = sigmoidf_(yl + yrp[bb * 256 + row]);
                    float fv = bf2f(aux[(size_t)coll * 256 + row]);
                    ((float*)Cv)[((size_t)bb * 256 + row) * 4096 + (coll & 4095)] = fv * sg;
                }
            }
        }
    }
}

// ---------------------------------------------------------------------------
// Flash attention v2: swapped QK + register P-transpose via ds_bpermute.
// 512 thr / 8 waves / 32 q per wave / 256 q per block; kv-quarter per block.
// No-max softmax. Outputs UNNORMALIZED bf16 partials per kvq + fp32 row sums.
// ---------------------------------------------------------------------------
__global__ __launch_bounds__(512, 2) void flash_k(
    const short* __restrict__ Q, const short* __restrict__ K,
    const short* __restrict__ V, short* __restrict__ Op, float* __restrict__ lp)
{
    __shared__ alignas(16) short smem[32768];
    // BYTES: K dbuf [0, 32768) | V dbuf [32768, 65536)

    const int tid = threadIdx.x;
    const int l = tid & 63;
    const int wv = tid >> 6;              // 0..7
    const int bid = blockIdx.x;
    const int combo = bid & 15;           // batch*4 + kvq
    const int batch = combo >> 2;
    const int kvq = combo & 3;
    const int q0 = (bid >> 4) * 256;
    const int kv0 = kvq * 1024;

    const short* Qb = Q + (size_t)batch * 4096 * 256;
    const short* Kb = K + (size_t)batch * 4096 * 256;
    const short* Vb = V + (size_t)batch * 256 * 4096;

    const int lc = l & 15, ks = l >> 4;

    // ---- Q fragments direct from global (B-operand: col=q=lc, k-chunk=ks) ----
    bf16x8 bq[2][8];
#pragma unroll
    for (int f = 0; f < 2; ++f)
#pragma unroll
        for (int cc = 0; cc < 8; ++cc)
            bq[f][cc] = *(const bf16x8*)(Qb +
                (size_t)(q0 + wv * 32 + f * 16 + lc) * 256 + cc * 32 + ks * 8);

    // ---- K/V staging ----
    const short* ksrc[2]; short* kdst[2];
    const short* vsrc[2]; short* vdst[2];
#pragma unroll
    for (int i = 0; i < 2; ++i) {
        int row = wv * 4 + i * 2 + (l >> 5);
        int s = l & 31;
        int g = s ^ (row & 7);
        ksrc[i] = Kb + (size_t)(kv0 + row) * 256 + g * 8;
        kdst[i] = smem + wv * 1024 + i * 512;
        int c = wv * 32 + i * 16 + (l >> 2);
        int sv = l & 3;
        int gv = sv ^ ((c >> 1) & 3);
        vsrc[i] = Vb + (size_t)c * 4096 + kv0 + gv * 8;
        vdst[i] = smem + 16384 + wv * 1024 + i * 512;
    }
    auto stageKV = [&](int buf, int t) {
#pragma unroll
        for (int i = 0; i < 2; ++i) gl_lds16(ksrc[i] + (size_t)t * 8192, kdst[i] + buf * 8192);
#pragma unroll
        for (int i = 0; i < 2; ++i) gl_lds16(vsrc[i] + t * 32, vdst[i] + buf * 8192);
    };

    stageKV(0, 0);
    __syncthreads();

    const int kro = lc * 512;
    const int kxr = lc & 7;
    const int vb0 = lc * 64 + ((ks ^ ((lc >> 1) & 3)) << 4);
    const int addrA = (((ks & 1) * 2) * 16 + lc) * 4;
    const int addrB = addrA + 64;

    bf16x8 ones;
#pragma unroll
    for (int e = 0; e < 8; ++e) ones[e] = (short)0x3F80;

    f32x4 acc_o[2][16] = {};
    f32x4 acc_l[2] = {};

    int cur = 0;
    for (int t = 0; t < 32; ++t) {
        if (t + 1 < 32) stageKV(cur ^ 1, t + 1);

        // ---- S^T = K·Q^T (hi/lo 3-term) ----
        const char* kb_ = (const char*)smem + cur * 16384;
        f32x4 s00 = {}, s01 = {}, s10 = {}, s11 = {};
        __builtin_amdgcn_s_setprio(1);
#pragma unroll
        for (int jc = 0; jc < 4; ++jc) {
#pragma unroll
            for (int kvf = 0; kvf < 2; ++kvf) {
                const char* rb_ = kb_ + kro + kvf * 8192;
                bf16x8 kh_ = *(const bf16x8*)(rb_ + ((((jc * 4) + ks) ^ kxr) << 4));
                bf16x8 kl_ = *(const bf16x8*)(rb_ + (((((jc + 4) * 4) + ks) ^ kxr) << 4));
                f32x4& sA = kvf ? s01 : s00;
                f32x4& sB = kvf ? s11 : s10;
                sA = __builtin_amdgcn_mfma_f32_16x16x32_bf16(kh_, bq[0][jc], sA, 0, 0, 0);
                sB = __builtin_amdgcn_mfma_f32_16x16x32_bf16(kh_, bq[1][jc], sB, 0, 0, 0);
                sA = __builtin_amdgcn_mfma_f32_16x16x32_bf16(kl_, bq[0][jc], sA, 0, 0, 0);
                sB = __builtin_amdgcn_mfma_f32_16x16x32_bf16(kl_, bq[1][jc], sB, 0, 0, 0);
                sA = __builtin_amdgcn_mfma_f32_16x16x32_bf16(kh_, bq[0][jc + 4], sA, 0, 0, 0);
                sB = __builtin_amdgcn_mfma_f32_16x16x32_bf16(kh_, bq[1][jc + 4], sB, 0, 0, 0);
            }
        }
        __builtin_amdgcn_s_setprio(0);

        // ---- P = exp(S); register transpose via ds_bpermute ----
        bf16x8 pa[2];
#pragma unroll
        for (int f = 0; f < 2; ++f) {
            const f32x4& sa = f ? s10 : s00;
            const f32x4& sb = f ? s11 : s01;
            int u0 = pk2(__expf(sa[0]), __expf(sa[1]));
            int u1 = pk2(__expf(sa[2]), __expf(sa[3]));
            int u2 = pk2(__expf(sb[0]), __expf(sb[1]));
            int u3 = pk2(__expf(sb[2]), __expf(sb[3]));
            int a0 = __builtin_amdgcn_ds_bpermute(addrA, u0);
            int b0 = __builtin_amdgcn_ds_bpermute(addrA, u2);
            int a1 = __builtin_amdgcn_ds_bpermute(addrA, u1);
            int b1 = __builtin_amdgcn_ds_bpermute(addrA, u3);
            int a2 = __builtin_amdgcn_ds_bpermute(addrB, u0);
            int b2 = __builtin_amdgcn_ds_bpermute(addrB, u2);
            int a3 = __builtin_amdgcn_ds_bpermute(addrB, u1);
            int b3 = __builtin_amdgcn_ds_bpermute(addrB, u3);
            union { int i4[4]; bf16x8 v; } un;
            un.i4[0] = (ks < 2) ? a0 : b0;
            un.i4[1] = (ks < 2) ? a1 : b1;
            un.i4[2] = (ks < 2) ? a2 : b2;
            un.i4[3] = (ks < 2) ? a3 : b3;
            pa[f] = un.v;
        }

        // ---- O += P·V ; l += P·1 ----
        const char* vbb = (const char*)smem + 32768 + cur * 16384;
        __builtin_amdgcn_s_setprio(1);
#pragma unroll
        for (int j = 0; j < 16; ++j) {
            bf16x8 vv = *(const bf16x8*)(vbb + vb0 + j * 1024);
            acc_o[0][j] = __builtin_amdgcn_mfma_f32_16x16x32_bf16(pa[0], vv, acc_o[0][j], 0, 0, 0);
            acc_o[1][j] = __builtin_amdgcn_mfma_f32_16x16x32_bf16(pa[1], vv, acc_o[1][j], 0, 0, 0);
        }
        acc_l[0] = __builtin_amdgcn_mfma_f32_16x16x32_bf16(pa[0], ones, acc_l[0], 0, 0, 0);
        acc_l[1] = __builtin_amdgcn_mfma_f32_16x16x32_bf16(pa[1], ones, acc_l[1], 0, 0, 0);
        __builtin_amdgcn_s_setprio(0);
        __syncthreads();
        cur ^= 1;
    }

    // ---- store unnormalized bf16 partials ----
    short* Ob = Op + ((size_t)combo * 4096 + q0 + wv * 32) * 256;
#pragma unroll
    for (int f = 0; f < 2; ++f)
#pragma unroll
        for (int j = 0; j < 16; ++j)
#pragma unroll
            for (int r = 0; r < 4; ++r)
                Ob[(size_t)(f * 16 + ks * 4 + r) * 256 + j * 16 + lc] = f2bf(acc_o[f][j][r]);
    if (lc == 0) {
        float* lb = lp + (size_t)combo * 4096 + q0 + wv * 32;
#pragma unroll
        for (int f = 0; f < 2; ++f)
#pragma unroll
            for (int r = 0; r < 4; ++r)
                lb[f * 16 + ks * 4 + r] = acc_l[f][r];
    }
}

// featT = (sum of 4 bf16 kvq partials) / (sum of l), cast bf16.
__global__ __launch_bounds__(256) void combine_k(const short* __restrict__ Op,
                                                 const float* __restrict__ lp,
                                                 short* __restrict__ o)
{
    int idx = blockIdx.x * 256 + threadIdx.x;
    size_t e = (size_t)idx * 4;
    int row = (int)(e >> 8);            // (b, q)
    int batch = row >> 12, ql = row & 4095;
    int c = (int)(e & 255);
    size_t lbase = (size_t)batch * 4 * 4096 + ql;
    float li = 1.0f / (lp[lbase] + lp[lbase + 4096] + lp[lbase + 8192] + lp[lbase + 12288]);
    size_t base = ((size_t)(batch * 4) * 4096 + ql) * 256 + c;
    const short4 a = *(const short4*)(Op + base);
    const short4 b = *(const short4*)(Op + base + 1048576);
    const short4 cc = *(const short4*)(Op + base + 2097152);
    const short4 d = *(const short4*)(Op + base + 3145728);
    short4 o4;
    o4.x = f2bf((bf2f(a.x) + bf2f(b.x) + bf2f(cc.x) + bf2f(d.x)) * li);
    o4.y = f2bf((bf2f(a.y) + bf2f(b.y) + bf2f(cc.y) + bf2f(d.y)) * li);
    o4.z = f2bf((bf2f(a.z) + bf2f(b.z) + bf2f(cc.z) + bf2f(d.z)) * li);
    o4.w = f2bf((bf2f(a.w) + bf2f(b.w) + bf2f(cc.w) + bf2f(d.w)) * li);
    *(short4*)(o + (size_t)row * 256 + c) = o4;
}

// ---------------------------------------------------------------------------
// x [B][256][4096] fp32 -> xT3 [(b,n)][768] bf16 hi/lo: [xh xh xl]
// ---------------------------------------------------------------------------
__global__ __launch_bounds__(256) void transpose_x_k(const float* __restrict__ x,
                                                     short* __restrict__ xT3)
{
    __shared__ float t[64][65];
    const int b = blockIdx.z, c0 = blockIdx.y * 64, n0 = blockIdx.x * 64;
    const int tid = threadIdx.x;
#pragma unroll
    for (int rep = 0; rep < 16; ++rep) {
        int idx = tid + rep * 256;
        int i = idx >> 6, j = idx & 63;
        t[i][j] = x[((size_t)(b * 256 + c0 + i)) * NPIX + n0 + j];
    }
    __syncthreads();
#pragma unroll
    for (int rep = 0; rep < 16; ++rep) {
        int idx = tid + rep * 256;
        int i = idx >> 6, j = idx & 63;
        float v = t[j][i];
        short hi = f2bf(v);
        short lo = f2bf(v - bf2f(hi));
        size_t rb = ((size_t)(b * NPIX + n0 + i)) * 768;
        xT3[rb + c0 + j] = hi;
        xT3[rb + 256 + c0 + j] = hi;
        xT3[rb + 512 + c0 + j] = lo;
    }
}

// ---------------------------------------------------------------------------
// Merged setup: wq/wk hi-lo-hi, 4 plain cvts, l2w permute. Grid 3584.
// ---------------------------------------------------------------------------
__global__ __launch_bounds__(256) void prep_k(
    const float* __restrict__ wq, const float* __restrict__ wk,
    const float* __restrict__ wvp, const float* __restrict__ d1w,
    const float* __restrict__ l1w, const float* __restrict__ l3w,
    const float* __restrict__ l2w,
    short* __restrict__ wqk3, short* __restrict__ wvb, short* __restrict__ d1wb,
    short* __restrict__ l1wb, short* __restrict__ l3wb, short* __restrict__ w2b)
{
    const int b = blockIdx.x;
    const int tid = threadIdx.x;
    if (b < 256) {
        int idx = b * 256 + tid;
        int o = idx >> 8, c = idx & 255;
        const float* src = (o < 128) ? wq : wk;
        float v = src[(o & 127) * 256 + c];
        short hi = f2bf(v);
        short lo = f2bf(v - bf2f(hi));
        size_t rb = (size_t)o * 768;
        wqk3[rb + c] = hi;
        wqk3[rb + 256 + c] = lo;
        wqk3[rb + 512 + c] = hi;
    } else if (b < 1280) {
        int g = (b - 256) >> 8;
        int i = ((b - 256) & 255) * 256 + tid;
        const float* s = g == 0 ? wvp : g == 1 ? d1w : g == 2 ? l1w : l3w;
        short* d = g == 0 ? wvb : g == 1 ? d1wb : g == 2 ? l1wb : l3wb;
        d[i] = f2bf(s[i]);
    } else {
        int idx = (b - 1280) * 256 + tid;
        int t = idx >> 16;
        int rem = idx & 65535;
        int co = rem >> 8, ci = rem & 255;
        w2b[idx] = f2bf(l2w[((size_t)(co * 256 + ci)) * 9 + t]);
    }
}

// ---------------------------------------------------------------------------
__global__ __launch_bounds__(256) void pool_s1_k(const short* __restrict__ yT,
                                                 float* __restrict__ ppart)
{
    const int ns = blockIdx.x, cg = blockIdx.y, b = blockIdx.z;
    const int tid = threadIdx.x;
    const int cl = tid & 63, ph = tid >> 6;
    float s = 0.f;
    const int nbase = ns * 256;
    for (int n = ph; n < 256; n += 4)
        s += bf2f(yT[((size_t)(b * NPIX + nbase + n)) * 256 + cg * 64 + cl]);
    __shared__ float ls[4][64];
    ls[ph][cl] = s;
    __syncthreads();
    if (ph == 0)
        ppart[((size_t)(b * 4 + cg) * 16 + ns) * 64 + cl] =
            ls[0][cl] + ls[1][cl] + ls[2][cl] + ls[3][cl];
}

__global__ __launch_bounds__(256) void pool_s2_k(const float* __restrict__ ppart,
                                                 float* __restrict__ pooled)
{
    const int b = blockIdx.x;
    const int c = threadIdx.x;
    const int cg = c >> 6, cl = c & 63;
    float s = 0.f;
#pragma unroll
    for (int ns = 0; ns < 16; ++ns)
        s += ppart[((size_t)(b * 4 + cg) * 16 + ns) * 64 + cl];
    pooled[b * 256 + c] = s * (1.0f / NPIX);
}

__global__ __launch_bounds__(256) void se_k(
    const float* __restrict__ pooled,
    const float* __restrict__ r1w, const float* __restrict__ r1b,
    const float* __restrict__ g, const float* __restrict__ bb,
    const float* __restrict__ m, const float* __restrict__ vv,
    const float* __restrict__ r2w, const float* __restrict__ r2b,
    float* __restrict__ yr)
{
    const int b = blockIdx.x;
    const int tid = threadIdx.x;
    __shared__ float p[256], hbuf[128];
    p[tid] = pooled[b * 256 + tid];
    __syncthreads();
    if (tid < 128) {
        float a = r1b[tid];
        for (int ci = 0; ci < 256; ++ci) a = fmaf(r1w[tid * 256 + ci], p[ci], a);
        float s = g[tid] * rsqrtf(vv[tid] + EPSBN);
        float t = bb[tid] - m[tid] * s;
        hbuf[tid] = fmaxf(s * a + t, 0.f);
    }
    __syncthreads();
    float a = r2b[tid];
    for (int c2 = 0; c2 < 128; ++c2) a = fmaf(r2w[tid * 128 + c2], hbuf[c2], a);
    yr[b * 256 + tid] = a;
}

// ---------------------------------------------------------------------------
extern "C" void kernel_launch(void* const* d_in, const int* in_sizes, int n_in,
                              void* d_out, int out_size, void* d_ws, size_t ws_size,
                              hipStream_t stream)
{
    const float* x    = (const float*)d_in[0];
    const float* wq   = (const float*)d_in[1];
    const float* bq   = (const float*)d_in[2];
    const float* wk   = (const float*)d_in[3];
    const float* bk   = (const float*)d_in[4];
    const float* wvp  = (const float*)d_in[5];
    const float* bv   = (const float*)d_in[6];
    const float* d1w  = (const float*)d_in[7];
    const float* d1b  = (const float*)d_in[8];
    const float* bn1g = (const float*)d_in[9];
    const float* bn1b = (const float*)d_in[10];
    const float* bn1m = (const float*)d_in[11];
    const float* bn1v = (const float*)d_in[12];
    const float* lbn1g = (const float*)d_in[13];
    const float* lbn1b = (const float*)d_in[14];
    const float* lbn1m = (const float*)d_in[15];
    const float* lbn1v = (const float*)d_in[16];
    const float* lbn2g = (const float*)d_in[17];
    const float* lbn2b = (const float*)d_in[18];
    const float* lbn2m = (const float*)d_in[19];
    const float* lbn2v = (const float*)d_in[20];
    const float* lbn3g = (const float*)d_in[21];
    const float* lbn3b = (const float*)d_in[22];
    const float* lbn3m = (const float*)d_in[23];
    const float* lbn3v = (const float*)d_in[24];
    const float* l1w  = (const float*)d_in[25];
    const float* l1b  = (const float*)d_in[26];
    const float* l2w  = (const float*)d_in[27];
    const float* l2b  = (const float*)d_in[28];
    const float* l3w  = (const float*)d_in[29];
    const float* l3b  = (const float*)d_in[30];
    const float* r1w  = (const float*)d_in[31];
    const float* r1b  = (const float*)d_in[32];
    const float* rbng = (const float*)d_in[33];
    const float* rbnb = (const float*)d_in[34];
    const float* rbnm = (const float*)d_in[35];
    const float* rbnv = (const float*)d_in[36];
    const float* r2w  = (const float*)d_in[37];
    const float* r2b  = (const float*)d_in[38];

    float* out = (float*)d_out;
    char* wsb = (char*)d_ws;

    // ---- workspace layout ----
    short* xT3  = (short*)(wsb);                    // 0-24 MB (dead after proj)
    short* qbuf = (short*)(wsb + (24ull << 20));    // 24-32
    short* kbuf = (short*)(wsb + (32ull << 20));    // 32-40
    short* vbuf = (short*)(wsb + (40ull << 20));    // 40-48
    short* Opart= (short*)(wsb + (48ull << 20));    // 48-80 bf16 (dead after combine)
    short* featT= (short*)(wsb + (112ull << 20));   // 112-120
    float* lpart= (float*)(wsb + (120ull << 20));   // 256 KB
    short* yT   = (short*)(wsb + (48ull << 20));    // overlay Opart post-combine
    short* t1pad= (short*)(wsb + (56ull << 20));    // overlay, 8.51 MB
    short* t2T  = (short*)(wsb + (65ull << 20));    // overlay
    short* wqk3 = (short*)(wsb + (121ull << 20));   // 384 KB
    short* wvb  = wqk3 + 196608;                    // 128 KB each
    short* d1wb = wvb + 65536;
    short* l1wb = d1wb + 65536;
    short* l3wb = l1wb + 65536;
    short* w2b  = l3wb + 65536;                     // 1.125 MB
    float* pooled = (float*)(wsb + (123ull << 20) + (512ull << 10));
    float* yrb  = pooled + 1024;
    float* ppart= yrb + 1024;                       // 64 KB

    dim3 blk(256);

    // ---- setup ----
    transpose_x_k<<<dim3(64, 4, 4), blk, 0, stream>>>(x, xT3);
    prep_k<<<3584, blk, 0, stream>>>(wq, wk, wvp, d1w, l1w, l3w, l2w,
                                     wqk3, wvb, d1wb, l1wb, l3wb, w2b);

    // ---- projections ----
    gbt_k<1, 128, 64><<<dim3(4, 128), blk, 0, stream>>>(xT3, 768, wqk3, 768, qbuf, kbuf, 768,
        bq, bk, nullptr, nullptr, nullptr, nullptr, nullptr, nullptr);
    gbt_k<2, 64, 128><<<dim3(128, 4), blk, 0, stream>>>(wvb, 256, xT3, 768, vbuf, nullptr, 256,
        bv, nullptr, nullptr, nullptr, nullptr, nullptr, nullptr, nullptr);

    // ---- fused flash attention (kv-quarter bf16 partials) + combine ----
    flash_k<<<256, dim3(512), 0, stream>>>(qbuf, kbuf, vbuf, Opart, lpart);
    combine_k<<<4096, blk, 0, stream>>>(Opart, lpart, featT);

    // ---- gate: yT = feat * sigmoid(relu(bn1(d1(feat)))) ----
    gbt_k<3, 128, 64><<<dim3(4, 128), blk, 0, stream>>>(featT, 256, d1wb, 256, yT, nullptr, 256,
        d1b, nullptr, bn1g, bn1b, bn1m, bn1v, featT, nullptr);

    hipMemsetAsync(t1pad, 0, (size_t)4 * 4356 * 256 * 2, stream);

    // ---- SE branch ----
    pool_s1_k<<<dim3(16, 4, 4), blk, 0, stream>>>(yT, ppart);
    pool_s2_k<<<4, blk, 0, stream>>>(ppart, pooled);
    se_k<<<4, blk, 0, stream>>>(pooled, r1w, r1b, rbng, rbnb, rbnm, rbnv, r2w, r2b, yrb);

    // ---- left branch ----
    gbt_k<4, 128, 64><<<dim3(4, 128), blk, 0, stream>>>(yT, 256, l1wb, 256, t1pad, nullptr, 256,
        l1b, nullptr, lbn1g, lbn1b, lbn1m, lbn1v, nullptr, nullptr);
    gbt_k<5, 128, 64><<<dim3(4, 128), blk, 0, stream>>>(t1pad, 256, w2b, 256, t2T, nullptr, 2304,
        l2b, nullptr, lbn2g, lbn2b, lbn2m, lbn2v, nullptr, nullptr);

    // ---- final: out = feat * sigmoid(relu(bn3(l3(t2))) + yr) ----
    gbt_k<6, 64, 128><<<dim3(128, 4), blk, 0, stream>>>(l3wb, 256, t2T, 256, out, nullptr, 256,
        l3b, nullptr, lbn3g, lbn3b, lbn3m, lbn3v, featT, yrb);
}

// Round 11
// 224.598 us; speedup vs baseline: 8.1349x; 1.1153x over previous
//
#include <hip/hip_runtime.h>
#include <math.h>

#define NPIX 4096
#define EPSBN 1e-5f

typedef __attribute__((ext_vector_type(8))) short bf16x8;
typedef __attribute__((ext_vector_type(4))) float f32x4;

__device__ __forceinline__ float sigmoidf_(float x) { return 1.0f / (1.0f + expf(-x)); }

__device__ __forceinline__ short f2bf(float f) {
    unsigned u = __float_as_uint(f);
    u += 0x7fffu + ((u >> 16) & 1u);
    return (short)(u >> 16);
}
__device__ __forceinline__ float bf2f(short s) {
    return __uint_as_float(((unsigned)(unsigned short)s) << 16);
}
__device__ __forceinline__ int pk2(float lo, float hi) {
    return (int)(unsigned short)f2bf(lo) | ((int)(unsigned short)f2bf(hi) << 16);
}

__device__ __forceinline__ void gl_lds16(const short* g, short* l) {
    __builtin_amdgcn_global_load_lds(
        (const __attribute__((address_space(1))) void*)g,
        (__attribute__((address_space(3))) void*)l, 16, 0, 0);
}

// ---------------------------------------------------------------------------
// Universal bf16 GEMM-BT:  C = epi( A[M][K] * B[N][K]^T )
// Tile BM x BN, 4 waves, double-buffered LDS, 1-deep prefetch.
// EPI 1: A=xT2 [xh xl] rows (lda=512); K=768 via eA remap k<256?k:k-256.
// EPI 3: gate; also writes per-block column sums to Cv2 (pool stage 1 fused).
// ---------------------------------------------------------------------------
template <int EPI, int BM, int BN>
__global__ __launch_bounds__(256) void gbt_k(
    const short* __restrict__ A, int lda,
    const short* __restrict__ B, int ldb,
    void* __restrict__ Cv, void* __restrict__ Cv2, int Ktot,
    const float* __restrict__ bias, const float* __restrict__ bias2,
    const float* __restrict__ bng, const float* __restrict__ bnb,
    const float* __restrict__ bnm, const float* __restrict__ bnv,
    const short* __restrict__ aux, const float* __restrict__ yrp)
{
    constexpr int FI = BM / 32, FJ = BN / 32;
    constexpr int SA = BM / 64, SB = BN / 64;
    __shared__ alignas(16) short lsA[2 * BM * 32];
    __shared__ alignas(16) short lsB[2 * BN * 32];

    const int tid = threadIdx.x;
    const int l = tid & 63;
    const int wv = tid >> 6;
    const int wm = wv >> 1, wn = wv & 1;
    const int m0 = blockIdx.y * BM;
    const int n0 = blockIdx.x * BN;

    const short* arow[2];
    const short* brow[2];
#pragma unroll
    for (int s = 0; s < SA; ++s) {
        int r = wv * (16 * SA) + s * 16 + (l >> 2);
        int sd = (l & 3) ^ ((r >> 1) & 3);
        if (EPI == 5) {
            int g = m0 + r;
            int p = (g >> 12) * 4356 + (((g & 4095) >> 6) + 1) * 66 + ((g & 63) + 1);
            arow[s] = A + (size_t)p * 256 + (sd << 3);
        } else {
            arow[s] = A + (size_t)(m0 + r) * lda + (sd << 3);
        }
    }
#pragma unroll
    for (int s = 0; s < SB; ++s) {
        int r = wv * (16 * SB) + s * 16 + (l >> 2);
        int sd = (l & 3) ^ ((r >> 1) & 3);
        brow[s] = B + (size_t)(n0 + r) * ldb + (sd << 3);
    }

    const int ks = l >> 4;
    const int lc = l & 15;
    int aoff[FI], boff[FJ];
#pragma unroll
    for (int f = 0; f < FI; ++f) {
        int ra = wm * (BM / 2) + f * 16 + lc;
        aoff[f] = ra * 64 + ((ks ^ ((ra >> 1) & 3)) << 4);
    }
#pragma unroll
    for (int f = 0; f < FJ; ++f) {
        int rb = wn * (BN / 2) + f * 16 + lc;
        boff[f] = rb * 64 + ((ks ^ ((rb >> 1) & 3)) << 4);
    }

    auto stage = [&](int d, int k0l) {
        int eA, eB;
        if (EPI == 5) {
            int t = k0l >> 8, ci0 = k0l & 255;
            eA = ((t / 3) * 66 + (t % 3) - 67) * 256 + ci0;
            eB = t * 65536 + ci0;
        } else if (EPI == 1) {
            eA = (k0l < 256) ? k0l : k0l - 256;   // [xh xh xl] from [xh xl]
            eB = k0l;
        } else {
            eA = k0l; eB = k0l;
        }
        short* dA = lsA + d * (BM * 32) + wv * (SA * 512);
        short* dB = lsB + d * (BN * 32) + wv * (SB * 512);
#pragma unroll
        for (int s = 0; s < SA; ++s) gl_lds16(arow[s] + eA, dA + s * 512);
#pragma unroll
        for (int s = 0; s < SB; ++s) gl_lds16(brow[s] + eB, dB + s * 512);
    };

    f32x4 acc[FI][FJ] = {};
    const int nt = Ktot >> 5;

    stage(0, 0);
    __syncthreads();
    int cur = 0;
    for (int t = 0; t < nt; ++t) {
        if (t + 1 < nt) stage(cur ^ 1, (t + 1) << 5);
        bf16x8 af[FI], bfr[FJ];
#pragma unroll
        for (int f = 0; f < FI; ++f)
            af[f] = *(const bf16x8*)((const char*)lsA + cur * (BM * 64) + aoff[f]);
#pragma unroll
        for (int f = 0; f < FJ; ++f)
            bfr[f] = *(const bf16x8*)((const char*)lsB + cur * (BN * 64) + boff[f]);
#pragma unroll
        for (int i = 0; i < FI; ++i)
#pragma unroll
            for (int j = 0; j < FJ; ++j)
                acc[i][j] = __builtin_amdgcn_mfma_f32_16x16x32_bf16(af[i], bfr[j], acc[i][j], 0, 0, 0);
        __syncthreads();
        cur ^= 1;
    }

    float colsum[FJ < 1 ? 1 : FJ] = {};
    const int lr = (l >> 4) << 2;
#pragma unroll
    for (int i = 0; i < FI; ++i) {
        const int rowl = wm * (BM / 2) + i * 16 + lr;
#pragma unroll
        for (int j = 0; j < FJ; ++j) {
            const int coll = n0 + wn * (BN / 2) + j * 16 + lc;

            float sc = 0.f, tc = 0.f, bi = 0.f;
            if constexpr (EPI == 1) {
                bi = (coll < 128) ? bias[coll] : bias2[coll - 128];
            } else if constexpr (EPI == 3 || EPI == 4 || EPI == 5) {
                sc = bng[coll] * rsqrtf(bnv[coll] + EPSBN);
                tc = bnb[coll] - bnm[coll] * sc;
                bi = bias[coll];
            }

#pragma unroll
            for (int r = 0; r < 4; ++r) {
                const int row = m0 + rowl + r;
                float vvv = acc[i][j][r];
                if constexpr (EPI == 1) {
                    float val = vvv + bi;
                    short hi = f2bf(val);
                    short lo = f2bf(val - bf2f(hi));
                    size_t rb = (size_t)row * 256;
                    if (coll < 128) {
                        short* qb_ = (short*)Cv;
                        qb_[rb + coll] = hi;
                        qb_[rb + 128 + coll] = lo;
                    } else {
                        short* kb_ = (short*)Cv2;
                        int c = coll - 128;
                        kb_[rb + c] = hi;
                        kb_[rb + 128 + c] = lo;
                    }
                } else if constexpr (EPI == 2) {
                    int bb = coll >> 12;
                    ((short*)Cv)[((size_t)bb * 256 + row) * 4096 + (coll & 4095)] = f2bf(vvv + bias[row]);
                } else if constexpr (EPI == 3) {
                    float g = sigmoidf_(fmaxf(sc * (vvv + bi) + tc, 0.f));
                    float fv = bf2f(aux[(size_t)row * 256 + coll]);
                    float yv = fv * g;
                    ((short*)Cv)[(size_t)row * 256 + coll] = f2bf(yv);
                    colsum[j] += yv;
                } else if constexpr (EPI == 4) {
                    float rv = fmaxf(sc * (vvv + bi) + tc, 0.f);
                    int bb = row >> 12, n = row & 4095;
                    int pr = bb * 4356 + ((n >> 6) + 1) * 66 + (n & 63) + 1;
                    ((short*)Cv)[(size_t)pr * 256 + coll] = f2bf(rv);
                } else if constexpr (EPI == 5) {
                    float rv = fmaxf(sc * (vvv + bi) + tc, 0.f);
                    ((short*)Cv)[(size_t)row * 256 + coll] = f2bf(rv);
                } else if constexpr (EPI == 6) {
                    float s6 = bng[row] * rsqrtf(bnv[row] + EPSBN);
                    float t6 = bnb[row] - bnm[row] * s6;
                    int bb = coll >> 12;
                    float yl = fmaxf(s6 * (vvv + bias[row]) + t6, 0.f);
                    float sg = sigmoidf_(yl + yrp[bb * 256 + row]);
                    float fv = bf2f(aux[(size_t)coll * 256 + row]);
                    ((float*)Cv)[((size_t)bb * 256 + row) * 4096 + (coll & 4095)] = fv * sg;
                }
            }
        }
    }

    // ---- EPI 3: fused pool stage 1 — per-block column sums -> Cv2 ----
    if constexpr (EPI == 3) {
        float* lsum = (float*)lsA;   // [64 cols][8 partials], 2 KB
#pragma unroll
        for (int j = 0; j < FJ; ++j) {
            int cl = wn * (BN / 2) + j * 16 + lc;
            lsum[cl * 8 + wm * 4 + ks] = colsum[j];
        }
        __syncthreads();
        if (tid < BN) {
            float s = 0.f;
#pragma unroll
            for (int u = 0; u < 8; ++u) s += lsum[tid * 8 + u];
            ((float*)Cv2)[(size_t)blockIdx.y * 256 + n0 + tid] = s;
        }
    }
}

// ---------------------------------------------------------------------------
// Flash attention v3: swapped QK + K-ROW-PERMUTED staging so P needs NO
// cross-lane transpose (pa = packed exp of own registers).
// 512 thr / 8 waves / 32 q per wave / 256 q per block; kv-quarter per block.
// LDS K-slot m holds global kv row g(m) = ((m>>2)&3)*8 + (m>>4)*4 + (m&3).
// ---------------------------------------------------------------------------
__global__ __launch_bounds__(512, 2) void flash_k(
    const short* __restrict__ Q, const short* __restrict__ K,
    const short* __restrict__ V, short* __restrict__ Op, float* __restrict__ lp)
{
    __shared__ alignas(16) short smem[32768];
    // BYTES: K dbuf [0, 32768) | V dbuf [32768, 65536)

    const int tid = threadIdx.x;
    const int l = tid & 63;
    const int wv = tid >> 6;              // 0..7
    const int bid = blockIdx.x;
    const int combo = bid & 15;           // batch*4 + kvq
    const int batch = combo >> 2;
    const int kvq = combo & 3;
    const int q0 = (bid >> 4) * 256;
    const int kv0 = kvq * 1024;

    const short* Qb = Q + (size_t)batch * 4096 * 256;
    const short* Kb = K + (size_t)batch * 4096 * 256;
    const short* Vb = V + (size_t)batch * 256 * 4096;

    const int lc = l & 15, ks = l >> 4;

    // ---- Q fragments direct from global (B-operand: col=q=lc, k-chunk=ks) ----
    bf16x8 bq[2][8];
#pragma unroll
    for (int f = 0; f < 2; ++f)
#pragma unroll
        for (int cc = 0; cc < 8; ++cc)
            bq[f][cc] = *(const bf16x8*)(Qb +
                (size_t)(q0 + wv * 32 + f * 16 + lc) * 256 + cc * 32 + ks * 8);

    // ---- K/V staging (K rows permuted by g(slot)) ----
    const short* ksrc[2]; short* kdst[2];
    const short* vsrc[2]; short* vdst[2];
#pragma unroll
    for (int i = 0; i < 2; ++i) {
        int slot = wv * 4 + i * 2 + (l >> 5);
        int grow = ((slot >> 2) & 3) * 8 + (slot >> 4) * 4 + (slot & 3);
        int s = l & 31;
        int g = s ^ (slot & 7);
        ksrc[i] = Kb + (size_t)(kv0 + grow) * 256 + g * 8;
        kdst[i] = smem + wv * 1024 + i * 512;
        int c = wv * 32 + i * 16 + (l >> 2);
        int sv = l & 3;
        int gv = sv ^ ((c >> 1) & 3);
        vsrc[i] = Vb + (size_t)c * 4096 + kv0 + gv * 8;
        vdst[i] = smem + 16384 + wv * 1024 + i * 512;
    }
    auto stageKV = [&](int buf, int t) {
#pragma unroll
        for (int i = 0; i < 2; ++i) gl_lds16(ksrc[i] + (size_t)t * 8192, kdst[i] + buf * 8192);
#pragma unroll
        for (int i = 0; i < 2; ++i) gl_lds16(vsrc[i] + t * 32, vdst[i] + buf * 8192);
    };

    stageKV(0, 0);
    __syncthreads();

    const int kro = lc * 512;
    const int kxr = lc & 7;
    const int vb0 = lc * 64 + ((ks ^ ((lc >> 1) & 3)) << 4);

    bf16x8 ones;
#pragma unroll
    for (int e = 0; e < 8; ++e) ones[e] = (short)0x3F80;

    f32x4 acc_o[2][16] = {};
    f32x4 acc_l[2] = {};

    int cur = 0;
    for (int t = 0; t < 32; ++t) {
        if (t + 1 < 32) stageKV(cur ^ 1, t + 1);

        // ---- S^T = K·Q^T (hi/lo 3-term) ----
        const char* kb_ = (const char*)smem + cur * 16384;
        f32x4 s00 = {}, s01 = {}, s10 = {}, s11 = {};
        __builtin_amdgcn_s_setprio(1);
#pragma unroll
        for (int jc = 0; jc < 4; ++jc) {
#pragma unroll
            for (int kvf = 0; kvf < 2; ++kvf) {
                const char* rb_ = kb_ + kro + kvf * 8192;
                bf16x8 kh_ = *(const bf16x8*)(rb_ + ((((jc * 4) + ks) ^ kxr) << 4));
                bf16x8 kl_ = *(const bf16x8*)(rb_ + (((((jc + 4) * 4) + ks) ^ kxr) << 4));
                f32x4& sA = kvf ? s01 : s00;
                f32x4& sB = kvf ? s11 : s10;
                sA = __builtin_amdgcn_mfma_f32_16x16x32_bf16(kh_, bq[0][jc], sA, 0, 0, 0);
                sB = __builtin_amdgcn_mfma_f32_16x16x32_bf16(kh_, bq[1][jc], sB, 0, 0, 0);
                sA = __builtin_amdgcn_mfma_f32_16x16x32_bf16(kl_, bq[0][jc], sA, 0, 0, 0);
                sB = __builtin_amdgcn_mfma_f32_16x16x32_bf16(kl_, bq[1][jc], sB, 0, 0, 0);
                sA = __builtin_amdgcn_mfma_f32_16x16x32_bf16(kh_, bq[0][jc + 4], sA, 0, 0, 0);
                sB = __builtin_amdgcn_mfma_f32_16x16x32_bf16(kh_, bq[1][jc + 4], sB, 0, 0, 0);
            }
        }
        __builtin_amdgcn_s_setprio(0);

        // ---- P = exp(S): registers are already in PV A-operand order ----
        bf16x8 pa[2];
#pragma unroll
        for (int f = 0; f < 2; ++f) {
            const f32x4& sa = f ? s10 : s00;   // kv = ks*8 + 0..3
            const f32x4& sb = f ? s11 : s01;   // kv = ks*8 + 4..7
            union { int i4[4]; bf16x8 v; } un;
            un.i4[0] = pk2(__expf(sa[0]), __expf(sa[1]));
            un.i4[1] = pk2(__expf(sa[2]), __expf(sa[3]));
            un.i4[2] = pk2(__expf(sb[0]), __expf(sb[1]));
            un.i4[3] = pk2(__expf(sb[2]), __expf(sb[3]));
            pa[f] = un.v;
        }

        // ---- O += P·V ; l += P·1 ----
        const char* vbb = (const char*)smem + 32768 + cur * 16384;
        __builtin_amdgcn_s_setprio(1);
#pragma unroll
        for (int j = 0; j < 16; ++j) {
            bf16x8 vv = *(const bf16x8*)(vbb + vb0 + j * 1024);
            acc_o[0][j] = __builtin_amdgcn_mfma_f32_16x16x32_bf16(pa[0], vv, acc_o[0][j], 0, 0, 0);
            acc_o[1][j] = __builtin_amdgcn_mfma_f32_16x16x32_bf16(pa[1], vv, acc_o[1][j], 0, 0, 0);
        }
        acc_l[0] = __builtin_amdgcn_mfma_f32_16x16x32_bf16(pa[0], ones, acc_l[0], 0, 0, 0);
        acc_l[1] = __builtin_amdgcn_mfma_f32_16x16x32_bf16(pa[1], ones, acc_l[1], 0, 0, 0);
        __builtin_amdgcn_s_setprio(0);
        __syncthreads();
        cur ^= 1;
    }

    // ---- store unnormalized bf16 partials ----
    short* Ob = Op + ((size_t)combo * 4096 + q0 + wv * 32) * 256;
#pragma unroll
    for (int f = 0; f < 2; ++f)
#pragma unroll
        for (int j = 0; j < 16; ++j)
#pragma unroll
            for (int r = 0; r < 4; ++r)
                Ob[(size_t)(f * 16 + ks * 4 + r) * 256 + j * 16 + lc] = f2bf(acc_o[f][j][r]);
    if (lc == 0) {
        float* lb = lp + (size_t)combo * 4096 + q0 + wv * 32;
#pragma unroll
        for (int f = 0; f < 2; ++f)
#pragma unroll
            for (int r = 0; r < 4; ++r)
                lb[f * 16 + ks * 4 + r] = acc_l[f][r];
    }
}

// featT = (sum of 4 bf16 kvq partials) / (sum of l), cast bf16.
__global__ __launch_bounds__(256) void combine_k(const short* __restrict__ Op,
                                                 const float* __restrict__ lp,
                                                 short* __restrict__ o)
{
    int idx = blockIdx.x * 256 + threadIdx.x;
    size_t e = (size_t)idx * 4;
    int row = (int)(e >> 8);            // (b, q)
    int batch = row >> 12, ql = row & 4095;
    int c = (int)(e & 255);
    size_t lbase = (size_t)batch * 4 * 4096 + ql;
    float li = 1.0f / (lp[lbase] + lp[lbase + 4096] + lp[lbase + 8192] + lp[lbase + 12288]);
    size_t base = ((size_t)(batch * 4) * 4096 + ql) * 256 + c;
    const short4 a = *(const short4*)(Op + base);
    const short4 b = *(const short4*)(Op + base + 1048576);
    const short4 cc = *(const short4*)(Op + base + 2097152);
    const short4 d = *(const short4*)(Op + base + 3145728);
    short4 o4;
    o4.x = f2bf((bf2f(a.x) + bf2f(b.x) + bf2f(cc.x) + bf2f(d.x)) * li);
    o4.y = f2bf((bf2f(a.y) + bf2f(b.y) + bf2f(cc.y) + bf2f(d.y)) * li);
    o4.z = f2bf((bf2f(a.z) + bf2f(b.z) + bf2f(cc.z) + bf2f(d.z)) * li);
    o4.w = f2bf((bf2f(a.w) + bf2f(b.w) + bf2f(cc.w) + bf2f(d.w)) * li);
    *(short4*)(o + (size_t)row * 256 + c) = o4;
}

// ---------------------------------------------------------------------------
// x [B][256][4096] fp32 -> xT2 [(b,n)][512] bf16 hi/lo: [xh(256) xl(256)]
// ---------------------------------------------------------------------------
__global__ __launch_bounds__(256) void transpose_x_k(const float* __restrict__ x,
                                                     short* __restrict__ xT2)
{
    __shared__ float t[64][65];
    const int b = blockIdx.z, c0 = blockIdx.y * 64, n0 = blockIdx.x * 64;
    const int tid = threadIdx.x;
#pragma unroll
    for (int rep = 0; rep < 16; ++rep) {
        int idx = tid + rep * 256;
        int i = idx >> 6, j = idx & 63;
        t[i][j] = x[((size_t)(b * 256 + c0 + i)) * NPIX + n0 + j];
    }
    __syncthreads();
#pragma unroll
    for (int rep = 0; rep < 16; ++rep) {
        int idx = tid + rep * 256;
        int i = idx >> 6, j = idx & 63;
        float v = t[j][i];
        short hi = f2bf(v);
        short lo = f2bf(v - bf2f(hi));
        size_t rb = ((size_t)(b * NPIX + n0 + i)) * 512;
        xT2[rb + c0 + j] = hi;
        xT2[rb + 256 + c0 + j] = lo;
    }
}

// ---------------------------------------------------------------------------
// Merged setup: wq/wk hi-lo-hi, 4 plain cvts, l2w permute. Grid 3584.
// ---------------------------------------------------------------------------
__global__ __launch_bounds__(256) void prep_k(
    const float* __restrict__ wq, const float* __restrict__ wk,
    const float* __restrict__ wvp, const float* __restrict__ d1w,
    const float* __restrict__ l1w, const float* __restrict__ l3w,
    const float* __restrict__ l2w,
    short* __restrict__ wqk3, short* __restrict__ wvb, short* __restrict__ d1wb,
    short* __restrict__ l1wb, short* __restrict__ l3wb, short* __restrict__ w2b)
{
    const int b = blockIdx.x;
    const int tid = threadIdx.x;
    if (b < 256) {
        int idx = b * 256 + tid;
        int o = idx >> 8, c = idx & 255;
        const float* src = (o < 128) ? wq : wk;
        float v = src[(o & 127) * 256 + c];
        short hi = f2bf(v);
        short lo = f2bf(v - bf2f(hi));
        size_t rb = (size_t)o * 768;
        wqk3[rb + c] = hi;
        wqk3[rb + 256 + c] = lo;
        wqk3[rb + 512 + c] = hi;
    } else if (b < 1280) {
        int g = (b - 256) >> 8;
        int i = ((b - 256) & 255) * 256 + tid;
        const float* s = g == 0 ? wvp : g == 1 ? d1w : g == 2 ? l1w : l3w;
        short* d = g == 0 ? wvb : g == 1 ? d1wb : g == 2 ? l1wb : l3wb;
        d[i] = f2bf(s[i]);
    } else {
        int idx = (b - 1280) * 256 + tid;
        int t = idx >> 16;
        int rem = idx & 65535;
        int co = rem >> 8, ci = rem & 255;
        w2b[idx] = f2bf(l2w[((size_t)(co * 256 + ci)) * 9 + t]);
    }
}

// ---------------------------------------------------------------------------
// Pool stage 2: pooled[b*256+c] = (sum of 32 per-block partials)/4096
// ---------------------------------------------------------------------------
__global__ __launch_bounds__(256) void pool_s2_k(const float* __restrict__ pp2,
                                                 float* __restrict__ pooled)
{
    const int b = blockIdx.x;
    const int c = threadIdx.x;
    float s = 0.f;
#pragma unroll
    for (int k = 0; k < 32; ++k)
        s += pp2[(size_t)(b * 32 + k) * 256 + c];
    pooled[b * 256 + c] = s * (1.0f / NPIX);
}

__global__ __launch_bounds__(256) void se_k(
    const float* __restrict__ pooled,
    const float* __restrict__ r1w, const float* __restrict__ r1b,
    const float* __restrict__ g, const float* __restrict__ bb,
    const float* __restrict__ m, const float* __restrict__ vv,
    const float* __restrict__ r2w, const float* __restrict__ r2b,
    float* __restrict__ yr)
{
    const int b = blockIdx.x;
    const int tid = threadIdx.x;
    __shared__ float p[256], hbuf[128];
    p[tid] = pooled[b * 256 + tid];
    __syncthreads();
    if (tid < 128) {
        float a = r1b[tid];
        for (int ci = 0; ci < 256; ++ci) a = fmaf(r1w[tid * 256 + ci], p[ci], a);
        float s = g[tid] * rsqrtf(vv[tid] + EPSBN);
        float t = bb[tid] - m[tid] * s;
        hbuf[tid] = fmaxf(s * a + t, 0.f);
    }
    __syncthreads();
    float a = r2b[tid];
    for (int c2 = 0; c2 < 128; ++c2) a = fmaf(r2w[tid * 128 + c2], hbuf[c2], a);
    yr[b * 256 + tid] = a;
}

// ---------------------------------------------------------------------------
extern "C" void kernel_launch(void* const* d_in, const int* in_sizes, int n_in,
                              void* d_out, int out_size, void* d_ws, size_t ws_size,
                              hipStream_t stream)
{
    const float* x    = (const float*)d_in[0];
    const float* wq   = (const float*)d_in[1];
    const float* bq   = (const float*)d_in[2];
    const float* wk   = (const float*)d_in[3];
    const float* bk   = (const float*)d_in[4];
    const float* wvp  = (const float*)d_in[5];
    const float* bv   = (const float*)d_in[6];
    const float* d1w  = (const float*)d_in[7];
    const float* d1b  = (const float*)d_in[8];
    const float* bn1g = (const float*)d_in[9];
    const float* bn1b = (const float*)d_in[10];
    const float* bn1m = (const float*)d_in[11];
    const float* bn1v = (const float*)d_in[12];
    const float* lbn1g = (const float*)d_in[13];
    const float* lbn1b = (const float*)d_in[14];
    const float* lbn1m = (const float*)d_in[15];
    const float* lbn1v = (const float*)d_in[16];
    const float* lbn2g = (const float*)d_in[17];
    const float* lbn2b = (const float*)d_in[18];
    const float* lbn2m = (const float*)d_in[19];
    const float* lbn2v = (const float*)d_in[20];
    const float* lbn3g = (const float*)d_in[21];
    const float* lbn3b = (const float*)d_in[22];
    const float* lbn3m = (const float*)d_in[23];
    const float* lbn3v = (const float*)d_in[24];
    const float* l1w  = (const float*)d_in[25];
    const float* l1b  = (const float*)d_in[26];
    const float* l2w  = (const float*)d_in[27];
    const float* l2b  = (const float*)d_in[28];
    const float* l3w  = (const float*)d_in[29];
    const float* l3b  = (const float*)d_in[30];
    const float* r1w  = (const float*)d_in[31];
    const float* r1b  = (const float*)d_in[32];
    const float* rbng = (const float*)d_in[33];
    const float* rbnb = (const float*)d_in[34];
    const float* rbnm = (const float*)d_in[35];
    const float* rbnv = (const float*)d_in[36];
    const float* r2w  = (const float*)d_in[37];
    const float* r2b  = (const float*)d_in[38];

    float* out = (float*)d_out;
    char* wsb = (char*)d_ws;

    // ---- workspace layout ----
    short* xT2  = (short*)(wsb);                    // 0-16 MB (dead after proj)
    short* qbuf = (short*)(wsb + (24ull << 20));    // 24-32
    short* kbuf = (short*)(wsb + (32ull << 20));    // 32-40
    short* vbuf = (short*)(wsb + (40ull << 20));    // 40-48
    short* Opart= (short*)(wsb + (48ull << 20));    // 48-80 bf16 (dead after combine)
    short* featT= (short*)(wsb + (112ull << 20));   // 112-120
    float* lpart= (float*)(wsb + (120ull << 20));   // 256 KB
    short* yT   = (short*)(wsb + (48ull << 20));    // overlay Opart post-combine
    short* t1pad= (short*)(wsb + (56ull << 20));    // overlay, 8.51 MB
    short* t2T  = (short*)(wsb + (65ull << 20));    // overlay
    short* wqk3 = (short*)(wsb + (121ull << 20));   // 384 KB
    short* wvb  = wqk3 + 196608;                    // 128 KB each
    short* d1wb = wvb + 65536;
    short* l1wb = d1wb + 65536;
    short* l3wb = l1wb + 65536;
    short* w2b  = l3wb + 65536;                     // 1.125 MB
    float* pooled = (float*)(wsb + (123ull << 20) + (512ull << 10));
    float* yrb  = pooled + 1024;
    float* ppart2 = yrb + 1024;                     // [128][256] 128 KB

    dim3 blk(256);

    // ---- setup ----
    transpose_x_k<<<dim3(64, 4, 4), blk, 0, stream>>>(x, xT2);
    prep_k<<<3584, blk, 0, stream>>>(wq, wk, wvp, d1w, l1w, l3w, l2w,
                                     wqk3, wvb, d1wb, l1wb, l3wb, w2b);

    // ---- projections ----
    gbt_k<1, 128, 64><<<dim3(4, 128), blk, 0, stream>>>(xT2, 512, wqk3, 768, qbuf, kbuf, 768,
        bq, bk, nullptr, nullptr, nullptr, nullptr, nullptr, nullptr);
    gbt_k<2, 64, 128><<<dim3(128, 4), blk, 0, stream>>>(wvb, 256, xT2, 512, vbuf, nullptr, 256,
        bv, nullptr, nullptr, nullptr, nullptr, nullptr, nullptr, nullptr);

    // ---- fused flash attention (kv-quarter bf16 partials) + combine ----
    flash_k<<<256, dim3(512), 0, stream>>>(qbuf, kbuf, vbuf, Opart, lpart);
    combine_k<<<4096, blk, 0, stream>>>(Opart, lpart, featT);

    // ---- gate: yT = feat * sigmoid(relu(bn1(d1(feat)))); fused pool s1 ----
    gbt_k<3, 128, 64><<<dim3(4, 128), blk, 0, stream>>>(featT, 256, d1wb, 256, yT, ppart2, 256,
        d1b, nullptr, bn1g, bn1b, bn1m, bn1v, featT, nullptr);

    hipMemsetAsync(t1pad, 0, (size_t)4 * 4356 * 256 * 2, stream);

    // ---- SE branch ----
    pool_s2_k<<<4, blk, 0, stream>>>(ppart2, pooled);
    se_k<<<4, blk, 0, stream>>>(pooled, r1w, r1b, rbng, rbnb, rbnm, rbnv, r2w, r2b, yrb);

    // ---- left branch ----
    gbt_k<4, 128, 64><<<dim3(4, 128), blk, 0, stream>>>(yT, 256, l1wb, 256, t1pad, nullptr, 256,
        l1b, nullptr, lbn1g, lbn1b, lbn1m, lbn1v, nullptr, nullptr);
    gbt_k<5, 128, 64><<<dim3(4, 128), blk, 0, stream>>>(t1pad, 256, w2b, 256, t2T, nullptr, 2304,
        l2b, nullptr, lbn2g, lbn2b, lbn2m, lbn2v, nullptr, nullptr);

    // ---- final: out = feat * sigmoid(relu(bn3(l3(t2))) + yr) ----
    gbt_k<6, 64, 128><<<dim3(128, 4), blk, 0, stream>>>(l3wb, 256, t2T, 256, out, nullptr, 256,
        l3b, nullptr, lbn3g, lbn3b, lbn3m, lbn3v, featT, yrb);
}